// Round 5
// baseline (4584.736 us; speedup 1.0000x reference)
//
#include <hip/hip_runtime.h>
#include <stdint.h>

#define N_TOK 2048
#define IN_D  1024
#define NEXP  10
#define NSTEP 4
#define INNER 768
#define SHD   2048
#define DMAX  3328
#define DSUM  24064

typedef __attribute__((ext_vector_type(4))) float f32x4;
typedef __attribute__((ext_vector_type(8))) short bf16x8;

__device__ const int c_dims[10] = {1536,2048,2560,3072,1792,2304,2816,2048,2560,3328};
__device__ const int c_offs[10] = {0,1536,3584,6144,9216,11008,13312,16128,18176,20736};
__device__ const int c_acts[10] = {0,1,2,3,4,5,6,7,0,1};
__device__ const int c_cum[11]  = {0,12,28,48,72,86,104,126,142,162,188};

__device__ __forceinline__ float wred(float v){
#pragma unroll
  for (int s = 32; s > 0; s >>= 1) v += __shfl_xor(v, s, 64);
  return v;
}
__device__ __forceinline__ float bf2f(uint16_t u){
  return __uint_as_float(((uint32_t)u) << 16);
}
__device__ __forceinline__ uint16_t f2bf(float f){
  uint32_t u = __float_as_uint(f);
  return (uint16_t)((u + 0x7FFFu + ((u >> 16) & 1u)) >> 16);
}
__device__ __forceinline__ void gload16(const uint16_t* g, uint16_t* l){
  __builtin_amdgcn_global_load_lds(
      (const __attribute__((address_space(1))) uint32_t*)(const void*)g,
      (__attribute__((address_space(3))) uint32_t*)(void*)l, 16, 0, 0);
}

__device__ __forceinline__ float actf(int a, float x){
  switch(a){
    case 0: return x / (1.f + expf(-x));
    case 1: return 0.5f * x * (1.f + erff(x * 0.7071067811865475f));
    case 2: { float sp = fmaxf(x,0.f) + log1pf(expf(-fabsf(x)));
              return x * tanhf(sp); }
    case 3: return fmaxf(x, 0.f);
    case 4: return x > 0.f ? 1.0507009873554805f * x
                           : 1.7580993408473768f * expm1f(x);
    case 5: return tanhf(x);
    case 6: return fmaxf(x,0.f) + log1pf(expf(-fabsf(x)));
    default: return x > 0.f ? x : expm1f(x);
  }
}

// ---------------- f32 -> (hi, lo) bf16 split -----------------------------------
__global__ void split_kernel(const float* __restrict__ src, uint16_t* __restrict__ hi,
                             uint16_t* __restrict__ lo, size_t n){
  size_t i = ((size_t)blockIdx.x * blockDim.x + threadIdx.x) << 2;
  size_t stride = ((size_t)gridDim.x * blockDim.x) << 2;
  for (; i < n; i += stride){
    float4 v = *(const float4*)(src + i);
    ushort4 h, l;
    h.x = f2bf(v.x); l.x = f2bf(v.x - bf2f(h.x));
    h.y = f2bf(v.y); l.y = f2bf(v.y - bf2f(h.y));
    h.z = f2bf(v.z); l.z = f2bf(v.z - bf2f(h.z));
    h.w = f2bf(v.w); l.w = f2bf(v.w - bf2f(h.w));
    *(ushort4*)(hi + i) = h;
    *(ushort4*)(lo + i) = l;
  }
}
__global__ void cvt_bf16_kernel(const float* __restrict__ src, uint16_t* __restrict__ dst, size_t n){
  size_t i = ((size_t)blockIdx.x * blockDim.x + threadIdx.x) << 2;
  size_t stride = ((size_t)gridDim.x * blockDim.x) << 2;
  for (; i < n; i += stride){
    float4 v = *(const float4*)(src + i);
    ushort4 h;
    h.x = f2bf(v.x); h.y = f2bf(v.y); h.z = f2bf(v.z); h.w = f2bf(v.w);
    *(ushort4*)(dst + i) = h;
  }
}
__global__ void fill1_kernel(float* __restrict__ p, int n){
  int i = blockIdx.x * blockDim.x + threadIdx.x;
  if (i < n) p[i] = 1.f;
}

// ---------------- split-bf16 MFMA GEMM, 2-phase dbuf, chunk-major LDS ----------
// C = epi(A @ W^T). A=(Ah,Al)[N,K], W=(Wh,Wl)[D,K]. 128x128 tile, BK=32.
enum { EPI_GELU_BIAS=0, EPI_ADD_BIAS=1, EPI_DUAL_PRE=2, EPI_DUAL_QTRIO=3 };

template<int EPI>
__global__ __launch_bounds__(256)
void gemm_sp(const uint16_t* __restrict__ Ah, const uint16_t* __restrict__ Al,
             const uint16_t* __restrict__ Wh, const uint16_t* __restrict__ Wl,
             const float* __restrict__ bias, const float* __restrict__ addend,
             float* __restrict__ C, float* __restrict__ C2,
             uint16_t* __restrict__ outH, uint16_t* __restrict__ outL,
             int K, int D, int ld1, int ld2, int split)
{
  // [tensor Ah,Al,Wh,Wl][buf][128 rows x 4 chunks of 16B, chunk-major]
  __shared__ __align__(16) uint16_t sm[4][2][4096];
  int tid = threadIdx.x, lane = tid & 63, wave = tid >> 6;
  int wr = wave >> 1, wc = wave & 1;
  int arow = lane & 15, agrp = lane >> 4;
  int rowBase = blockIdx.y * 128, colBase = blockIdx.x * 128;
  f32x4 acc[4][4];
#pragma unroll
  for (int m = 0; m < 4; m++)
#pragma unroll
    for (int n = 0; n < 4; n++){ f32x4 z = {0.f,0.f,0.f,0.f}; acc[m][n] = z; }

#define STAGE_G(buf, k0) do { \
  _Pragma("unroll") \
  for (int s = 0; s < 2; s++){ \
    int u = tid + s * 256; \
    int rr = u & 127, ch = u >> 7; \
    size_t ga = (size_t)(rowBase + rr) * K + (k0) + ch * 8; \
    size_t gw = (size_t)(colBase + rr) * K + (k0) + ch * 8; \
    gload16(&Ah[ga], &sm[0][buf][u << 3]); \
    gload16(&Al[ga], &sm[1][buf][u << 3]); \
    gload16(&Wh[gw], &sm[2][buf][u << 3]); \
    gload16(&Wl[gw], &sm[3][buf][u << 3]); \
  } } while(0)

  STAGE_G(0, 0);
  __syncthreads();
  int nk = K >> 5;
  for (int ki = 0; ki < nk; ki++){
    int cb = ki & 1;
    if (ki + 1 < nk) STAGE_G(cb ^ 1, (ki + 1) << 5);
    bf16x8 ah[4], al[4], bh[4], bl[4];
#pragma unroll
    for (int m = 0; m < 4; m++){
      int u = (agrp << 7) + wr*64 + m*16 + arow;   // chunk-major unit
      ah[m] = *(const bf16x8*)&sm[0][cb][u << 3];
      al[m] = *(const bf16x8*)&sm[1][cb][u << 3];
    }
#pragma unroll
    for (int n = 0; n < 4; n++){
      int u = (agrp << 7) + wc*64 + n*16 + arow;
      bh[n] = *(const bf16x8*)&sm[2][cb][u << 3];
      bl[n] = *(const bf16x8*)&sm[3][cb][u << 3];
    }
#pragma unroll
    for (int m = 0; m < 4; m++)
#pragma unroll
      for (int n = 0; n < 4; n++){
        acc[m][n] = __builtin_amdgcn_mfma_f32_16x16x32_bf16(ah[m], bh[n], acc[m][n], 0, 0, 0);
        acc[m][n] = __builtin_amdgcn_mfma_f32_16x16x32_bf16(ah[m], bl[n], acc[m][n], 0, 0, 0);
        acc[m][n] = __builtin_amdgcn_mfma_f32_16x16x32_bf16(al[m], bh[n], acc[m][n], 0, 0, 0);
      }
    __syncthreads();
  }
#undef STAGE_G
#pragma unroll
  for (int m = 0; m < 4; m++){
#pragma unroll
    for (int n = 0; n < 4; n++){
      int col = colBase + wc*64 + n*16 + arow;
#pragma unroll
      for (int r2 = 0; r2 < 4; r2++){
        int row = rowBase + wr*64 + m*16 + agrp*4 + r2;
        float v = acc[m][n][r2];
        if (EPI == EPI_GELU_BIAS){
          v += bias[col];
          v = 0.5f * v * (1.f + erff(v * 0.7071067811865475f));
          size_t idx = (size_t)row * D + col;
          uint16_t h = f2bf(v);
          outH[idx] = h; outL[idx] = f2bf(v - bf2f(h));
        }
        if (EPI == EPI_ADD_BIAS){
          v += bias[col] + addend[(size_t)row * D + col];
          size_t idx = (size_t)row * D + col;
          C[idx] = v;
          uint16_t h = f2bf(v);
          outH[idx] = h; outL[idx] = f2bf(v - bf2f(h));
        }
        if (EPI == EPI_DUAL_PRE){
          if (col < split) C[(size_t)row * ld1 + col] = v;
          else C2[(size_t)row * ld2 + (col - split)] = v / (1.f + expf(-v));
        }
        if (EPI == EPI_DUAL_QTRIO){
          if (col < split) C[(size_t)row * ld1 + col] = v;
          else C2[(size_t)row * ld2 + (col - split)] = v + bias[col - split];
        }
      }
    }
  }
}

// ---------------- sparse expert up: 256x128 tile, 8 waves, BK=64 ---------------
__global__ __launch_bounds__(512)
void expert_up_mfma(const uint16_t* __restrict__ Abf, const uint16_t* __restrict__ Ubf,
                    const int* __restrict__ cnt, const int* __restrict__ gidx,
                    uint16_t* __restrict__ HH)
{
  // decode (e, ct) from blockIdx.y via cumulative tile table
  int y = blockIdx.y;
  int e = 0;
#pragma unroll
  for (int i = 1; i < 11; i++) if (y >= c_cum[i]) e = i;
  int ct = y - c_cum[e];
  int dcols = c_dims[e];
  int ne = cnt[e];
  int rowBase = blockIdx.x * 256;
  if (rowBase >= ne) return;
  const uint16_t* W = Ubf + (size_t)e * DMAX * IN_D + (size_t)ct * 128 * IN_D;

  __shared__ __align__(16) uint16_t sA[2048 * 8];   // 32KB: 8 chunks x 256 rows
  __shared__ __align__(16) uint16_t sB[1024 * 8];   // 16KB: 8 chunks x 128 rows
  int tid = threadIdx.x, lane = tid & 63, wave = tid >> 6;
  int wr = wave >> 1, wc = wave & 1;                 // wr 0..3, wc 0..1
  int arow = lane & 15, agrp = lane >> 4;

  int slot = rowBase + (tid & 255);
  int tok = (slot < ne) ? gidx[e * N_TOK + slot] : 0;

  f32x4 acc[4][4];
#pragma unroll
  for (int m = 0; m < 4; m++)
#pragma unroll
    for (int n = 0; n < 4; n++){ f32x4 z = {0.f,0.f,0.f,0.f}; acc[m][n] = z; }

  for (int k0 = 0; k0 < IN_D; k0 += 64){
    // A: 2048 units (row = u&255 == tid&255 -> one token per thread)
#pragma unroll
    for (int s = 0; s < 4; s++){
      int u = tid + s * 512;
      int ch = u >> 8;
      gload16(&Abf[(size_t)tok * IN_D + k0 + ch * 8], &sA[u << 3]);
    }
    // B: 1024 units (row = u&127, chunk = u>>7)
#pragma unroll
    for (int s = 0; s < 2; s++){
      int u = tid + s * 512;
      int rr = u & 127, ch = u >> 7;
      gload16(&W[(size_t)rr * IN_D + k0 + ch * 8], &sB[u << 3]);
    }
    __syncthreads();
#pragma unroll
    for (int kk = 0; kk < 2; kk++){
      bf16x8 a[4], b[4];
#pragma unroll
      for (int m = 0; m < 4; m++){
        int u = ((kk*4 + agrp) << 8) + wr*64 + m*16 + arow;
        a[m] = *(const bf16x8*)&sA[u << 3];
      }
#pragma unroll
      for (int n = 0; n < 4; n++){
        int u = ((kk*4 + agrp) << 7) + wc*64 + n*16 + arow;
        b[n] = *(const bf16x8*)&sB[u << 3];
      }
#pragma unroll
      for (int m = 0; m < 4; m++)
#pragma unroll
        for (int n = 0; n < 4; n++)
          acc[m][n] = __builtin_amdgcn_mfma_f32_16x16x32_bf16(a[m], b[n], acc[m][n], 0, 0, 0);
    }
    __syncthreads();
  }
  // epilogue: 2 passes of 128 rows through sA as Ht (32KB)
  int actid = c_acts[e];
  uint16_t* Ht = sA;
  size_t base_e = (size_t)N_TOK * c_offs[e];
#pragma unroll
  for (int p = 0; p < 2; p++){
    if ((wr >> 1) == p){
      int lwr = wr & 1;
#pragma unroll
      for (int m = 0; m < 4; m++){
        int rb0 = lwr*64 + m*16 + agrp*4;
#pragma unroll
        for (int n = 0; n < 4; n++){
          int col = wc*64 + n*16 + arow;
#pragma unroll
          for (int r2 = 0; r2 < 4; r2++){
            int row = rb0 + r2;
            float v = actf(actid, acc[m][n][r2]);
            Ht[row * 128 + (col ^ ((row & 7) << 3))] = f2bf(v);
          }
        }
      }
    }
    __syncthreads();
    // copy 128 rows x 16 chunks = 2048 units with 512 threads -> 4 iterations
#pragma unroll
    for (int i = 0; i < 4; i++){
      int c = tid + i * 512;
      int row = c >> 4, chunk = c & 15;
      int schunk = (chunk & 8) | ((chunk ^ row) & 7);
      int4 val = *(const int4*)&Ht[row * 128 + schunk * 8];
      *(int4*)&HH[base_e + (size_t)(rowBase + p*128 + row) * dcols
                  + (size_t)ct * 128 + chunk * 8] = val;
    }
    __syncthreads();
  }
}

// ---------------- rowred: mem scores+softmax, depth softmax, ssm_a -------------
__global__ __launch_bounds__(256)
void rowred_kernel(const float* __restrict__ qout, const float* __restrict__ keys,
                   const float* __restrict__ Ac, const float* __restrict__ W0,
                   const float* __restrict__ W1, const float* __restrict__ W2,
                   const float* __restrict__ cur, const float* __restrict__ saw,
                   const float* __restrict__ sab,
                   const float* __restrict__ t0, const float* __restrict__ t1,
                   const float* __restrict__ t2,
                   float* __restrict__ ubuf, float* __restrict__ sval,
                   float* __restrict__ dval, float* __restrict__ t40, int t)
{
  int lane = threadIdx.x & 63;
  int row = blockIdx.x * 4 + (threadIdx.x >> 6);
  size_t qb = (size_t)row * 2048;
  size_t rb = (size_t)row * IN_D;
  size_t tb = (size_t)row * 3072;
  float p[24], ps[40];
  float a0 = 0.f, a1 = 0.f, a2 = 0.f;
#pragma unroll
  for (int m = 0; m < 24; m++) p[m] = 0.f;
#pragma unroll
  for (int o = 0; o < 40; o++) ps[o] = 0.f;
  for (int k = lane; k < IN_D; k += 64){
    float qv = qout[qb + k];
    float cv = cur[rb + k];
#pragma unroll
    for (int m = 0; m < 24; m++) p[m] = fmaf(qv, keys[m * IN_D + k], p[m]);
#pragma unroll
    for (int o = 0; o < 40; o++) ps[o] = fmaf(cv, saw[o * IN_D + k], ps[o]);
    if (t > 0){
      float dqv = qout[qb + 1024 + k];
      a0 = fmaf(dqv, t0[tb + k], a0);
      if (t > 1) a1 = fmaf(dqv, t1[tb + k], a1);
      if (t > 2) a2 = fmaf(dqv, t2[tb + k], a2);
    }
  }
#pragma unroll
  for (int m = 0; m < 24; m++) p[m] = wred(p[m]) * 0.03125f;
#pragma unroll
  for (int o = 0; o < 40; o++) ps[o] = wred(ps[o]);
  // memory softmax + history coefficients
  float mx = p[0];
#pragma unroll
  for (int m = 1; m < 24; m++) mx = fmaxf(mx, p[m]);
  float s = 0.f;
#pragma unroll
  for (int m = 0; m < 24; m++){ p[m] = expf(p[m] - mx); s += p[m]; }
  float inv = 1.f / s;
  float s0 = 0.f, s1 = 0.f, s2 = 0.f;
#pragma unroll
  for (int m = 0; m < 24; m++){
    float a = p[m] * inv;
    p[m] = a;
    if (t > 0) s0 = fmaf(a, W0[row * 24 + m], s0);
    if (t > 1) s1 = fmaf(a, W1[row * 24 + m], s1);
    if (t > 2) s2 = fmaf(a, W2[row * 24 + m], s2);
  }
  // depth softmax
  float e0 = 0.f, e1 = 0.f, e2 = 0.f;
  if (t > 0){
    a0 = wred(a0) * 0.03125f; a1 = wred(a1) * 0.03125f; a2 = wred(a2) * 0.03125f;
    float dmx = a0;
    if (t > 1) dmx = fmaxf(dmx, a1);
    if (t > 2) dmx = fmaxf(dmx, a2);
    e0 = expf(a0 - dmx);
    e1 = (t > 1) ? expf(a1 - dmx) : 0.f;
    e2 = (t > 2) ? expf(a2 - dmx) : 0.f;
    float dinv = 1.f / (e0 + e1 + e2);
    e0 *= dinv; e1 *= dinv; e2 *= dinv;
  }
  if (lane == 0){
#pragma unroll
    for (int m = 0; m < 24; m++) ubuf[row * 24 + m] = p[m] * Ac[row * 24 + m];
    sval[row * 4 + 0] = s0; sval[row * 4 + 1] = s1; sval[row * 4 + 2] = s2;
    dval[row * 4 + 0] = e0; dval[row * 4 + 1] = e1; dval[row * 4 + 2] = e2;
#pragma unroll
    for (int o = 0; o < 40; o++) t40[row * 40 + o] = tanhf(ps[o] + sab[o]);
  }
}

// ---------------- ctx_enr: mctx + dctx + ssm_b + enriched + LN + split ---------
__global__ __launch_bounds__(256)
void ctx_enr_kernel(const float* __restrict__ ubuf, const float* __restrict__ sval,
                    const float* __restrict__ dval, const float* __restrict__ mvi,
                    const float* __restrict__ t0, const float* __restrict__ t1,
                    const float* __restrict__ t2, const float* __restrict__ cur,
                    const float* __restrict__ t40, const float* __restrict__ sbw,
                    const float* __restrict__ sbb, const float* __restrict__ lng,
                    const float* __restrict__ lnbv, float* __restrict__ mctx,
                    float* __restrict__ dctx, float* __restrict__ enr,
                    uint16_t* __restrict__ lnh, uint16_t* __restrict__ lnl, int t)
{
  int row = blockIdx.x;
  int tid = threadIdx.x;
  __shared__ float su[24], ss[3], de[3], s40[40], red[8];
  if (tid < 24) su[tid] = ubuf[row * 24 + tid];
  if (tid >= 32 && tid < 35) ss[tid - 32] = sval[row * 4 + (tid - 32)];
  if (tid >= 64 && tid < 67) de[tid - 64] = dval[row * 4 + (tid - 64)];
  if (tid >= 96 && tid < 136) s40[tid - 96] = t40[row * 40 + (tid - 96)];
  __syncthreads();
  size_t tb = (size_t)row * 3072;
  float ev[4];
  float part = 0.f;
#pragma unroll
  for (int j = 0; j < 4; j++){
    int d = tid + j * 256;
    size_t idx = (size_t)row * IN_D + d;
    float mv = 0.f;
#pragma unroll
    for (int m = 0; m < 24; m++) mv = fmaf(su[m], mvi[m * IN_D + d], mv);
    float dv = 0.f;
    if (t > 0){
      mv = fmaf(ss[0], t0[tb + 2048 + d], mv);
      dv = de[0] * t0[tb + 1024 + d];
      if (t > 1){ mv = fmaf(ss[1], t1[tb + 2048 + d], mv); dv = fmaf(de[1], t1[tb + 1024 + d], dv); }
      if (t > 2){ mv = fmaf(ss[2], t2[tb + 2048 + d], mv); dv = fmaf(de[2], t2[tb + 1024 + d], dv); }
    }
    float sv = sbb[d];
#pragma unroll
    for (int o = 0; o < 40; o++) sv = fmaf(s40[o], sbw[d * 40 + o], sv);
    float v = cur[idx] + 0.34f * mv + 0.22f * dv + 0.18f * sv;
    mctx[idx] = mv;
    dctx[idx] = dv;
    ev[j] = v; part += v;
  }
  part = wred(part);
  if ((tid & 63) == 0) red[tid >> 6] = part;
  __syncthreads();
  float mean = (red[0] + red[1] + red[2] + red[3]) * (1.f / 1024.f);
  float vp = 0.f;
#pragma unroll
  for (int j = 0; j < 4; j++){ float dd = ev[j] - mean; vp += dd * dd; }
  vp = wred(vp);
  if ((tid & 63) == 0) red[4 + (tid >> 6)] = vp;
  __syncthreads();
  float var = (red[4] + red[5] + red[6] + red[7]) * (1.f / 1024.f);
  float rs = 1.f / sqrtf(var + 1e-5f);
#pragma unroll
  for (int j = 0; j < 4; j++){
    int d = tid + j * 256;
    size_t idx = (size_t)row * IN_D + d;
    enr[idx] = ev[j];
    float v = (ev[j] - mean) * rs * lng[t * IN_D + d] + lnbv[t * IN_D + d];
    uint16_t h = f2bf(v);
    lnh[idx] = h;
    lnl[idx] = f2bf(v - bf2f(h));
  }
}

// ---------------- routing + compaction ------------------------------------------
__global__ __launch_bounds__(256)
void routing_kernel(const float* __restrict__ cur, const float* __restrict__ mctx,
                    const float* __restrict__ dctx,
                    const float* __restrict__ msw, const float* __restrict__ msb,
                    const float* __restrict__ mmw, const float* __restrict__ mmb,
                    const float* __restrict__ ebias,
                    const float* __restrict__ bw, const float* __restrict__ bb,
                    const float* __restrict__ wgw, const float* __restrict__ wgb,
                    const float* __restrict__ hw, const float* __restrict__ hb,
                    float* __restrict__ sg, float* __restrict__ haltb,
                    float* __restrict__ Ac, float* __restrict__ W0,
                    float* __restrict__ W1, float* __restrict__ W2,
                    int* __restrict__ cnt, int* __restrict__ gidx,
                    int* __restrict__ pos, int t)
{
  int lane = threadIdx.x & 63;
  int row = blockIdx.x * 4 + (threadIdx.x >> 6);
  size_t rb = (size_t)row * IN_D;
  float ps[40], pw[24], pm[4], pb[4], ph = 0.f;
#pragma unroll
  for (int o = 0; o < 40; o++) ps[o] = 0.f;
#pragma unroll
  for (int m = 0; m < 24; m++) pw[m] = 0.f;
#pragma unroll
  for (int o = 0; o < 4; o++){ pm[o] = 0.f; pb[o] = 0.f; }
  const float* hwt = hw + t * IN_D;
  for (int k = lane; k < IN_D; k += 64){
    float cv = cur[rb + k], mv = mctx[rb + k], dv = dctx[rb + k];
#pragma unroll
    for (int o = 0; o < 40; o++) ps[o] = fmaf(cv, msw[o * IN_D + k], ps[o]);
#pragma unroll
    for (int o = 0; o < 4; o++) pm[o] = fmaf(cv, mmw[o * IN_D + k], pm[o]);
#pragma unroll
    for (int o = 0; o < 4; o++) pb[o] = fmaf(cv, bw[o * IN_D + k], pb[o]);
#pragma unroll
    for (int m = 0; m < 24; m++){
      float t1v = fmaf(cv, wgw[m * 2048 + k], pw[m]);
      pw[m] = fmaf(mv, wgw[m * 2048 + 1024 + k], t1v);
    }
    ph = fmaf(cv + 0.2f * mv + 0.1f * dv, hwt[k], ph);
  }
#pragma unroll
  for (int o = 0; o < 40; o++) ps[o] = wred(ps[o]);
#pragma unroll
  for (int m = 0; m < 24; m++) pw[m] = wred(pw[m]);
#pragma unroll
  for (int o = 0; o < 4; o++){ pm[o] = wred(pm[o]); pb[o] = wred(pb[o]); }
  ph = wred(ph);

#pragma unroll
  for (int o = 0; o < 4; o++) pm[o] += mmb[o];
  float mmx = fmaxf(fmaxf(pm[0], pm[1]), fmaxf(pm[2], pm[3]));
  float msum = 0.f;
#pragma unroll
  for (int o = 0; o < 4; o++){ pm[o] = expf(pm[o] - mmx); msum += pm[o]; }
  float minv = 1.f / msum;
  float gl[10];
#pragma unroll
  for (int e = 0; e < 10; e++){
    float g = ebias[e];
#pragma unroll
    for (int s2 = 0; s2 < 4; s2++) g = fmaf(pm[s2] * minv, ps[s2 * 10 + e] + msb[s2 * 10 + e], g);
    gl[e] = g;
  }
  float gmx = gl[0];
#pragma unroll
  for (int e = 1; e < 10; e++) gmx = fmaxf(gmx, gl[e]);
  float gs = 0.f;
#pragma unroll
  for (int e = 0; e < 10; e++){ gl[e] = expf(gl[e] - gmx); gs += gl[e]; }
  float ginv = 1.f / gs;
#pragma unroll
  for (int e = 0; e < 10; e++) gl[e] *= ginv;
#pragma unroll
  for (int o = 0; o < 4; o++) pb[o] += bb[o];
  int bud = 1; float bbest = pb[0];
  if (pb[1] > bbest){ bbest = pb[1]; bud = 2; }
  if (pb[2] > bbest){ bbest = pb[2]; bud = 3; }
  if (pb[3] > bbest){ bbest = pb[3]; bud = 4; }
  float tv[4]; int ti[4]; unsigned used = 0;
#pragma unroll
  for (int j = 0; j < 4; j++){
    float best = -1e30f; int bi = 0;
#pragma unroll
    for (int e = 0; e < 10; e++){
      bool ok = (!((used >> e) & 1u)) && (gl[e] > best);
      if (ok){ best = gl[e]; bi = e; }
    }
    tv[j] = best; ti[j] = bi; used |= (1u << bi);
  }
  float ssum = tv[0];
  if (bud > 1) ssum += tv[1];
  if (bud > 2) ssum += tv[2];
  if (bud > 3) ssum += tv[3];
  float den = fmaxf(ssum, 1e-6f);
  float sup = 1.f - tv[0] / den;
#pragma unroll
  for (int m = 0; m < 24; m++) pw[m] += wgb[m];
  float wmx = pw[0];
#pragma unroll
  for (int m = 1; m < 24; m++) wmx = fmaxf(wmx, pw[m]);
  float wsum = 0.f;
#pragma unroll
  for (int m = 0; m < 24; m++){ pw[m] = expf(pw[m] - wmx); wsum += pw[m]; }
  float winv = 1.f / wsum;
  float hv = 1.f / (1.f + expf(-(ph + hb[t])));

  if (lane == 0){
#pragma unroll
    for (int e = 0; e < 10; e++){
      float sv = 0.f;
#pragma unroll
      for (int j = 0; j < 4; j++) if (j < bud && ti[j] == e) sv = tv[j] / den;
      sg[row * 10 + e] = sv;
      if (sv != 0.f){
        int slot = atomicAdd(&cnt[e], 1);
        gidx[e * N_TOK + slot] = row;
        pos[row * 10 + e] = slot;
      }
    }
    haltb[row] = hv;
#pragma unroll
    for (int m = 0; m < 24; m++){
      float c = sup * pw[m] * winv;
      float om = 1.f - c;
      Ac[row * 24 + m] *= om;
      if (t > 0) W0[row * 24 + m] *= om;
      if (t > 1) W1[row * 24 + m] *= om;
      if (t > 2) W2[row * 24 + m] *= om;
      if (t == 0)      W0[row * 24 + m] = c;
      else if (t == 1) W1[row * 24 + m] = c;
      else if (t == 2) W2[row * 24 + m] = c;
    }
  }
}

// ---------------- downfin: expert down + LN + gated acc + step finalize --------
__global__ __launch_bounds__(256)
void downfin_kernel(const uint16_t* __restrict__ HH, const int* __restrict__ pos,
                    const float* __restrict__ ED, const float* __restrict__ sg,
                    const float* __restrict__ eng, const float* __restrict__ enb,
                    const float* __restrict__ mctx, const float* __restrict__ dctx,
                    const float* __restrict__ mow, const float* __restrict__ dow,
                    const float* __restrict__ haltb, float* __restrict__ total,
                    float* __restrict__ cumh)
{
  int lane = threadIdx.x & 63;
  int row = blockIdx.x * 4 + (threadIdx.x >> 6);
  float out[10] = {};
  for (int e = 0; e < NEXP; e++){
    float g = sg[row * 10 + e];
    if (g != 0.0f){
      int d = c_dims[e];
      int slot = pos[row * 10 + e];
      const uint16_t* hr = HH + (size_t)N_TOK * c_offs[e] + (size_t)slot * d;
      const float* wd = ED + (size_t)e * 10 * DMAX;
      float p[10] = {};
      for (int k = lane * 2; k < d; k += 128){
        uint32_t hv2 = *(const uint32_t*)&hr[k];
        float h0 = bf2f((uint16_t)hv2), h1 = bf2f((uint16_t)(hv2 >> 16));
#pragma unroll
        for (int o = 0; o < 10; o++){
          float2 w2 = *(const float2*)&wd[o * DMAX + k];
          p[o] = fmaf(h0, w2.x, fmaf(h1, w2.y, p[o]));
        }
      }
#pragma unroll
      for (int o = 0; o < 10; o++) p[o] = wred(p[o]);
      float mean = 0.f;
#pragma unroll
      for (int o = 0; o < 10; o++) mean += p[o];
      mean *= 0.1f;
      float var = 0.f;
#pragma unroll
      for (int o = 0; o < 10; o++){ float dd = p[o] - mean; var += dd * dd; }
      var *= 0.1f;
      float rs = 1.f / sqrtf(var + 1e-5f);
#pragma unroll
      for (int o = 0; o < 10; o++)
        out[o] += g * ((p[o] - mean) * rs * eng[e * 10 + o] + enb[e * 10 + o]);
    }
  }
  // mem/depth output projections
  size_t rb = (size_t)row * IN_D;
  float p1[10], p2[10];
#pragma unroll
  for (int o = 0; o < 10; o++){ p1[o] = 0.f; p2[o] = 0.f; }
  for (int k = lane; k < IN_D; k += 64){
    float mv = mctx[rb + k], dv = dctx[rb + k];
#pragma unroll
    for (int o = 0; o < 10; o++){
      p1[o] = fmaf(mv, mow[o * IN_D + k], p1[o]);
      p2[o] = fmaf(dv, dow[o * IN_D + k], p2[o]);
    }
  }
#pragma unroll
  for (int o = 0; o < 10; o++){ p1[o] = wred(p1[o]); p2[o] = wred(p2[o]); }
  if (lane == 0){
    float rem = 1.f - cumh[row];
#pragma unroll
    for (int o = 0; o < 10; o++)
      total[row * 10 + o] += rem * (out[o] + 0.22f * p1[o] + 0.14f * p2[o]);
    cumh[row] += rem * haltb[row];
  }
}

// ---------------- base ----------------------------------------------------------
__global__ __launch_bounds__(256)
void base_kernel(const float* __restrict__ x, const float* __restrict__ w,
                 const float* __restrict__ b, float* __restrict__ outp)
{
  int lane = threadIdx.x & 63;
  int row = blockIdx.x * 4 + (threadIdx.x >> 6);
  size_t rb = (size_t)row * IN_D;
  float p[10];
#pragma unroll
  for (int o = 0; o < 10; o++) p[o] = 0.f;
  for (int k = lane; k < IN_D; k += 64){
    float xv = x[rb + k];
#pragma unroll
    for (int o = 0; o < 10; o++) p[o] = fmaf(xv, w[o * IN_D + k], p[o]);
  }
#pragma unroll
  for (int o = 0; o < 10; o++) p[o] = wred(p[o]);
  if (lane == 0){
#pragma unroll
    for (int o = 0; o < 10; o++) outp[row * 10 + o] = p[o] + b[o];
  }
}

// ---------------- shared branch --------------------------------------------------
__global__ __launch_bounds__(256)
void shared_kernel(const float* __restrict__ shpre, const float* __restrict__ sdw,
                   const float* __restrict__ g, const float* __restrict__ b,
                   float* __restrict__ outp)
{
  int lane = threadIdx.x & 63;
  int row = blockIdx.x * 4 + (threadIdx.x >> 6);
  const float* xr = shpre + (size_t)row * SHD;
  float p[10];
#pragma unroll
  for (int o = 0; o < 10; o++) p[o] = 0.f;
  for (int k = lane; k < SHD; k += 64){
    float xv = xr[k];
#pragma unroll
    for (int o = 0; o < 10; o++) p[o] = fmaf(xv, sdw[o * SHD + k], p[o]);
  }
#pragma unroll
  for (int o = 0; o < 10; o++) p[o] = wred(p[o]);
  float mean = 0.f;
#pragma unroll
  for (int o = 0; o < 10; o++) mean += p[o];
  mean *= 0.1f;
  float var = 0.f;
#pragma unroll
  for (int o = 0; o < 10; o++){ float dd = p[o] - mean; var += dd * dd; }
  var *= 0.1f;
  float rs = 1.f / sqrtf(var + 1e-5f);
  if (lane == 0){
#pragma unroll
    for (int o = 0; o < 10; o++) outp[row * 10 + o] = (p[o] - mean) * rs * g[o] + b[o];
  }
}

// ---------------- final output ----------------------------------------------------
__global__ __launch_bounds__(256)
void final_out_kernel(const float* __restrict__ cur, const float* __restrict__ mow,
                      const float* __restrict__ basep, const float* __restrict__ sharedp,
                      const float* __restrict__ total, const float* __restrict__ sscale,
                      const float* __restrict__ alphap, const float* __restrict__ betap,
                      float* __restrict__ outp)
{
  int lane = threadIdx.x & 63;
  int row = blockIdx.x * 4 + (threadIdx.x >> 6);
  size_t rb = (size_t)row * IN_D;
  float p[10];
#pragma unroll
  for (int o = 0; o < 10; o++) p[o] = 0.f;
  for (int k = lane; k < IN_D; k += 64){
    float cv = cur[rb + k];
#pragma unroll
    for (int o = 0; o < 10; o++) p[o] = fmaf(cv, mow[o * IN_D + k], p[o]);
  }
#pragma unroll
  for (int o = 0; o < 10; o++) p[o] = wred(p[o]);
  if (lane == 0){
    float ss = sscale[0], av = alphap[0] + 1e-4f, bv = betap[0];
#pragma unroll
    for (int o = 0; o < 10; o++)
      outp[row * 10 + o] = basep[row * 10 + o] + ss * sharedp[row * 10 + o]
                         + av * (total[row * 10 + o] * 0.25f) + bv * p[o];
  }
}

// ====================================================================================
extern "C" void kernel_launch(void* const* d_in, const int* in_sizes, int n_in,
                              void* d_out, int out_size, void* d_ws, size_t ws_size,
                              hipStream_t stream)
{
  const float* x     = (const float*)d_in[0];
  const float* wgt   = (const float*)d_in[1];
  const float* bias  = (const float*)d_in[2];
  const float* suw   = (const float*)d_in[3];
  const float* sdw   = (const float*)d_in[4];
  const float* sng   = (const float*)d_in[5];
  const float* snb   = (const float*)d_in[6];
  const float* sscale= (const float*)d_in[7];
  const float* keys  = (const float*)d_in[8];
  const float* mvi   = (const float*)d_in[9];
  const float* mqw   = (const float*)d_in[10];
  const float* mow   = (const float*)d_in[11];
  const float* wgw   = (const float*)d_in[12];
  const float* wgb   = (const float*)d_in[13];
  const float* wvw   = (const float*)d_in[14];
  const float* wvb   = (const float*)d_in[15];
  const float* dqw   = (const float*)d_in[16];
  const float* dkw   = (const float*)d_in[17];
  const float* dvw   = (const float*)d_in[18];
  const float* dow   = (const float*)d_in[19];
  const float* clng  = (const float*)d_in[20];
  const float* clnb  = (const float*)d_in[21];
  const float* fc1w  = (const float*)d_in[22];
  const float* fc1b  = (const float*)d_in[23];
  const float* fc2w  = (const float*)d_in[24];
  const float* fc2b  = (const float*)d_in[25];
  const float* saw   = (const float*)d_in[26];
  const float* sab   = (const float*)d_in[27];
  const float* sbw   = (const float*)d_in[28];
  const float* sbb   = (const float*)d_in[29];
  const float* msw   = (const float*)d_in[30];
  const float* msb   = (const float*)d_in[31];
  const float* mmw   = (const float*)d_in[32];
  const float* mmb   = (const float*)d_in[33];
  const float* ebias = (const float*)d_in[34];
  const float* bw    = (const float*)d_in[35];
  const float* bb    = (const float*)d_in[36];
  const float* eup   = (const float*)d_in[37];
  const float* edn   = (const float*)d_in[38];
  const float* eng   = (const float*)d_in[39];
  const float* enb   = (const float*)d_in[40];
  const float* hw    = (const float*)d_in[41];
  const float* hb    = (const float*)d_in[42];
  const float* alphap= (const float*)d_in[43];
  const float* betap = (const float*)d_in[44];
  float* outp = (float*)d_out;

  char* wsb = (char*)d_ws;
  size_t off = 0;
  auto AL = [&](size_t bytes) -> void* {
    void* p = wsb + off;
    off = (off + bytes + 255) & ~(size_t)255;
    return p;
  };
  const size_t NI = (size_t)N_TOK * IN_D;
  float* cur    = (float*)AL(NI * 4);
  float* enr    = (float*)AL(NI * 4);
  float* mqdq   = (float*)AL((size_t)N_TOK * 2048 * 4);
  float* mctx   = (float*)AL(NI * 4);
  float* dctx   = (float*)AL(NI * 4);
  float* t40    = (float*)AL((size_t)N_TOK * 40 * 4);
  float* trio0  = (float*)AL((size_t)N_TOK * 3072 * 4);
  float* trio1  = (float*)AL((size_t)N_TOK * 3072 * 4);
  float* trio2  = (float*)AL((size_t)N_TOK * 3072 * 4);
  float* ubuf   = (float*)AL((size_t)N_TOK * 24 * 4);
  float* sval   = (float*)AL((size_t)N_TOK * 4 * 4);
  float* dval   = (float*)AL((size_t)N_TOK * 4 * 4);
  float* Ac     = (float*)AL((size_t)N_TOK * 24 * 4);
  float* W0     = (float*)AL((size_t)N_TOK * 24 * 4);
  float* W1     = (float*)AL((size_t)N_TOK * 24 * 4);
  float* W2     = (float*)AL((size_t)N_TOK * 24 * 4);
  float* sg     = (float*)AL((size_t)N_TOK * 10 * 4);
  float* haltb  = (float*)AL((size_t)N_TOK * 4);
  // single zeroed region: total | cumh | cnt(4 steps x 16)
  char*  zblk   = (char*)AL((size_t)N_TOK * 10 * 4 + N_TOK * 4 + 4 * 16 * 4);
  float* total  = (float*)zblk;
  float* cumh   = (float*)(zblk + (size_t)N_TOK * 10 * 4);
  int*   cnt    = (int*)(zblk + (size_t)N_TOK * 10 * 4 + N_TOK * 4);
  int*   gidx   = (int*)AL((size_t)NEXP * N_TOK * 4);
  int*   pos    = (int*)AL((size_t)N_TOK * NEXP * 4);
  float* basep  = (float*)AL((size_t)N_TOK * 10 * 4);
  float* sharedp= (float*)AL((size_t)N_TOK * 10 * 4);
  float* cbias  = (float*)AL(3072 * 4);
  // bf16 split activations
  uint16_t* curh = (uint16_t*)AL(NI * 2);
  uint16_t* curl = (uint16_t*)AL(NI * 2);
  uint16_t* lnh  = (uint16_t*)AL(NI * 2);
  uint16_t* lnl  = (uint16_t*)AL(NI * 2);
  uint16_t* h7h  = (uint16_t*)AL((size_t)N_TOK * INNER * 2);
  uint16_t* h7l  = (uint16_t*)AL((size_t)N_TOK * INNER * 2);
  // bf16 split weights
  const size_t W1M = (size_t)IN_D * IN_D;
  uint16_t* prewh  = (uint16_t*)AL(3 * W1M * 2); uint16_t* prewl  = (uint16_t*)AL(3 * W1M * 2);
  uint16_t* qtriowh= (uint16_t*)AL(5 * W1M * 2); uint16_t* qtriowl= (uint16_t*)AL(5 * W1M * 2);
  const size_t WFC = (size_t)NSTEP * INNER * IN_D;
  uint16_t* fc1wh = (uint16_t*)AL(WFC * 2); uint16_t* fc1wl = (uint16_t*)AL(WFC * 2);
  uint16_t* fc2wh = (uint16_t*)AL(WFC * 2); uint16_t* fc2wl = (uint16_t*)AL(WFC * 2);
  // big buffers
  uint16_t* upbf  = (uint16_t*)AL((size_t)NEXP * DMAX * IN_D * 2);
  uint16_t* HHc   = (uint16_t*)AL((size_t)N_TOK * DSUM * 2);
  float* shpre  = (float*)HHc;   // alias: consumed before HHc is written

  // ---- init ----
  hipMemsetAsync(zblk, 0, (size_t)N_TOK * 10 * 4 + N_TOK * 4 + 4 * 16 * 4, stream);
  hipMemsetAsync(cbias, 0, 3072 * 4, stream);
  hipMemcpyAsync(cbias + 2048, wvb, 1024 * 4, hipMemcpyDeviceToDevice, stream);
  hipMemcpyAsync(cur, x, NI * 4, hipMemcpyDeviceToDevice, stream);
  fill1_kernel<<<(N_TOK * 24 + 255) / 256, 256, 0, stream>>>(Ac, N_TOK * 24);
  cvt_bf16_kernel<<<2048, 256, 0, stream>>>(eup, upbf, (size_t)NEXP * DMAX * IN_D);
  // weight splits: prew = [mqw; suw], qtriow = [mqw; dqw; dkw; dvw; wvw]
  split_kernel<<<1024, 256, 0, stream>>>(mqw, prewh, prewl, W1M);
  split_kernel<<<1024, 256, 0, stream>>>(suw, prewh + W1M, prewl + W1M, 2 * W1M);
  split_kernel<<<1024, 256, 0, stream>>>(mqw, qtriowh, qtriowl, W1M);
  split_kernel<<<1024, 256, 0, stream>>>(dqw, qtriowh + W1M, qtriowl + W1M, W1M);
  split_kernel<<<1024, 256, 0, stream>>>(dkw, qtriowh + 2*W1M, qtriowl + 2*W1M, W1M);
  split_kernel<<<1024, 256, 0, stream>>>(dvw, qtriowh + 3*W1M, qtriowl + 3*W1M, W1M);
  split_kernel<<<1024, 256, 0, stream>>>(wvw, qtriowh + 4*W1M, qtriowl + 4*W1M, W1M);
  split_kernel<<<1024, 256, 0, stream>>>(fc1w, fc1wh, fc1wl, WFC);
  split_kernel<<<1024, 256, 0, stream>>>(fc2w, fc2wh, fc2wl, WFC);
  split_kernel<<<1024, 256, 0, stream>>>(x, curh, curl, NI);

  base_kernel<<<512, 256, 0, stream>>>(x, wgt, bias, basep);
  // preamble GEMM: [mq | silu(shared_up)] D=3072, split=1024
  gemm_sp<EPI_DUAL_PRE><<<dim3(24, 16), 256, 0, stream>>>(
      curh, curl, prewh, prewl, nullptr, nullptr,
      mqdq, shpre, nullptr, nullptr, IN_D, 3072, 2048, 2048, 1024);
  shared_kernel<<<512, 256, 0, stream>>>(shpre, sdw, sng, snb, sharedp);

  float* trioB[3] = {trio0, trio1, trio2};

  for (int t = 0; t < NSTEP; t++){
    rowred_kernel<<<512, 256, 0, stream>>>(mqdq, keys, Ac, W0, W1, W2, cur, saw, sab,
                                           trio0, trio1, trio2, ubuf, sval, dval, t40, t);
    ctx_enr_kernel<<<2048, 256, 0, stream>>>(ubuf, sval, dval, mvi, trio0, trio1, trio2,
                                             cur, t40, sbw, sbb, clng, clnb,
                                             mctx, dctx, enr, lnh, lnl, t);
    gemm_sp<EPI_GELU_BIAS><<<dim3(INNER/128, 16), 256, 0, stream>>>(
        lnh, lnl, fc1wh + (size_t)t * INNER * IN_D, fc1wl + (size_t)t * INNER * IN_D,
        fc1b + t * INNER, nullptr, nullptr, nullptr, h7h, h7l, IN_D, INNER, 0, 0, 0);
    gemm_sp<EPI_ADD_BIAS><<<dim3(8, 16), 256, 0, stream>>>(
        h7h, h7l, fc2wh + (size_t)t * IN_D * INNER, fc2wl + (size_t)t * IN_D * INNER,
        fc2b + t * IN_D, enr, cur, nullptr, curh, curl, INNER, IN_D, 0, 0, 0);
    routing_kernel<<<512, 256, 0, stream>>>(cur, mctx, dctx, msw, msb, mmw, mmb, ebias,
                                            bw, bb, wgw, wgb, hw, hb,
                                            sg, haltb, Ac, W0, W1, W2,
                                            cnt + t * 16, gidx, pos, t);
    expert_up_mfma<<<dim3(8, 188), 512, 0, stream>>>(curh, upbf, cnt + t * 16, gidx, HHc);
    downfin_kernel<<<512, 256, 0, stream>>>(HHc, pos, edn, sg, eng, enb,
                                            mctx, dctx, mow, dow, haltb, total, cumh);
    // next-step q projections + this step's bank trio: [mq|dq | k|v|wv]
    if (t < 3)
      gemm_sp<EPI_DUAL_QTRIO><<<dim3(40, 16), 256, 0, stream>>>(
          curh, curl, qtriowh, qtriowl, cbias, nullptr,
          mqdq, trioB[t], nullptr, nullptr, IN_D, 5120, 2048, 3072, 2048);
  }
  final_out_kernel<<<512, 256, 0, stream>>>(cur, mow, basep, sharedp, total, sscale,
                                            alphap, betap, outp);
}

// Round 6
// 4295.605 us; speedup vs baseline: 1.0673x; 1.0673x over previous
//
#include <hip/hip_runtime.h>
#include <stdint.h>

#define N_TOK 2048
#define IN_D  1024
#define NEXP  10
#define NSTEP 4
#define INNER 768
#define SHD   2048
#define DMAX  3328
#define DSUM  24064

typedef __attribute__((ext_vector_type(4))) float f32x4;
typedef __attribute__((ext_vector_type(8))) short bf16x8;

__device__ const int c_dims[10] = {1536,2048,2560,3072,1792,2304,2816,2048,2560,3328};
__device__ const int c_offs[10] = {0,1536,3584,6144,9216,11008,13312,16128,18176,20736};
__device__ const int c_acts[10] = {0,1,2,3,4,5,6,7,0,1};
__device__ const int c_cum[11]  = {0,12,28,48,72,86,104,126,142,162,188};

__device__ __forceinline__ float wred(float v){
#pragma unroll
  for (int s = 32; s > 0; s >>= 1) v += __shfl_xor(v, s, 64);
  return v;
}
__device__ __forceinline__ float bf2f(uint16_t u){
  return __uint_as_float(((uint32_t)u) << 16);
}
__device__ __forceinline__ uint16_t f2bf(float f){
  uint32_t u = __float_as_uint(f);
  return (uint16_t)((u + 0x7FFFu + ((u >> 16) & 1u)) >> 16);
}
__device__ __forceinline__ void gload16(const uint16_t* g, uint16_t* l){
  __builtin_amdgcn_global_load_lds(
      (const __attribute__((address_space(1))) uint32_t*)(const void*)g,
      (__attribute__((address_space(3))) uint32_t*)(void*)l, 16, 0, 0);
}

__device__ __forceinline__ float actf(int a, float x){
  switch(a){
    case 0: return x / (1.f + expf(-x));
    case 1: return 0.5f * x * (1.f + erff(x * 0.7071067811865475f));
    case 2: { float sp = fmaxf(x,0.f) + log1pf(expf(-fabsf(x)));
              return x * tanhf(sp); }
    case 3: return fmaxf(x, 0.f);
    case 4: return x > 0.f ? 1.0507009873554805f * x
                           : 1.7580993408473768f * expm1f(x);
    case 5: return tanhf(x);
    case 6: return fmaxf(x,0.f) + log1pf(expf(-fabsf(x)));
    default: return x > 0.f ? x : expm1f(x);
  }
}

// ---------------- f32 -> (hi, lo) bf16 split -----------------------------------
__global__ void split_kernel(const float* __restrict__ src, uint16_t* __restrict__ hi,
                             uint16_t* __restrict__ lo, size_t n){
  size_t i = ((size_t)blockIdx.x * blockDim.x + threadIdx.x) << 2;
  size_t stride = ((size_t)gridDim.x * blockDim.x) << 2;
  for (; i < n; i += stride){
    float4 v = *(const float4*)(src + i);
    ushort4 h, l;
    h.x = f2bf(v.x); l.x = f2bf(v.x - bf2f(h.x));
    h.y = f2bf(v.y); l.y = f2bf(v.y - bf2f(h.y));
    h.z = f2bf(v.z); l.z = f2bf(v.z - bf2f(h.z));
    h.w = f2bf(v.w); l.w = f2bf(v.w - bf2f(h.w));
    *(ushort4*)(hi + i) = h;
    *(ushort4*)(lo + i) = l;
  }
}
__global__ void cvt_bf16_kernel(const float* __restrict__ src, uint16_t* __restrict__ dst, size_t n){
  size_t i = ((size_t)blockIdx.x * blockDim.x + threadIdx.x) << 2;
  size_t stride = ((size_t)gridDim.x * blockDim.x) << 2;
  for (; i < n; i += stride){
    float4 v = *(const float4*)(src + i);
    ushort4 h;
    h.x = f2bf(v.x); h.y = f2bf(v.y); h.z = f2bf(v.z); h.w = f2bf(v.w);
    *(ushort4*)(dst + i) = h;
  }
}
__global__ void fill1_kernel(float* __restrict__ p, int n){
  int i = blockIdx.x * blockDim.x + threadIdx.x;
  if (i < n) p[i] = 1.f;
}

// ---------------- split-bf16 MFMA GEMM, 2-phase dbuf, chunk-major LDS ----------
// C = epi(A @ W^T). A=(Ah,Al)[N,K], W=(Wh,Wl)[D,K]. 128x128 tile, BK=32.
enum { EPI_GELU_BIAS=0, EPI_ADD_BIAS=1, EPI_DUAL_PRE=2, EPI_DUAL_QTRIO=3 };

template<int EPI>
__global__ __launch_bounds__(256)
void gemm_sp(const uint16_t* __restrict__ Ah, const uint16_t* __restrict__ Al,
             const uint16_t* __restrict__ Wh, const uint16_t* __restrict__ Wl,
             const float* __restrict__ bias, const float* __restrict__ addend,
             float* __restrict__ C, float* __restrict__ C2,
             uint16_t* __restrict__ outH, uint16_t* __restrict__ outL,
             int K, int D, int ld1, int ld2, int split)
{
  // [tensor Ah,Al,Wh,Wl][buf][128 rows x 4 chunks of 16B, chunk-major]
  __shared__ __align__(16) uint16_t sm[4][2][4096];
  int tid = threadIdx.x, lane = tid & 63, wave = tid >> 6;
  int wr = wave >> 1, wc = wave & 1;
  int arow = lane & 15, agrp = lane >> 4;
  int rowBase = blockIdx.y * 128, colBase = blockIdx.x * 128;
  f32x4 acc[4][4];
#pragma unroll
  for (int m = 0; m < 4; m++)
#pragma unroll
    for (int n = 0; n < 4; n++){ f32x4 z = {0.f,0.f,0.f,0.f}; acc[m][n] = z; }

#define STAGE_G(buf, k0) do { \
  _Pragma("unroll") \
  for (int s = 0; s < 2; s++){ \
    int u = tid + s * 256; \
    int rr = u & 127, ch = u >> 7; \
    size_t ga = (size_t)(rowBase + rr) * K + (k0) + ch * 8; \
    size_t gw = (size_t)(colBase + rr) * K + (k0) + ch * 8; \
    gload16(&Ah[ga], &sm[0][buf][u << 3]); \
    gload16(&Al[ga], &sm[1][buf][u << 3]); \
    gload16(&Wh[gw], &sm[2][buf][u << 3]); \
    gload16(&Wl[gw], &sm[3][buf][u << 3]); \
  } } while(0)

  STAGE_G(0, 0);
  __syncthreads();
  int nk = K >> 5;
  for (int ki = 0; ki < nk; ki++){
    int cb = ki & 1;
    if (ki + 1 < nk) STAGE_G(cb ^ 1, (ki + 1) << 5);
    bf16x8 ah[4], al[4], bh[4], bl[4];
#pragma unroll
    for (int m = 0; m < 4; m++){
      int u = (agrp << 7) + wr*64 + m*16 + arow;   // chunk-major unit
      ah[m] = *(const bf16x8*)&sm[0][cb][u << 3];
      al[m] = *(const bf16x8*)&sm[1][cb][u << 3];
    }
#pragma unroll
    for (int n = 0; n < 4; n++){
      int u = (agrp << 7) + wc*64 + n*16 + arow;
      bh[n] = *(const bf16x8*)&sm[2][cb][u << 3];
      bl[n] = *(const bf16x8*)&sm[3][cb][u << 3];
    }
#pragma unroll
    for (int m = 0; m < 4; m++)
#pragma unroll
      for (int n = 0; n < 4; n++){
        acc[m][n] = __builtin_amdgcn_mfma_f32_16x16x32_bf16(ah[m], bh[n], acc[m][n], 0, 0, 0);
        acc[m][n] = __builtin_amdgcn_mfma_f32_16x16x32_bf16(ah[m], bl[n], acc[m][n], 0, 0, 0);
        acc[m][n] = __builtin_amdgcn_mfma_f32_16x16x32_bf16(al[m], bh[n], acc[m][n], 0, 0, 0);
      }
    __syncthreads();
  }
#undef STAGE_G
#pragma unroll
  for (int m = 0; m < 4; m++){
#pragma unroll
    for (int n = 0; n < 4; n++){
      int col = colBase + wc*64 + n*16 + arow;
#pragma unroll
      for (int r2 = 0; r2 < 4; r2++){
        int row = rowBase + wr*64 + m*16 + agrp*4 + r2;
        float v = acc[m][n][r2];
        if (EPI == EPI_GELU_BIAS){
          v += bias[col];
          v = 0.5f * v * (1.f + erff(v * 0.7071067811865475f));
          size_t idx = (size_t)row * D + col;
          uint16_t h = f2bf(v);
          outH[idx] = h; outL[idx] = f2bf(v - bf2f(h));
        }
        if (EPI == EPI_ADD_BIAS){
          v += bias[col] + addend[(size_t)row * D + col];
          size_t idx = (size_t)row * D + col;
          C[idx] = v;
          uint16_t h = f2bf(v);
          outH[idx] = h; outL[idx] = f2bf(v - bf2f(h));
        }
        if (EPI == EPI_DUAL_PRE){
          if (col < split) C[(size_t)row * ld1 + col] = v;
          else C2[(size_t)row * ld2 + (col - split)] = v / (1.f + expf(-v));
        }
        if (EPI == EPI_DUAL_QTRIO){
          if (col < split) C[(size_t)row * ld1 + col] = v;
          else C2[(size_t)row * ld2 + (col - split)] = v + bias[col - split];
        }
      }
    }
  }
}

// ---------------- sparse expert up: 128x128 tile, 4 waves, BK=32, 2-phase dbuf --
__global__ __launch_bounds__(256)
void expert_up_mfma(const uint16_t* __restrict__ Abf, const uint16_t* __restrict__ Ubf,
                    const int* __restrict__ cnt, const int* __restrict__ gidx,
                    uint16_t* __restrict__ HH)
{
  // decode (e, ct) from blockIdx.y via cumulative tile table
  int y = blockIdx.y;
  int e = 0;
#pragma unroll
  for (int i = 1; i < 11; i++) if (y >= c_cum[i]) e = i;
  int ct = y - c_cum[e];
  int dcols = c_dims[e];
  int ne = cnt[e];
  int rowBase = blockIdx.x * 128;
  if (rowBase >= ne) return;
  const uint16_t* W = Ubf + (size_t)e * DMAX * IN_D + (size_t)ct * 128 * IN_D;

  // 32KB total: sA dbuf (16KB) | sB dbuf (16KB); reused as Ht (32KB) in epilogue
  __shared__ __align__(16) uint16_t smem[16384];
  uint16_t* sA = smem;          // [2][512 units] chunk-major
  uint16_t* sB = smem + 8192;
  int tid = threadIdx.x, lane = tid & 63, wave = tid >> 6;
  int wr = wave >> 1, wc = wave & 1;
  int arow = lane & 15, agrp = lane >> 4;

  // A stage rows: u&127 == tid&127 for both s -> one token per thread
  int slot = rowBase + (tid & 127);
  int tok = (slot < ne) ? gidx[e * N_TOK + slot] : 0;

  f32x4 acc[4][4];
#pragma unroll
  for (int m = 0; m < 4; m++)
#pragma unroll
    for (int n = 0; n < 4; n++){ f32x4 z = {0.f,0.f,0.f,0.f}; acc[m][n] = z; }

#define STAGE_E(buf, k0) do { \
  _Pragma("unroll") \
  for (int s = 0; s < 2; s++){ \
    int u = tid + s * 256; \
    int rr = u & 127, ch = u >> 7; \
    gload16(&Abf[(size_t)tok * IN_D + (k0) + ch * 8], &sA[((buf) * 512 + u) << 3]); \
    gload16(&W[(size_t)rr * IN_D + (k0) + ch * 8],   &sB[((buf) * 512 + u) << 3]); \
  } } while(0)

  STAGE_E(0, 0);
  __syncthreads();
#pragma unroll 1
  for (int ki = 0; ki < 32; ki++){
    int cb = ki & 1;
    if (ki + 1 < 32) STAGE_E(cb ^ 1, (ki + 1) << 5);
    bf16x8 a[4], b[4];
#pragma unroll
    for (int m = 0; m < 4; m++){
      int u = cb * 512 + (agrp << 7) + wr*64 + m*16 + arow;
      a[m] = *(const bf16x8*)&sA[u << 3];
    }
#pragma unroll
    for (int n = 0; n < 4; n++){
      int u = cb * 512 + (agrp << 7) + wc*64 + n*16 + arow;
      b[n] = *(const bf16x8*)&sB[u << 3];
    }
#pragma unroll
    for (int m = 0; m < 4; m++)
#pragma unroll
      for (int n = 0; n < 4; n++)
        acc[m][n] = __builtin_amdgcn_mfma_f32_16x16x32_bf16(a[m], b[n], acc[m][n], 0, 0, 0);
    __syncthreads();
  }
#undef STAGE_E
  // epilogue: activation -> swizzled LDS tile -> coalesced 16B stores
  int actid = c_acts[e];
  uint16_t* Ht = smem;
#pragma unroll
  for (int m = 0; m < 4; m++){
    int rb0 = wr*64 + m*16 + agrp*4;
#pragma unroll
    for (int n = 0; n < 4; n++){
      int col = wc*64 + n*16 + arow;
#pragma unroll
      for (int r2 = 0; r2 < 4; r2++){
        int row = rb0 + r2;
        float v = actf(actid, acc[m][n][r2]);
        Ht[row * 128 + (col ^ ((row & 7) << 3))] = f2bf(v);
      }
    }
  }
  __syncthreads();
  size_t base_e = (size_t)N_TOK * c_offs[e];
#pragma unroll
  for (int i = 0; i < 8; i++){
    int c = tid + i * 256;
    int row = c >> 4, chunk = c & 15;
    int schunk = (chunk & 8) | ((chunk ^ row) & 7);
    int4 val = *(const int4*)&Ht[row * 128 + schunk * 8];
    *(int4*)&HH[base_e + (size_t)(rowBase + row) * dcols
                + (size_t)ct * 128 + chunk * 8] = val;
  }
}

// ---------------- rowred: mem scores+softmax, depth softmax, ssm_a -------------
__global__ __launch_bounds__(256)
void rowred_kernel(const float* __restrict__ qout, const float* __restrict__ keys,
                   const float* __restrict__ Ac, const float* __restrict__ W0,
                   const float* __restrict__ W1, const float* __restrict__ W2,
                   const float* __restrict__ cur, const float* __restrict__ saw,
                   const float* __restrict__ sab,
                   const float* __restrict__ t0, const float* __restrict__ t1,
                   const float* __restrict__ t2,
                   float* __restrict__ ubuf, float* __restrict__ sval,
                   float* __restrict__ dval, float* __restrict__ t40, int t)
{
  int lane = threadIdx.x & 63;
  int row = blockIdx.x * 4 + (threadIdx.x >> 6);
  size_t qb = (size_t)row * 2048;
  size_t rb = (size_t)row * IN_D;
  size_t tb = (size_t)row * 3072;
  float p[24], ps[40];
  float a0 = 0.f, a1 = 0.f, a2 = 0.f;
#pragma unroll
  for (int m = 0; m < 24; m++) p[m] = 0.f;
#pragma unroll
  for (int o = 0; o < 40; o++) ps[o] = 0.f;
  for (int k = lane; k < IN_D; k += 64){
    float qv = qout[qb + k];
    float cv = cur[rb + k];
#pragma unroll
    for (int m = 0; m < 24; m++) p[m] = fmaf(qv, keys[m * IN_D + k], p[m]);
#pragma unroll
    for (int o = 0; o < 40; o++) ps[o] = fmaf(cv, saw[o * IN_D + k], ps[o]);
    if (t > 0){
      float dqv = qout[qb + 1024 + k];
      a0 = fmaf(dqv, t0[tb + k], a0);
      if (t > 1) a1 = fmaf(dqv, t1[tb + k], a1);
      if (t > 2) a2 = fmaf(dqv, t2[tb + k], a2);
    }
  }
#pragma unroll
  for (int m = 0; m < 24; m++) p[m] = wred(p[m]) * 0.03125f;
#pragma unroll
  for (int o = 0; o < 40; o++) ps[o] = wred(ps[o]);
  // memory softmax + history coefficients
  float mx = p[0];
#pragma unroll
  for (int m = 1; m < 24; m++) mx = fmaxf(mx, p[m]);
  float s = 0.f;
#pragma unroll
  for (int m = 0; m < 24; m++){ p[m] = expf(p[m] - mx); s += p[m]; }
  float inv = 1.f / s;
  float s0 = 0.f, s1 = 0.f, s2 = 0.f;
#pragma unroll
  for (int m = 0; m < 24; m++){
    float a = p[m] * inv;
    p[m] = a;
    if (t > 0) s0 = fmaf(a, W0[row * 24 + m], s0);
    if (t > 1) s1 = fmaf(a, W1[row * 24 + m], s1);
    if (t > 2) s2 = fmaf(a, W2[row * 24 + m], s2);
  }
  // depth softmax
  float e0 = 0.f, e1 = 0.f, e2 = 0.f;
  if (t > 0){
    a0 = wred(a0) * 0.03125f; a1 = wred(a1) * 0.03125f; a2 = wred(a2) * 0.03125f;
    float dmx = a0;
    if (t > 1) dmx = fmaxf(dmx, a1);
    if (t > 2) dmx = fmaxf(dmx, a2);
    e0 = expf(a0 - dmx);
    e1 = (t > 1) ? expf(a1 - dmx) : 0.f;
    e2 = (t > 2) ? expf(a2 - dmx) : 0.f;
    float dinv = 1.f / (e0 + e1 + e2);
    e0 *= dinv; e1 *= dinv; e2 *= dinv;
  }
  if (lane == 0){
#pragma unroll
    for (int m = 0; m < 24; m++) ubuf[row * 24 + m] = p[m] * Ac[row * 24 + m];
    sval[row * 4 + 0] = s0; sval[row * 4 + 1] = s1; sval[row * 4 + 2] = s2;
    dval[row * 4 + 0] = e0; dval[row * 4 + 1] = e1; dval[row * 4 + 2] = e2;
#pragma unroll
    for (int o = 0; o < 40; o++) t40[row * 40 + o] = tanhf(ps[o] + sab[o]);
  }
}

// ---------------- ctx_enr: mctx + dctx + ssm_b + enriched + LN + split ---------
__global__ __launch_bounds__(256)
void ctx_enr_kernel(const float* __restrict__ ubuf, const float* __restrict__ sval,
                    const float* __restrict__ dval, const float* __restrict__ mvi,
                    const float* __restrict__ t0, const float* __restrict__ t1,
                    const float* __restrict__ t2, const float* __restrict__ cur,
                    const float* __restrict__ t40, const float* __restrict__ sbw,
                    const float* __restrict__ sbb, const float* __restrict__ lng,
                    const float* __restrict__ lnbv, float* __restrict__ mctx,
                    float* __restrict__ dctx, float* __restrict__ enr,
                    uint16_t* __restrict__ lnh, uint16_t* __restrict__ lnl, int t)
{
  int row = blockIdx.x;
  int tid = threadIdx.x;
  __shared__ float su[24], ss[3], de[3], s40[40], red[8];
  if (tid < 24) su[tid] = ubuf[row * 24 + tid];
  if (tid >= 32 && tid < 35) ss[tid - 32] = sval[row * 4 + (tid - 32)];
  if (tid >= 64 && tid < 67) de[tid - 64] = dval[row * 4 + (tid - 64)];
  if (tid >= 96 && tid < 136) s40[tid - 96] = t40[row * 40 + (tid - 96)];
  __syncthreads();
  size_t tb = (size_t)row * 3072;
  float ev[4];
  float part = 0.f;
#pragma unroll
  for (int j = 0; j < 4; j++){
    int d = tid + j * 256;
    size_t idx = (size_t)row * IN_D + d;
    float mv = 0.f;
#pragma unroll
    for (int m = 0; m < 24; m++) mv = fmaf(su[m], mvi[m * IN_D + d], mv);
    float dv = 0.f;
    if (t > 0){
      mv = fmaf(ss[0], t0[tb + 2048 + d], mv);
      dv = de[0] * t0[tb + 1024 + d];
      if (t > 1){ mv = fmaf(ss[1], t1[tb + 2048 + d], mv); dv = fmaf(de[1], t1[tb + 1024 + d], dv); }
      if (t > 2){ mv = fmaf(ss[2], t2[tb + 2048 + d], mv); dv = fmaf(de[2], t2[tb + 1024 + d], dv); }
    }
    float sv = sbb[d];
#pragma unroll
    for (int o = 0; o < 40; o++) sv = fmaf(s40[o], sbw[d * 40 + o], sv);
    float v = cur[idx] + 0.34f * mv + 0.22f * dv + 0.18f * sv;
    mctx[idx] = mv;
    dctx[idx] = dv;
    ev[j] = v; part += v;
  }
  part = wred(part);
  if ((tid & 63) == 0) red[tid >> 6] = part;
  __syncthreads();
  float mean = (red[0] + red[1] + red[2] + red[3]) * (1.f / 1024.f);
  float vp = 0.f;
#pragma unroll
  for (int j = 0; j < 4; j++){ float dd = ev[j] - mean; vp += dd * dd; }
  vp = wred(vp);
  if ((tid & 63) == 0) red[4 + (tid >> 6)] = vp;
  __syncthreads();
  float var = (red[4] + red[5] + red[6] + red[7]) * (1.f / 1024.f);
  float rs = 1.f / sqrtf(var + 1e-5f);
#pragma unroll
  for (int j = 0; j < 4; j++){
    int d = tid + j * 256;
    size_t idx = (size_t)row * IN_D + d;
    enr[idx] = ev[j];
    float v = (ev[j] - mean) * rs * lng[t * IN_D + d] + lnbv[t * IN_D + d];
    uint16_t h = f2bf(v);
    lnh[idx] = h;
    lnl[idx] = f2bf(v - bf2f(h));
  }
}

// ---------------- routing + compaction ------------------------------------------
__global__ __launch_bounds__(256)
void routing_kernel(const float* __restrict__ cur, const float* __restrict__ mctx,
                    const float* __restrict__ dctx,
                    const float* __restrict__ msw, const float* __restrict__ msb,
                    const float* __restrict__ mmw, const float* __restrict__ mmb,
                    const float* __restrict__ ebias,
                    const float* __restrict__ bw, const float* __restrict__ bb,
                    const float* __restrict__ wgw, const float* __restrict__ wgb,
                    const float* __restrict__ hw, const float* __restrict__ hb,
                    float* __restrict__ sg, float* __restrict__ haltb,
                    float* __restrict__ Ac, float* __restrict__ W0,
                    float* __restrict__ W1, float* __restrict__ W2,
                    int* __restrict__ cnt, int* __restrict__ gidx,
                    int* __restrict__ pos, int t)
{
  int lane = threadIdx.x & 63;
  int row = blockIdx.x * 4 + (threadIdx.x >> 6);
  size_t rb = (size_t)row * IN_D;
  float ps[40], pw[24], pm[4], pb[4], ph = 0.f;
#pragma unroll
  for (int o = 0; o < 40; o++) ps[o] = 0.f;
#pragma unroll
  for (int m = 0; m < 24; m++) pw[m] = 0.f;
#pragma unroll
  for (int o = 0; o < 4; o++){ pm[o] = 0.f; pb[o] = 0.f; }
  const float* hwt = hw + t * IN_D;
  for (int k = lane; k < IN_D; k += 64){
    float cv = cur[rb + k], mv = mctx[rb + k], dv = dctx[rb + k];
#pragma unroll
    for (int o = 0; o < 40; o++) ps[o] = fmaf(cv, msw[o * IN_D + k], ps[o]);
#pragma unroll
    for (int o = 0; o < 4; o++) pm[o] = fmaf(cv, mmw[o * IN_D + k], pm[o]);
#pragma unroll
    for (int o = 0; o < 4; o++) pb[o] = fmaf(cv, bw[o * IN_D + k], pb[o]);
#pragma unroll
    for (int m = 0; m < 24; m++){
      float t1v = fmaf(cv, wgw[m * 2048 + k], pw[m]);
      pw[m] = fmaf(mv, wgw[m * 2048 + 1024 + k], t1v);
    }
    ph = fmaf(cv + 0.2f * mv + 0.1f * dv, hwt[k], ph);
  }
#pragma unroll
  for (int o = 0; o < 40; o++) ps[o] = wred(ps[o]);
#pragma unroll
  for (int m = 0; m < 24; m++) pw[m] = wred(pw[m]);
#pragma unroll
  for (int o = 0; o < 4; o++){ pm[o] = wred(pm[o]); pb[o] = wred(pb[o]); }
  ph = wred(ph);

#pragma unroll
  for (int o = 0; o < 4; o++) pm[o] += mmb[o];
  float mmx = fmaxf(fmaxf(pm[0], pm[1]), fmaxf(pm[2], pm[3]));
  float msum = 0.f;
#pragma unroll
  for (int o = 0; o < 4; o++){ pm[o] = expf(pm[o] - mmx); msum += pm[o]; }
  float minv = 1.f / msum;
  float gl[10];
#pragma unroll
  for (int e = 0; e < 10; e++){
    float g = ebias[e];
#pragma unroll
    for (int s2 = 0; s2 < 4; s2++) g = fmaf(pm[s2] * minv, ps[s2 * 10 + e] + msb[s2 * 10 + e], g);
    gl[e] = g;
  }
  float gmx = gl[0];
#pragma unroll
  for (int e = 1; e < 10; e++) gmx = fmaxf(gmx, gl[e]);
  float gs = 0.f;
#pragma unroll
  for (int e = 0; e < 10; e++){ gl[e] = expf(gl[e] - gmx); gs += gl[e]; }
  float ginv = 1.f / gs;
#pragma unroll
  for (int e = 0; e < 10; e++) gl[e] *= ginv;
#pragma unroll
  for (int o = 0; o < 4; o++) pb[o] += bb[o];
  int bud = 1; float bbest = pb[0];
  if (pb[1] > bbest){ bbest = pb[1]; bud = 2; }
  if (pb[2] > bbest){ bbest = pb[2]; bud = 3; }
  if (pb[3] > bbest){ bbest = pb[3]; bud = 4; }
  float tv[4]; int ti[4]; unsigned used = 0;
#pragma unroll
  for (int j = 0; j < 4; j++){
    float best = -1e30f; int bi = 0;
#pragma unroll
    for (int e = 0; e < 10; e++){
      bool ok = (!((used >> e) & 1u)) && (gl[e] > best);
      if (ok){ best = gl[e]; bi = e; }
    }
    tv[j] = best; ti[j] = bi; used |= (1u << bi);
  }
  float ssum = tv[0];
  if (bud > 1) ssum += tv[1];
  if (bud > 2) ssum += tv[2];
  if (bud > 3) ssum += tv[3];
  float den = fmaxf(ssum, 1e-6f);
  float sup = 1.f - tv[0] / den;
#pragma unroll
  for (int m = 0; m < 24; m++) pw[m] += wgb[m];
  float wmx = pw[0];
#pragma unroll
  for (int m = 1; m < 24; m++) wmx = fmaxf(wmx, pw[m]);
  float wsum = 0.f;
#pragma unroll
  for (int m = 0; m < 24; m++){ pw[m] = expf(pw[m] - wmx); wsum += pw[m]; }
  float winv = 1.f / wsum;
  float hv = 1.f / (1.f + expf(-(ph + hb[t])));

  if (lane == 0){
#pragma unroll
    for (int e = 0; e < 10; e++){
      float sv = 0.f;
#pragma unroll
      for (int j = 0; j < 4; j++) if (j < bud && ti[j] == e) sv = tv[j] / den;
      sg[row * 10 + e] = sv;
      if (sv != 0.f){
        int slot = atomicAdd(&cnt[e], 1);
        gidx[e * N_TOK + slot] = row;
        pos[row * 10 + e] = slot;
      }
    }
    haltb[row] = hv;
#pragma unroll
    for (int m = 0; m < 24; m++){
      float c = sup * pw[m] * winv;
      float om = 1.f - c;
      Ac[row * 24 + m] *= om;
      if (t > 0) W0[row * 24 + m] *= om;
      if (t > 1) W1[row * 24 + m] *= om;
      if (t > 2) W2[row * 24 + m] *= om;
      if (t == 0)      W0[row * 24 + m] = c;
      else if (t == 1) W1[row * 24 + m] = c;
      else if (t == 2) W2[row * 24 + m] = c;
    }
  }
}

// ---------------- downfin: expert down + LN + gated acc + step finalize --------
__global__ __launch_bounds__(256)
void downfin_kernel(const uint16_t* __restrict__ HH, const int* __restrict__ pos,
                    const float* __restrict__ ED, const float* __restrict__ sg,
                    const float* __restrict__ eng, const float* __restrict__ enb,
                    const float* __restrict__ mctx, const float* __restrict__ dctx,
                    const float* __restrict__ mow, const float* __restrict__ dow,
                    const float* __restrict__ haltb, float* __restrict__ total,
                    float* __restrict__ cumh)
{
  int lane = threadIdx.x & 63;
  int row = blockIdx.x * 4 + (threadIdx.x >> 6);
  float out[10] = {};
  for (int e = 0; e < NEXP; e++){
    float g = sg[row * 10 + e];
    if (g != 0.0f){
      int d = c_dims[e];
      int slot = pos[row * 10 + e];
      const uint16_t* hr = HH + (size_t)N_TOK * c_offs[e] + (size_t)slot * d;
      const float* wd = ED + (size_t)e * 10 * DMAX;
      float p[10] = {};
      for (int k = lane * 2; k < d; k += 128){
        uint32_t hv2 = *(const uint32_t*)&hr[k];
        float h0 = bf2f((uint16_t)hv2), h1 = bf2f((uint16_t)(hv2 >> 16));
#pragma unroll
        for (int o = 0; o < 10; o++){
          float2 w2 = *(const float2*)&wd[o * DMAX + k];
          p[o] = fmaf(h0, w2.x, fmaf(h1, w2.y, p[o]));
        }
      }
#pragma unroll
      for (int o = 0; o < 10; o++) p[o] = wred(p[o]);
      float mean = 0.f;
#pragma unroll
      for (int o = 0; o < 10; o++) mean += p[o];
      mean *= 0.1f;
      float var = 0.f;
#pragma unroll
      for (int o = 0; o < 10; o++){ float dd = p[o] - mean; var += dd * dd; }
      var *= 0.1f;
      float rs = 1.f / sqrtf(var + 1e-5f);
#pragma unroll
      for (int o = 0; o < 10; o++)
        out[o] += g * ((p[o] - mean) * rs * eng[e * 10 + o] + enb[e * 10 + o]);
    }
  }
  // mem/depth output projections
  size_t rb = (size_t)row * IN_D;
  float p1[10], p2[10];
#pragma unroll
  for (int o = 0; o < 10; o++){ p1[o] = 0.f; p2[o] = 0.f; }
  for (int k = lane; k < IN_D; k += 64){
    float mv = mctx[rb + k], dv = dctx[rb + k];
#pragma unroll
    for (int o = 0; o < 10; o++){
      p1[o] = fmaf(mv, mow[o * IN_D + k], p1[o]);
      p2[o] = fmaf(dv, dow[o * IN_D + k], p2[o]);
    }
  }
#pragma unroll
  for (int o = 0; o < 10; o++){ p1[o] = wred(p1[o]); p2[o] = wred(p2[o]); }
  if (lane == 0){
    float rem = 1.f - cumh[row];
#pragma unroll
    for (int o = 0; o < 10; o++)
      total[row * 10 + o] += rem * (out[o] + 0.22f * p1[o] + 0.14f * p2[o]);
    cumh[row] += rem * haltb[row];
  }
}

// ---------------- base ----------------------------------------------------------
__global__ __launch_bounds__(256)
void base_kernel(const float* __restrict__ x, const float* __restrict__ w,
                 const float* __restrict__ b, float* __restrict__ outp)
{
  int lane = threadIdx.x & 63;
  int row = blockIdx.x * 4 + (threadIdx.x >> 6);
  size_t rb = (size_t)row * IN_D;
  float p[10];
#pragma unroll
  for (int o = 0; o < 10; o++) p[o] = 0.f;
  for (int k = lane; k < IN_D; k += 64){
    float xv = x[rb + k];
#pragma unroll
    for (int o = 0; o < 10; o++) p[o] = fmaf(xv, w[o * IN_D + k], p[o]);
  }
#pragma unroll
  for (int o = 0; o < 10; o++) p[o] = wred(p[o]);
  if (lane == 0){
#pragma unroll
    for (int o = 0; o < 10; o++) outp[row * 10 + o] = p[o] + b[o];
  }
}

// ---------------- shared branch --------------------------------------------------
__global__ __launch_bounds__(256)
void shared_kernel(const float* __restrict__ shpre, const float* __restrict__ sdw,
                   const float* __restrict__ g, const float* __restrict__ b,
                   float* __restrict__ outp)
{
  int lane = threadIdx.x & 63;
  int row = blockIdx.x * 4 + (threadIdx.x >> 6);
  const float* xr = shpre + (size_t)row * SHD;
  float p[10];
#pragma unroll
  for (int o = 0; o < 10; o++) p[o] = 0.f;
  for (int k = lane; k < SHD; k += 64){
    float xv = xr[k];
#pragma unroll
    for (int o = 0; o < 10; o++) p[o] = fmaf(xv, sdw[o * SHD + k], p[o]);
  }
#pragma unroll
  for (int o = 0; o < 10; o++) p[o] = wred(p[o]);
  float mean = 0.f;
#pragma unroll
  for (int o = 0; o < 10; o++) mean += p[o];
  mean *= 0.1f;
  float var = 0.f;
#pragma unroll
  for (int o = 0; o < 10; o++){ float dd = p[o] - mean; var += dd * dd; }
  var *= 0.1f;
  float rs = 1.f / sqrtf(var + 1e-5f);
  if (lane == 0){
#pragma unroll
    for (int o = 0; o < 10; o++) outp[row * 10 + o] = (p[o] - mean) * rs * g[o] + b[o];
  }
}

// ---------------- final output ----------------------------------------------------
__global__ __launch_bounds__(256)
void final_out_kernel(const float* __restrict__ cur, const float* __restrict__ mow,
                      const float* __restrict__ basep, const float* __restrict__ sharedp,
                      const float* __restrict__ total, const float* __restrict__ sscale,
                      const float* __restrict__ alphap, const float* __restrict__ betap,
                      float* __restrict__ outp)
{
  int lane = threadIdx.x & 63;
  int row = blockIdx.x * 4 + (threadIdx.x >> 6);
  size_t rb = (size_t)row * IN_D;
  float p[10];
#pragma unroll
  for (int o = 0; o < 10; o++) p[o] = 0.f;
  for (int k = lane; k < IN_D; k += 64){
    float cv = cur[rb + k];
#pragma unroll
    for (int o = 0; o < 10; o++) p[o] = fmaf(cv, mow[o * IN_D + k], p[o]);
  }
#pragma unroll
  for (int o = 0; o < 10; o++) p[o] = wred(p[o]);
  if (lane == 0){
    float ss = sscale[0], av = alphap[0] + 1e-4f, bv = betap[0];
#pragma unroll
    for (int o = 0; o < 10; o++)
      outp[row * 10 + o] = basep[row * 10 + o] + ss * sharedp[row * 10 + o]
                         + av * (total[row * 10 + o] * 0.25f) + bv * p[o];
  }
}

// ====================================================================================
extern "C" void kernel_launch(void* const* d_in, const int* in_sizes, int n_in,
                              void* d_out, int out_size, void* d_ws, size_t ws_size,
                              hipStream_t stream)
{
  const float* x     = (const float*)d_in[0];
  const float* wgt   = (const float*)d_in[1];
  const float* bias  = (const float*)d_in[2];
  const float* suw   = (const float*)d_in[3];
  const float* sdw   = (const float*)d_in[4];
  const float* sng   = (const float*)d_in[5];
  const float* snb   = (const float*)d_in[6];
  const float* sscale= (const float*)d_in[7];
  const float* keys  = (const float*)d_in[8];
  const float* mvi   = (const float*)d_in[9];
  const float* mqw   = (const float*)d_in[10];
  const float* mow   = (const float*)d_in[11];
  const float* wgw   = (const float*)d_in[12];
  const float* wgb   = (const float*)d_in[13];
  const float* wvw   = (const float*)d_in[14];
  const float* wvb   = (const float*)d_in[15];
  const float* dqw   = (const float*)d_in[16];
  const float* dkw   = (const float*)d_in[17];
  const float* dvw   = (const float*)d_in[18];
  const float* dow   = (const float*)d_in[19];
  const float* clng  = (const float*)d_in[20];
  const float* clnb  = (const float*)d_in[21];
  const float* fc1w  = (const float*)d_in[22];
  const float* fc1b  = (const float*)d_in[23];
  const float* fc2w  = (const float*)d_in[24];
  const float* fc2b  = (const float*)d_in[25];
  const float* saw   = (const float*)d_in[26];
  const float* sab   = (const float*)d_in[27];
  const float* sbw   = (const float*)d_in[28];
  const float* sbb   = (const float*)d_in[29];
  const float* msw   = (const float*)d_in[30];
  const float* msb   = (const float*)d_in[31];
  const float* mmw   = (const float*)d_in[32];
  const float* mmb   = (const float*)d_in[33];
  const float* ebias = (const float*)d_in[34];
  const float* bw    = (const float*)d_in[35];
  const float* bb    = (const float*)d_in[36];
  const float* eup   = (const float*)d_in[37];
  const float* edn   = (const float*)d_in[38];
  const float* eng   = (const float*)d_in[39];
  const float* enb   = (const float*)d_in[40];
  const float* hw    = (const float*)d_in[41];
  const float* hb    = (const float*)d_in[42];
  const float* alphap= (const float*)d_in[43];
  const float* betap = (const float*)d_in[44];
  float* outp = (float*)d_out;

  char* wsb = (char*)d_ws;
  size_t off = 0;
  auto AL = [&](size_t bytes) -> void* {
    void* p = wsb + off;
    off = (off + bytes + 255) & ~(size_t)255;
    return p;
  };
  const size_t NI = (size_t)N_TOK * IN_D;
  float* cur    = (float*)AL(NI * 4);
  float* enr    = (float*)AL(NI * 4);
  float* mqdq   = (float*)AL((size_t)N_TOK * 2048 * 4);
  float* mctx   = (float*)AL(NI * 4);
  float* dctx   = (float*)AL(NI * 4);
  float* t40    = (float*)AL((size_t)N_TOK * 40 * 4);
  float* trio0  = (float*)AL((size_t)N_TOK * 3072 * 4);
  float* trio1  = (float*)AL((size_t)N_TOK * 3072 * 4);
  float* trio2  = (float*)AL((size_t)N_TOK * 3072 * 4);
  float* ubuf   = (float*)AL((size_t)N_TOK * 24 * 4);
  float* sval   = (float*)AL((size_t)N_TOK * 4 * 4);
  float* dval   = (float*)AL((size_t)N_TOK * 4 * 4);
  float* Ac     = (float*)AL((size_t)N_TOK * 24 * 4);
  float* W0     = (float*)AL((size_t)N_TOK * 24 * 4);
  float* W1     = (float*)AL((size_t)N_TOK * 24 * 4);
  float* W2     = (float*)AL((size_t)N_TOK * 24 * 4);
  float* sg     = (float*)AL((size_t)N_TOK * 10 * 4);
  float* haltb  = (float*)AL((size_t)N_TOK * 4);
  // single zeroed region: total | cumh | cnt(4 steps x 16)
  char*  zblk   = (char*)AL((size_t)N_TOK * 10 * 4 + N_TOK * 4 + 4 * 16 * 4);
  float* total  = (float*)zblk;
  float* cumh   = (float*)(zblk + (size_t)N_TOK * 10 * 4);
  int*   cnt    = (int*)(zblk + (size_t)N_TOK * 10 * 4 + N_TOK * 4);
  int*   gidx   = (int*)AL((size_t)NEXP * N_TOK * 4);
  int*   pos    = (int*)AL((size_t)N_TOK * NEXP * 4);
  float* basep  = (float*)AL((size_t)N_TOK * 10 * 4);
  float* sharedp= (float*)AL((size_t)N_TOK * 10 * 4);
  float* cbias  = (float*)AL(3072 * 4);
  // bf16 split activations
  uint16_t* curh = (uint16_t*)AL(NI * 2);
  uint16_t* curl = (uint16_t*)AL(NI * 2);
  uint16_t* lnh  = (uint16_t*)AL(NI * 2);
  uint16_t* lnl  = (uint16_t*)AL(NI * 2);
  uint16_t* h7h  = (uint16_t*)AL((size_t)N_TOK * INNER * 2);
  uint16_t* h7l  = (uint16_t*)AL((size_t)N_TOK * INNER * 2);
  // bf16 split weights
  const size_t W1M = (size_t)IN_D * IN_D;
  uint16_t* prewh  = (uint16_t*)AL(3 * W1M * 2); uint16_t* prewl  = (uint16_t*)AL(3 * W1M * 2);
  uint16_t* qtriowh= (uint16_t*)AL(5 * W1M * 2); uint16_t* qtriowl= (uint16_t*)AL(5 * W1M * 2);
  const size_t WFC = (size_t)NSTEP * INNER * IN_D;
  uint16_t* fc1wh = (uint16_t*)AL(WFC * 2); uint16_t* fc1wl = (uint16_t*)AL(WFC * 2);
  uint16_t* fc2wh = (uint16_t*)AL(WFC * 2); uint16_t* fc2wl = (uint16_t*)AL(WFC * 2);
  // big buffers
  uint16_t* upbf  = (uint16_t*)AL((size_t)NEXP * DMAX * IN_D * 2);
  uint16_t* HHc   = (uint16_t*)AL((size_t)N_TOK * DSUM * 2);
  float* shpre  = (float*)HHc;   // alias: consumed before HHc is written

  // ---- init ----
  hipMemsetAsync(zblk, 0, (size_t)N_TOK * 10 * 4 + N_TOK * 4 + 4 * 16 * 4, stream);
  hipMemsetAsync(cbias, 0, 3072 * 4, stream);
  hipMemcpyAsync(cbias + 2048, wvb, 1024 * 4, hipMemcpyDeviceToDevice, stream);
  hipMemcpyAsync(cur, x, NI * 4, hipMemcpyDeviceToDevice, stream);
  fill1_kernel<<<(N_TOK * 24 + 255) / 256, 256, 0, stream>>>(Ac, N_TOK * 24);
  cvt_bf16_kernel<<<2048, 256, 0, stream>>>(eup, upbf, (size_t)NEXP * DMAX * IN_D);
  // weight splits: prew = [mqw; suw], qtriow = [mqw; dqw; dkw; dvw; wvw]
  split_kernel<<<1024, 256, 0, stream>>>(mqw, prewh, prewl, W1M);
  split_kernel<<<1024, 256, 0, stream>>>(suw, prewh + W1M, prewl + W1M, 2 * W1M);
  split_kernel<<<1024, 256, 0, stream>>>(mqw, qtriowh, qtriowl, W1M);
  split_kernel<<<1024, 256, 0, stream>>>(dqw, qtriowh + W1M, qtriowl + W1M, W1M);
  split_kernel<<<1024, 256, 0, stream>>>(dkw, qtriowh + 2*W1M, qtriowl + 2*W1M, W1M);
  split_kernel<<<1024, 256, 0, stream>>>(dvw, qtriowh + 3*W1M, qtriowl + 3*W1M, W1M);
  split_kernel<<<1024, 256, 0, stream>>>(wvw, qtriowh + 4*W1M, qtriowl + 4*W1M, W1M);
  split_kernel<<<1024, 256, 0, stream>>>(fc1w, fc1wh, fc1wl, WFC);
  split_kernel<<<1024, 256, 0, stream>>>(fc2w, fc2wh, fc2wl, WFC);
  split_kernel<<<1024, 256, 0, stream>>>(x, curh, curl, NI);

  base_kernel<<<512, 256, 0, stream>>>(x, wgt, bias, basep);
  // preamble GEMM: [mq | silu(shared_up)] D=3072, split=1024
  gemm_sp<EPI_DUAL_PRE><<<dim3(24, 16), 256, 0, stream>>>(
      curh, curl, prewh, prewl, nullptr, nullptr,
      mqdq, shpre, nullptr, nullptr, IN_D, 3072, 2048, 2048, 1024);
  shared_kernel<<<512, 256, 0, stream>>>(shpre, sdw, sng, snb, sharedp);

  float* trioB[3] = {trio0, trio1, trio2};

  for (int t = 0; t < NSTEP; t++){
    rowred_kernel<<<512, 256, 0, stream>>>(mqdq, keys, Ac, W0, W1, W2, cur, saw, sab,
                                           trio0, trio1, trio2, ubuf, sval, dval, t40, t);
    ctx_enr_kernel<<<2048, 256, 0, stream>>>(ubuf, sval, dval, mvi, trio0, trio1, trio2,
                                             cur, t40, sbw, sbb, clng, clnb,
                                             mctx, dctx, enr, lnh, lnl, t);
    gemm_sp<EPI_GELU_BIAS><<<dim3(INNER/128, 16), 256, 0, stream>>>(
        lnh, lnl, fc1wh + (size_t)t * INNER * IN_D, fc1wl + (size_t)t * INNER * IN_D,
        fc1b + t * INNER, nullptr, nullptr, nullptr, h7h, h7l, IN_D, INNER, 0, 0, 0);
    gemm_sp<EPI_ADD_BIAS><<<dim3(8, 16), 256, 0, stream>>>(
        h7h, h7l, fc2wh + (size_t)t * IN_D * INNER, fc2wl + (size_t)t * IN_D * INNER,
        fc2b + t * IN_D, enr, cur, nullptr, curh, curl, INNER, IN_D, 0, 0, 0);
    routing_kernel<<<512, 256, 0, stream>>>(cur, mctx, dctx, msw, msb, mmw, mmb, ebias,
                                            bw, bb, wgw, wgb, hw, hb,
                                            sg, haltb, Ac, W0, W1, W2,
                                            cnt + t * 16, gidx, pos, t);
    expert_up_mfma<<<dim3(16, 188), 256, 0, stream>>>(curh, upbf, cnt + t * 16, gidx, HHc);
    downfin_kernel<<<512, 256, 0, stream>>>(HHc, pos, edn, sg, eng, enb,
                                            mctx, dctx, mow, dow, haltb, total, cumh);
    // next-step q projections + this step's bank trio: [mq|dq | k|v|wv]
    if (t < 3)
      gemm_sp<EPI_DUAL_QTRIO><<<dim3(40, 16), 256, 0, stream>>>(
          curh, curl, qtriowh, qtriowl, cbias, nullptr,
          mqdq, trioB[t], nullptr, nullptr, IN_D, 5120, 2048, 3072, 2048);
  }
  final_out_kernel<<<512, 256, 0, stream>>>(cur, mow, basep, sharedp, total, sscale,
                                            alphap, betap, outp);
}

// Round 7
// 3739.019 us; speedup vs baseline: 1.2262x; 1.1489x over previous
//
#include <hip/hip_runtime.h>
#include <stdint.h>

#define N_TOK 2048
#define IN_D  1024
#define NEXP  10
#define NSTEP 4
#define INNER 768
#define SHD   2048
#define DMAX  3328
#define DSUM  24064

typedef __attribute__((ext_vector_type(4))) float f32x4;
typedef __attribute__((ext_vector_type(8))) short bf16x8;

__device__ const int c_dims[10] = {1536,2048,2560,3072,1792,2304,2816,2048,2560,3328};
__device__ const int c_offs[10] = {0,1536,3584,6144,9216,11008,13312,16128,18176,20736};
__device__ const int c_acts[10] = {0,1,2,3,4,5,6,7,0,1};
__device__ const int c_cum[11]  = {0,12,28,48,72,86,104,126,142,162,188};

__device__ __forceinline__ float wred(float v){
#pragma unroll
  for (int s = 32; s > 0; s >>= 1) v += __shfl_xor(v, s, 64);
  return v;
}
__device__ __forceinline__ float wmax(float v){
#pragma unroll
  for (int s = 32; s > 0; s >>= 1) v = fmaxf(v, __shfl_xor(v, s, 64));
  return v;
}
__device__ __forceinline__ float bf2f(uint16_t u){
  return __uint_as_float(((uint32_t)u) << 16);
}
__device__ __forceinline__ uint16_t f2bf(float f){
  uint32_t u = __float_as_uint(f);
  return (uint16_t)((u + 0x7FFFu + ((u >> 16) & 1u)) >> 16);
}
__device__ __forceinline__ void gload16(const uint16_t* g, uint16_t* l){
  __builtin_amdgcn_global_load_lds(
      (const __attribute__((address_space(1))) uint32_t*)(const void*)g,
      (__attribute__((address_space(3))) uint32_t*)(void*)l, 16, 0, 0);
}

__device__ __forceinline__ float actf(int a, float x){
  switch(a){
    case 0: return x / (1.f + expf(-x));
    case 1: return 0.5f * x * (1.f + erff(x * 0.7071067811865475f));
    case 2: { float sp = fmaxf(x,0.f) + log1pf(expf(-fabsf(x)));
              return x * tanhf(sp); }
    case 3: return fmaxf(x, 0.f);
    case 4: return x > 0.f ? 1.0507009873554805f * x
                           : 1.7580993408473768f * expm1f(x);
    case 5: return tanhf(x);
    case 6: return fmaxf(x,0.f) + log1pf(expf(-fabsf(x)));
    default: return x > 0.f ? x : expm1f(x);
  }
}

// ---------------- f32 -> (hi, lo) bf16 split, contiguous ------------------------
__global__ void split_kernel(const float* __restrict__ src, uint16_t* __restrict__ hi,
                             uint16_t* __restrict__ lo, size_t n){
  size_t i = ((size_t)blockIdx.x * blockDim.x + threadIdx.x) << 2;
  size_t stride = ((size_t)gridDim.x * blockDim.x) << 2;
  for (; i < n; i += stride){
    float4 v = *(const float4*)(src + i);
    ushort4 h, l;
    h.x = f2bf(v.x); l.x = f2bf(v.x - bf2f(h.x));
    h.y = f2bf(v.y); l.y = f2bf(v.y - bf2f(h.y));
    h.z = f2bf(v.z); l.z = f2bf(v.z - bf2f(h.z));
    h.w = f2bf(v.w); l.w = f2bf(v.w - bf2f(h.w));
    *(ushort4*)(hi + i) = h;
    *(ushort4*)(lo + i) = l;
  }
}
// strided destination variant (x -> A_route cols 0-1023)
__global__ void split_strided(const float* __restrict__ src, uint16_t* __restrict__ hi,
                              uint16_t* __restrict__ lo, int rows, int cols, int ldd){
  int nq = rows * (cols >> 2);
  for (int i = blockIdx.x * blockDim.x + threadIdx.x; i < nq; i += gridDim.x * blockDim.x){
    int r = i / (cols >> 2), c4 = (i - r * (cols >> 2)) << 2;
    float4 v = *(const float4*)(src + (size_t)r * cols + c4);
    ushort4 h, l;
    h.x = f2bf(v.x); l.x = f2bf(v.x - bf2f(h.x));
    h.y = f2bf(v.y); l.y = f2bf(v.y - bf2f(h.y));
    h.z = f2bf(v.z); l.z = f2bf(v.z - bf2f(h.z));
    h.w = f2bf(v.w); l.w = f2bf(v.w - bf2f(h.w));
    size_t d = (size_t)r * ldd + c4;
    *(ushort4*)(hi + d) = h;
    *(ushort4*)(lo + d) = l;
  }
}
__global__ void cvt_bf16_kernel(const float* __restrict__ src, uint16_t* __restrict__ dst, size_t n){
  size_t i = ((size_t)blockIdx.x * blockDim.x + threadIdx.x) << 2;
  size_t stride = ((size_t)gridDim.x * blockDim.x) << 2;
  for (; i < n; i += stride){
    float4 v = *(const float4*)(src + i);
    ushort4 h;
    h.x = f2bf(v.x); h.y = f2bf(v.y); h.z = f2bf(v.z); h.w = f2bf(v.w);
    *(ushort4*)(dst + i) = h;
  }
}
__global__ void fill1_kernel(float* __restrict__ p, int n){
  int i = blockIdx.x * blockDim.x + threadIdx.x;
  if (i < n) p[i] = 1.f;
}

// ---------------- K2 = keys @ mqw  [24,1024] ------------------------------------
__global__ __launch_bounds__(256)
void k2_kernel(const float* __restrict__ keys, const float* __restrict__ mqw,
               float* __restrict__ K2){
  int m = blockIdx.x;
  int j = blockIdx.y * 256 + threadIdx.x;
  float acc = 0.f;
  for (int d = 0; d < 1024; d++)
    acc = fmaf(keys[m * 1024 + d], mqw[d * 1024 + j], acc);
  K2[m * 1024 + j] = acc;
}

// ---------------- route weight builder: 4 x [128 rows x 3072] -------------------
__global__ void build_routew(const float* __restrict__ msw, const float* __restrict__ mmw,
                             const float* __restrict__ bw, const float* __restrict__ wgw,
                             const float* __restrict__ hw, const float* __restrict__ mow,
                             const float* __restrict__ dow, uint16_t* __restrict__ Wh,
                             uint16_t* __restrict__ Wl){
  const int TOT = 4 * 128 * 3072;
  for (int i = blockIdx.x * 256 + threadIdx.x; i < TOT; i += gridDim.x * 256){
    int t = i / (128 * 3072);
    int rem = i - t * (128 * 3072);
    int row = rem / 3072, col = rem - row * 3072;
    float v = 0.f;
    if (row < 40){ if (col < 1024) v = msw[row * 1024 + col]; }
    else if (row < 44){ if (col < 1024) v = mmw[(row - 40) * 1024 + col]; }
    else if (row < 48){ if (col < 1024) v = bw[(row - 44) * 1024 + col]; }
    else if (row < 72){ if (col < 2048) v = wgw[(row - 48) * 2048 + col]; }
    else if (row == 72){
      if (col < 1024) v = hw[t * 1024 + col];
      else if (col < 2048) v = 0.2f * hw[t * 1024 + col - 1024];
      else v = 0.1f * hw[t * 1024 + col - 2048];
    }
    else if (row < 83){ if (col >= 1024 && col < 2048) v = mow[(row - 73) * 1024 + col - 1024]; }
    else if (row < 93){ if (col >= 2048) v = dow[(row - 83) * 1024 + col - 2048]; }
    else if (row < 103){ if (col < 1024) v = mow[(row - 93) * 1024 + col]; }
    uint16_t h = f2bf(v);
    Wh[i] = h; Wl[i] = f2bf(v - bf2f(h));
  }
}

// ---------------- split-bf16 MFMA GEMM, 2-phase dbuf, chunk-major LDS ----------
enum { EPI_GELU=0, EPI_CUR=1, EPI_PRE=2, EPI_QTRIO=3, EPI_ROUTE=4 };

template<int EPI>
__global__ __launch_bounds__(256)
void gemm_sp(const uint16_t* __restrict__ Ah, const uint16_t* __restrict__ Al, int lda,
             const uint16_t* __restrict__ Wh, const uint16_t* __restrict__ Wl,
             const float* __restrict__ bias, const float* __restrict__ addend,
             float* __restrict__ D0, float* __restrict__ D1, float* __restrict__ D2,
             uint16_t* __restrict__ oH, uint16_t* __restrict__ oL,
             int K, int D)
{
  __shared__ __align__(16) uint16_t sm[4][2][4096];
  int tid = threadIdx.x, lane = tid & 63, wave = tid >> 6;
  int wr = wave >> 1, wc = wave & 1;
  int arow = lane & 15, agrp = lane >> 4;
  int rowBase = blockIdx.y * 128, colBase = blockIdx.x * 128;
  f32x4 acc[4][4];
#pragma unroll
  for (int m = 0; m < 4; m++)
#pragma unroll
    for (int n = 0; n < 4; n++){ f32x4 z = {0.f,0.f,0.f,0.f}; acc[m][n] = z; }

#define STAGE_G(buf, k0) do { \
  _Pragma("unroll") \
  for (int s = 0; s < 2; s++){ \
    int u = tid + s * 256; \
    int rr = u & 127, ch = u >> 7; \
    size_t ga = (size_t)(rowBase + rr) * lda + (k0) + ch * 8; \
    size_t gw = (size_t)(colBase + rr) * K + (k0) + ch * 8; \
    gload16(&Ah[ga], &sm[0][buf][u << 3]); \
    gload16(&Al[ga], &sm[1][buf][u << 3]); \
    gload16(&Wh[gw], &sm[2][buf][u << 3]); \
    gload16(&Wl[gw], &sm[3][buf][u << 3]); \
  } } while(0)

  STAGE_G(0, 0);
  __syncthreads();
  int nk = K >> 5;
  for (int ki = 0; ki < nk; ki++){
    int cb = ki & 1;
    if (ki + 1 < nk) STAGE_G(cb ^ 1, (ki + 1) << 5);
    bf16x8 ah[4], al[4], bh[4], bl[4];
#pragma unroll
    for (int m = 0; m < 4; m++){
      int u = (agrp << 7) + wr*64 + m*16 + arow;
      ah[m] = *(const bf16x8*)&sm[0][cb][u << 3];
      al[m] = *(const bf16x8*)&sm[1][cb][u << 3];
    }
#pragma unroll
    for (int n = 0; n < 4; n++){
      int u = (agrp << 7) + wc*64 + n*16 + arow;
      bh[n] = *(const bf16x8*)&sm[2][cb][u << 3];
      bl[n] = *(const bf16x8*)&sm[3][cb][u << 3];
    }
#pragma unroll
    for (int m = 0; m < 4; m++)
#pragma unroll
      for (int n = 0; n < 4; n++){
        acc[m][n] = __builtin_amdgcn_mfma_f32_16x16x32_bf16(ah[m], bh[n], acc[m][n], 0, 0, 0);
        acc[m][n] = __builtin_amdgcn_mfma_f32_16x16x32_bf16(ah[m], bl[n], acc[m][n], 0, 0, 0);
        acc[m][n] = __builtin_amdgcn_mfma_f32_16x16x32_bf16(al[m], bh[n], acc[m][n], 0, 0, 0);
      }
    __syncthreads();
  }
#undef STAGE_G
#pragma unroll
  for (int m = 0; m < 4; m++){
#pragma unroll
    for (int n = 0; n < 4; n++){
      int col = colBase + wc*64 + n*16 + arow;
#pragma unroll
      for (int r2 = 0; r2 < 4; r2++){
        int row = rowBase + wr*64 + m*16 + agrp*4 + r2;
        float v = acc[m][n][r2];
        if (EPI == EPI_GELU){
          v += bias[col];
          v = 0.5f * v * (1.f + erff(v * 0.7071067811865475f));
          size_t idx = (size_t)row * D + col;
          uint16_t h = f2bf(v); oH[idx] = h; oL[idx] = f2bf(v - bf2f(h));
        }
        if (EPI == EPI_CUR){
          v += bias[col] + addend[(size_t)row * 1024 + col];
          D0[(size_t)row * 1024 + col] = v;
          size_t idx = (size_t)row * 3072 + col;
          uint16_t h = f2bf(v); oH[idx] = h; oL[idx] = f2bf(v - bf2f(h));
        }
        if (EPI == EPI_PRE){
          if (col < 2048) D0[(size_t)row * 2048 + col] = v / (1.f + expf(-v));
          else D1[(size_t)row * 128 + col - 2048] = v;
        }
        if (EPI == EPI_QTRIO){
          if (col < 1024) D0[(size_t)row * 1024 + col] = v;
          else if (col < 4096) D1[(size_t)row * 3072 + col - 1024] = v + bias[col - 1024];
          else if (col < 4160) D2[(size_t)row * 128 + col - 4096] = v;
        }
        if (EPI == EPI_ROUTE) D0[(size_t)row * 128 + col] = v;
      }
    }
  }
}

// ---------------- sparse expert up: 128x128 tile, BK=32, 2-phase dbuf ----------
// A rows gathered from A_routeH (row stride 3072, cur in cols 0-1023)
__global__ __launch_bounds__(256)
void expert_up_mfma(const uint16_t* __restrict__ Abf, const uint16_t* __restrict__ Ubf,
                    const int* __restrict__ cnt, const int* __restrict__ gidx,
                    uint16_t* __restrict__ HH)
{
  int y = blockIdx.y;
  int e = 0;
#pragma unroll
  for (int i = 1; i < 11; i++) if (y >= c_cum[i]) e = i;
  int ct = y - c_cum[e];
  int dcols = c_dims[e];
  int ne = cnt[e];
  int rowBase = blockIdx.x * 128;
  if (rowBase >= ne) return;
  const uint16_t* W = Ubf + (size_t)e * DMAX * IN_D + (size_t)ct * 128 * IN_D;

  __shared__ __align__(16) uint16_t smem[16384];
  uint16_t* sA = smem;
  uint16_t* sB = smem + 8192;
  int tid = threadIdx.x, lane = tid & 63, wave = tid >> 6;
  int wr = wave >> 1, wc = wave & 1;
  int arow = lane & 15, agrp = lane >> 4;

  int slot = rowBase + (tid & 127);
  int tok = (slot < ne) ? gidx[e * N_TOK + slot] : 0;

  f32x4 acc[4][4];
#pragma unroll
  for (int m = 0; m < 4; m++)
#pragma unroll
    for (int n = 0; n < 4; n++){ f32x4 z = {0.f,0.f,0.f,0.f}; acc[m][n] = z; }

#define STAGE_E(buf, k0) do { \
  _Pragma("unroll") \
  for (int s = 0; s < 2; s++){ \
    int u = tid + s * 256; \
    int rr = u & 127, ch = u >> 7; \
    gload16(&Abf[(size_t)tok * 3072 + (k0) + ch * 8], &sA[((buf) * 512 + u) << 3]); \
    gload16(&W[(size_t)rr * IN_D + (k0) + ch * 8],   &sB[((buf) * 512 + u) << 3]); \
  } } while(0)

  STAGE_E(0, 0);
  __syncthreads();
#pragma unroll 1
  for (int ki = 0; ki < 32; ki++){
    int cb = ki & 1;
    if (ki + 1 < 32) STAGE_E(cb ^ 1, (ki + 1) << 5);
    bf16x8 a[4], b[4];
#pragma unroll
    for (int m = 0; m < 4; m++){
      int u = cb * 512 + (agrp << 7) + wr*64 + m*16 + arow;
      a[m] = *(const bf16x8*)&sA[u << 3];
    }
#pragma unroll
    for (int n = 0; n < 4; n++){
      int u = cb * 512 + (agrp << 7) + wc*64 + n*16 + arow;
      b[n] = *(const bf16x8*)&sB[u << 3];
    }
#pragma unroll
    for (int m = 0; m < 4; m++)
#pragma unroll
      for (int n = 0; n < 4; n++)
        acc[m][n] = __builtin_amdgcn_mfma_f32_16x16x32_bf16(a[m], b[n], acc[m][n], 0, 0, 0);
    __syncthreads();
  }
#undef STAGE_E
  int actid = c_acts[e];
  uint16_t* Ht = smem;
#pragma unroll
  for (int m = 0; m < 4; m++){
    int rb0 = wr*64 + m*16 + agrp*4;
#pragma unroll
    for (int n = 0; n < 4; n++){
      int col = wc*64 + n*16 + arow;
#pragma unroll
      for (int r2 = 0; r2 < 4; r2++){
        int row = rb0 + r2;
        float v = actf(actid, acc[m][n][r2]);
        Ht[row * 128 + (col ^ ((row & 7) << 3))] = f2bf(v);
      }
    }
  }
  __syncthreads();
  size_t base_e = (size_t)N_TOK * c_offs[e];
#pragma unroll
  for (int i = 0; i < 8; i++){
    int c = tid + i * 256;
    int row = c >> 4, chunk = c & 15;
    int schunk = (chunk & 8) | ((chunk ^ row) & 7);
    int4 val = *(const int4*)&Ht[row * 128 + schunk * 8];
    *(int4*)&HH[base_e + (size_t)(rowBase + row) * dcols
                + (size_t)ct * 128 + chunk * 8] = val;
  }
}

// ---------------- ctx_enr: mem softmax, depth attn, mctx/dctx/enriched/LN ------
__global__ __launch_bounds__(256)
void ctx_enr_kernel(const float* __restrict__ qaux, const float* __restrict__ dqbuf,
                    const float* __restrict__ Ac, const float* __restrict__ W0,
                    const float* __restrict__ W1, const float* __restrict__ W2,
                    const float* __restrict__ mvi,
                    const float* __restrict__ t0, const float* __restrict__ t1,
                    const float* __restrict__ t2, const float* __restrict__ cur,
                    const float* __restrict__ sab, const float* __restrict__ sbw,
                    const float* __restrict__ sbb, const float* __restrict__ lng,
                    const float* __restrict__ lnbv,
                    float* __restrict__ enr, uint16_t* __restrict__ lnh,
                    uint16_t* __restrict__ lnl, uint16_t* __restrict__ Arh,
                    uint16_t* __restrict__ Arl, int t)
{
  int row = blockIdx.x, tid = threadIdx.x;
  __shared__ float su[24], ss[3], s40[40], red[12], redm[8];
  // phase A: wave 0 — mem softmax over p24 = qaux cols 0-23 (pre-scaled dot), s40
  if (tid < 64){
    float pj = (tid < 24) ? qaux[(size_t)row * 128 + tid] * 0.03125f : -1e30f;
    float mx = wmax(pj);
    float ex = (tid < 24) ? expf(pj - mx) : 0.f;
    float sum = wred(ex);
    float attn = ex / sum;
    if (tid < 24) su[tid] = attn * Ac[row * 24 + tid];
    float w0v = (t > 0 && tid < 24) ? W0[row * 24 + tid] : 0.f;
    float s0 = wred(attn * w0v);
    float w1v = (t > 1 && tid < 24) ? W1[row * 24 + tid] : 0.f;
    float s1 = wred(attn * w1v);
    float w2v = (t > 2 && tid < 24) ? W2[row * 24 + tid] : 0.f;
    float s2 = wred(attn * w2v);
    if (tid == 0){ ss[0] = s0; ss[1] = s1; ss[2] = s2; }
    if (tid < 40) s40[tid] = tanhf(qaux[(size_t)row * 128 + 24 + tid] + sab[tid]);
  }
  // phase B: depth attention scores
  size_t tb = (size_t)row * 3072;
  if (t > 0){
    float a0 = 0.f, a1 = 0.f, a2 = 0.f;
#pragma unroll
    for (int j = 0; j < 4; j++){
      int d = tid + j * 256;
      float dq = dqbuf[(size_t)row * 1024 + d];
      a0 = fmaf(dq, t0[tb + d], a0);
      if (t > 1) a1 = fmaf(dq, t1[tb + d], a1);
      if (t > 2) a2 = fmaf(dq, t2[tb + d], a2);
    }
    a0 = wred(a0); a1 = wred(a1); a2 = wred(a2);
    if ((tid & 63) == 0){ int w = tid >> 6; red[w] = a0; red[4+w] = a1; red[8+w] = a2; }
  }
  __syncthreads();
  float e0 = 0.f, e1 = 0.f, e2 = 0.f;
  if (t > 0){
    float A0 = (red[0]+red[1]+red[2]+red[3]) * 0.03125f;
    float A1 = (red[4]+red[5]+red[6]+red[7]) * 0.03125f;
    float A2 = (red[8]+red[9]+red[10]+red[11]) * 0.03125f;
    float dmx = A0;
    if (t > 1) dmx = fmaxf(dmx, A1);
    if (t > 2) dmx = fmaxf(dmx, A2);
    e0 = expf(A0 - dmx);
    e1 = (t > 1) ? expf(A1 - dmx) : 0.f;
    e2 = (t > 2) ? expf(A2 - dmx) : 0.f;
    float dinv = 1.f / (e0 + e1 + e2);
    e0 *= dinv; e1 *= dinv; e2 *= dinv;
  }
  // main elementwise pass
  size_t ar = (size_t)row * 3072;
  float ev[4];
  float part = 0.f;
#pragma unroll
  for (int j = 0; j < 4; j++){
    int d = tid + j * 256;
    size_t idx = (size_t)row * IN_D + d;
    float mv = 0.f;
#pragma unroll
    for (int m = 0; m < 24; m++) mv = fmaf(su[m], mvi[m * IN_D + d], mv);
    float dv = 0.f;
    if (t > 0){
      mv = fmaf(ss[0], t0[tb + 2048 + d], mv);
      dv = e0 * t0[tb + 1024 + d];
      if (t > 1){ mv = fmaf(ss[1], t1[tb + 2048 + d], mv); dv = fmaf(e1, t1[tb + 1024 + d], dv); }
      if (t > 2){ mv = fmaf(ss[2], t2[tb + 2048 + d], mv); dv = fmaf(e2, t2[tb + 1024 + d], dv); }
    }
    float sv = sbb[d];
#pragma unroll
    for (int o = 0; o < 40; o++) sv = fmaf(s40[o], sbw[d * 40 + o], sv);
    float v = cur[idx] + 0.34f * mv + 0.22f * dv + 0.18f * sv;
    // mctx/dctx bf16 splits into A_route cols 1024-2047 / 2048-3071
    uint16_t mh = f2bf(mv);
    Arh[ar + 1024 + d] = mh; Arl[ar + 1024 + d] = f2bf(mv - bf2f(mh));
    uint16_t dh = f2bf(dv);
    Arh[ar + 2048 + d] = dh; Arl[ar + 2048 + d] = f2bf(dv - bf2f(dh));
    ev[j] = v; part += v;
  }
  part = wred(part);
  if ((tid & 63) == 0) redm[tid >> 6] = part;
  __syncthreads();
  float mean = (redm[0] + redm[1] + redm[2] + redm[3]) * (1.f / 1024.f);
  float vp = 0.f;
#pragma unroll
  for (int j = 0; j < 4; j++){ float dd = ev[j] - mean; vp += dd * dd; }
  vp = wred(vp);
  if ((tid & 63) == 0) redm[4 + (tid >> 6)] = vp;
  __syncthreads();
  float var = (redm[4] + redm[5] + redm[6] + redm[7]) * (1.f / 1024.f);
  float rs = 1.f / sqrtf(var + 1e-5f);
#pragma unroll
  for (int j = 0; j < 4; j++){
    int d = tid + j * 256;
    size_t idx = (size_t)row * IN_D + d;
    enr[idx] = ev[j];
    float v = (ev[j] - mean) * rs * lng[t * IN_D + d] + lnbv[t * IN_D + d];
    uint16_t h = f2bf(v);
    lnh[idx] = h;
    lnl[idx] = f2bf(v - bf2f(h));
  }
}

// ---------------- route_fin: softmaxes, top-k, coeff update, compaction --------
__global__ __launch_bounds__(256)
void route_fin(const float* __restrict__ RO, const float* __restrict__ mmb,
               const float* __restrict__ msb, const float* __restrict__ ebias,
               const float* __restrict__ bb, const float* __restrict__ wgb,
               const float* __restrict__ hb,
               float* __restrict__ sg, float* __restrict__ haltb,
               float* __restrict__ Ac, float* __restrict__ W0,
               float* __restrict__ W1, float* __restrict__ W2,
               int* __restrict__ cnt, int* __restrict__ gidx,
               int* __restrict__ pos, int t)
{
  int row = blockIdx.x * 256 + threadIdx.x;
  int lane = threadIdx.x & 63;
  const float* r = RO + (size_t)row * 128;
  // mix softmax
  float pm[4];
#pragma unroll
  for (int o = 0; o < 4; o++) pm[o] = r[40 + o] + mmb[o];
  float mmx = fmaxf(fmaxf(pm[0], pm[1]), fmaxf(pm[2], pm[3]));
  float msum = 0.f;
#pragma unroll
  for (int o = 0; o < 4; o++){ pm[o] = expf(pm[o] - mmx); msum += pm[o]; }
  float minv = 1.f / msum;
  // gate probs
  float gl[10];
#pragma unroll
  for (int e = 0; e < 10; e++){
    float g = ebias[e];
#pragma unroll
    for (int s2 = 0; s2 < 4; s2++)
      g = fmaf(pm[s2] * minv, r[s2 * 10 + e] + msb[s2 * 10 + e], g);
    gl[e] = g;
  }
  float gmx = gl[0];
#pragma unroll
  for (int e = 1; e < 10; e++) gmx = fmaxf(gmx, gl[e]);
  float gs = 0.f;
#pragma unroll
  for (int e = 0; e < 10; e++){ gl[e] = expf(gl[e] - gmx); gs += gl[e]; }
  float ginv = 1.f / gs;
#pragma unroll
  for (int e = 0; e < 10; e++) gl[e] *= ginv;
  // budget
  float pb0 = r[44] + bb[0], pb1 = r[45] + bb[1], pb2 = r[46] + bb[2], pb3 = r[47] + bb[3];
  int bud = 1; float bbest = pb0;
  if (pb1 > bbest){ bbest = pb1; bud = 2; }
  if (pb2 > bbest){ bbest = pb2; bud = 3; }
  if (pb3 > bbest){ bbest = pb3; bud = 4; }
  // top-4
  float tv[4]; int ti[4]; unsigned used = 0;
#pragma unroll
  for (int j = 0; j < 4; j++){
    float best = -1e30f; int bi = 0;
#pragma unroll
    for (int e = 0; e < 10; e++){
      bool ok = (!((used >> e) & 1u)) && (gl[e] > best);
      if (ok){ best = gl[e]; bi = e; }
    }
    tv[j] = best; ti[j] = bi; used |= (1u << bi);
  }
  float ssum = tv[0];
  if (bud > 1) ssum += tv[1];
  if (bud > 2) ssum += tv[2];
  if (bud > 3) ssum += tv[3];
  float den = fmaxf(ssum, 1e-6f);
  float sup = 1.f - tv[0] / den;
  // sg values
  float sgv[10];
#pragma unroll
  for (int e = 0; e < 10; e++){
    float sv = 0.f;
#pragma unroll
    for (int j = 0; j < 4; j++) if (j < bud && ti[j] == e) sv = tv[j] / den;
    sgv[e] = sv;
    sg[row * 10 + e] = sv;
  }
  // wg softmax + coeff update
  float pw[24];
#pragma unroll
  for (int m = 0; m < 24; m++) pw[m] = r[48 + m] + wgb[m];
  float wmx2 = pw[0];
#pragma unroll
  for (int m = 1; m < 24; m++) wmx2 = fmaxf(wmx2, pw[m]);
  float wsum = 0.f;
#pragma unroll
  for (int m = 0; m < 24; m++){ pw[m] = expf(pw[m] - wmx2); wsum += pw[m]; }
  float winv = 1.f / wsum;
#pragma unroll
  for (int m = 0; m < 24; m++){
    float c = sup * pw[m] * winv;
    float om = 1.f - c;
    Ac[row * 24 + m] *= om;
    if (t > 0) W0[row * 24 + m] *= om;
    if (t > 1) W1[row * 24 + m] *= om;
    if (t > 2) W2[row * 24 + m] *= om;
    if (t == 0)      W0[row * 24 + m] = c;
    else if (t == 1) W1[row * 24 + m] = c;
    else if (t == 2) W2[row * 24 + m] = c;
  }
  haltb[row] = 1.f / (1.f + expf(-(r[72] + hb[t])));
  // ballot compaction: one atomic per wave per expert
#pragma unroll
  for (int e = 0; e < 10; e++){
    bool act = sgv[e] != 0.f;
    unsigned long long mask = __ballot(act);
    int cw = __popcll(mask);
    int b0 = 0;
    if (lane == 0 && cw > 0) b0 = atomicAdd(&cnt[e], cw);
    b0 = __shfl(b0, 0, 64);
    if (act){
      int slot = b0 + __popcll(mask & ((1ull << lane) - 1ull));
      gidx[e * N_TOK + slot] = row;
      pos[row * 10 + e] = slot;
    }
  }
}

// ---------------- downfin: expert down + LN + gated acc + step finalize --------
__global__ __launch_bounds__(256)
void downfin_kernel(const uint16_t* __restrict__ HH, const int* __restrict__ pos,
                    const float* __restrict__ ED, const float* __restrict__ sg,
                    const float* __restrict__ eng, const float* __restrict__ enb,
                    const float* __restrict__ RO, const float* __restrict__ haltb,
                    float* __restrict__ total, float* __restrict__ cumh)
{
  int lane = threadIdx.x & 63;
  int row = blockIdx.x * 4 + (threadIdx.x >> 6);
  float out[10] = {};
  for (int e = 0; e < NEXP; e++){
    float g = sg[row * 10 + e];
    if (g != 0.0f){
      int d = c_dims[e];
      int slot = pos[row * 10 + e];
      const uint16_t* hr = HH + (size_t)N_TOK * c_offs[e] + (size_t)slot * d;
      const float* wd = ED + (size_t)e * 10 * DMAX;
      float p[10] = {};
      for (int k = lane * 2; k < d; k += 128){
        uint32_t hv2 = *(const uint32_t*)&hr[k];
        float h0 = bf2f((uint16_t)hv2), h1 = bf2f((uint16_t)(hv2 >> 16));
#pragma unroll
        for (int o = 0; o < 10; o++){
          float2 w2 = *(const float2*)&wd[o * DMAX + k];
          p[o] = fmaf(h0, w2.x, fmaf(h1, w2.y, p[o]));
        }
      }
#pragma unroll
      for (int o = 0; o < 10; o++) p[o] = wred(p[o]);
      float mean = 0.f;
#pragma unroll
      for (int o = 0; o < 10; o++) mean += p[o];
      mean *= 0.1f;
      float var = 0.f;
#pragma unroll
      for (int o = 0; o < 10; o++){ float dd = p[o] - mean; var += dd * dd; }
      var *= 0.1f;
      float rs = 1.f / sqrtf(var + 1e-5f);
#pragma unroll
      for (int o = 0; o < 10; o++)
        out[o] += g * ((p[o] - mean) * rs * eng[e * 10 + o] + enb[e * 10 + o]);
    }
  }
  if (lane == 0){
    const float* r = RO + (size_t)row * 128;
    float rem = 1.f - cumh[row];
#pragma unroll
    for (int o = 0; o < 10; o++)
      total[row * 10 + o] += rem * (out[o] + 0.22f * r[73 + o] + 0.14f * r[83 + o]);
    cumh[row] += rem * haltb[row];
  }
}

// ---------------- shared branch --------------------------------------------------
__global__ __launch_bounds__(256)
void shared_kernel(const float* __restrict__ shpre, const float* __restrict__ sdw,
                   const float* __restrict__ g, const float* __restrict__ b,
                   float* __restrict__ outp)
{
  int lane = threadIdx.x & 63;
  int row = blockIdx.x * 4 + (threadIdx.x >> 6);
  const float* xr = shpre + (size_t)row * SHD;
  float p[10];
#pragma unroll
  for (int o = 0; o < 10; o++) p[o] = 0.f;
  for (int k = lane; k < SHD; k += 64){
    float xv = xr[k];
#pragma unroll
    for (int o = 0; o < 10; o++) p[o] = fmaf(xv, sdw[o * SHD + k], p[o]);
  }
#pragma unroll
  for (int o = 0; o < 10; o++) p[o] = wred(p[o]);
  float mean = 0.f;
#pragma unroll
  for (int o = 0; o < 10; o++) mean += p[o];
  mean *= 0.1f;
  float var = 0.f;
#pragma unroll
  for (int o = 0; o < 10; o++){ float dd = p[o] - mean; var += dd * dd; }
  var *= 0.1f;
  float rs = 1.f / sqrtf(var + 1e-5f);
  if (lane == 0){
#pragma unroll
    for (int o = 0; o < 10; o++) outp[row * 10 + o] = (p[o] - mean) * rs * g[o] + b[o];
  }
}

// ---------------- final output (lite) --------------------------------------------
__global__ __launch_bounds__(256)
void final_lite(const float* __restrict__ qaux, const float* __restrict__ biasp,
                const float* __restrict__ sharedp, const float* __restrict__ total,
                const float* __restrict__ RO, const float* __restrict__ sscale,
                const float* __restrict__ alphap, const float* __restrict__ betap,
                float* __restrict__ outp)
{
  int row = blockIdx.x * 256 + threadIdx.x;
  float ss = sscale[0], av = alphap[0] + 1e-4f, bv = betap[0];
#pragma unroll
  for (int o = 0; o < 10; o++)
    outp[row * 10 + o] = (qaux[(size_t)row * 128 + 64 + o] + biasp[o])
                       + ss * sharedp[row * 10 + o]
                       + av * (total[row * 10 + o] * 0.25f)
                       + bv * RO[(size_t)row * 128 + 93 + o];
}

// ====================================================================================
extern "C" void kernel_launch(void* const* d_in, const int* in_sizes, int n_in,
                              void* d_out, int out_size, void* d_ws, size_t ws_size,
                              hipStream_t stream)
{
  const float* x     = (const float*)d_in[0];
  const float* wgt   = (const float*)d_in[1];
  const float* bias  = (const float*)d_in[2];
  const float* suw   = (const float*)d_in[3];
  const float* sdw   = (const float*)d_in[4];
  const float* sng   = (const float*)d_in[5];
  const float* snb   = (const float*)d_in[6];
  const float* sscale= (const float*)d_in[7];
  const float* keys  = (const float*)d_in[8];
  const float* mvi   = (const float*)d_in[9];
  const float* mqw   = (const float*)d_in[10];
  const float* mow   = (const float*)d_in[11];
  const float* wgw   = (const float*)d_in[12];
  const float* wgb   = (const float*)d_in[13];
  const float* wvw   = (const float*)d_in[14];
  const float* wvb   = (const float*)d_in[15];
  const float* dqw   = (const float*)d_in[16];
  const float* dkw   = (const float*)d_in[17];
  const float* dvw   = (const float*)d_in[18];
  const float* dow   = (const float*)d_in[19];
  const float* clng  = (const float*)d_in[20];
  const float* clnb  = (const float*)d_in[21];
  const float* fc1w  = (const float*)d_in[22];
  const float* fc1b  = (const float*)d_in[23];
  const float* fc2w  = (const float*)d_in[24];
  const float* fc2b  = (const float*)d_in[25];
  const float* saw   = (const float*)d_in[26];
  const float* sab   = (const float*)d_in[27];
  const float* sbw   = (const float*)d_in[28];
  const float* sbb   = (const float*)d_in[29];
  const float* msw   = (const float*)d_in[30];
  const float* msb   = (const float*)d_in[31];
  const float* mmw   = (const float*)d_in[32];
  const float* mmb   = (const float*)d_in[33];
  const float* ebias = (const float*)d_in[34];
  const float* bw    = (const float*)d_in[35];
  const float* bb    = (const float*)d_in[36];
  const float* eup   = (const float*)d_in[37];
  const float* edn   = (const float*)d_in[38];
  const float* eng   = (const float*)d_in[39];
  const float* enb   = (const float*)d_in[40];
  const float* hw    = (const float*)d_in[41];
  const float* hb    = (const float*)d_in[42];
  const float* alphap= (const float*)d_in[43];
  const float* betap = (const float*)d_in[44];
  float* outp = (float*)d_out;

  char* wsb = (char*)d_ws;
  size_t off = 0;
  auto AL = [&](size_t bytes) -> void* {
    void* p = wsb + off;
    off = (off + bytes + 255) & ~(size_t)255;
    return p;
  };
  const size_t NI = (size_t)N_TOK * IN_D;
  float* cur    = (float*)AL(NI * 4);
  float* enr    = (float*)AL(NI * 4);
  float* dqbuf  = (float*)AL(NI * 4);
  float* qaux   = (float*)AL((size_t)N_TOK * 128 * 4);
  float* routeOut=(float*)AL((size_t)N_TOK * 128 * 4);
  float* trio0  = (float*)AL((size_t)N_TOK * 3072 * 4);
  float* trio1  = (float*)AL((size_t)N_TOK * 3072 * 4);
  float* trio2  = (float*)AL((size_t)N_TOK * 3072 * 4);
  float* Ac     = (float*)AL((size_t)N_TOK * 24 * 4);
  float* W0     = (float*)AL((size_t)N_TOK * 24 * 4);
  float* W1     = (float*)AL((size_t)N_TOK * 24 * 4);
  float* W2     = (float*)AL((size_t)N_TOK * 24 * 4);
  float* sg     = (float*)AL((size_t)N_TOK * 10 * 4);
  float* haltb  = (float*)AL((size_t)N_TOK * 4);
  char*  zblk   = (char*)AL((size_t)N_TOK * 10 * 4 + N_TOK * 4 + 4 * 16 * 4);
  float* total  = (float*)zblk;
  float* cumh   = (float*)(zblk + (size_t)N_TOK * 10 * 4);
  int*   cnt    = (int*)(zblk + (size_t)N_TOK * 10 * 4 + N_TOK * 4);
  int*   gidx   = (int*)AL((size_t)NEXP * N_TOK * 4);
  int*   pos    = (int*)AL((size_t)N_TOK * NEXP * 4);
  float* sharedp= (float*)AL((size_t)N_TOK * 10 * 4);
  float* cbias  = (float*)AL(3072 * 4);
  float* K2f    = (float*)AL((size_t)24 * 1024 * 4);
  // activations
  uint16_t* lnh  = (uint16_t*)AL(NI * 2);
  uint16_t* lnl  = (uint16_t*)AL(NI * 2);
  uint16_t* h7h  = (uint16_t*)AL((size_t)N_TOK * INNER * 2);
  uint16_t* h7l  = (uint16_t*)AL((size_t)N_TOK * INNER * 2);
  uint16_t* Arh  = (uint16_t*)AL((size_t)N_TOK * 3072 * 2);
  uint16_t* Arl  = (uint16_t*)AL((size_t)N_TOK * 3072 * 2);
  // weights (bf16 hi/lo)
  const size_t W1M = (size_t)IN_D * IN_D;
  uint16_t* preWh  = (uint16_t*)AL((size_t)2176 * 1024 * 2);
  uint16_t* preWl  = (uint16_t*)AL((size_t)2176 * 1024 * 2);
  uint16_t* qtWh   = (uint16_t*)AL((size_t)4224 * 1024 * 2);
  uint16_t* qtWl   = (uint16_t*)AL((size_t)4224 * 1024 * 2);
  uint16_t* rtWh   = (uint16_t*)AL((size_t)4 * 128 * 3072 * 2);
  uint16_t* rtWl   = (uint16_t*)AL((size_t)4 * 128 * 3072 * 2);
  const size_t WFC = (size_t)NSTEP * INNER * IN_D;
  uint16_t* fc1wh = (uint16_t*)AL(WFC * 2); uint16_t* fc1wl = (uint16_t*)AL(WFC * 2);
  uint16_t* fc2wh = (uint16_t*)AL(WFC * 2); uint16_t* fc2wl = (uint16_t*)AL(WFC * 2);
  // big buffers
  uint16_t* upbf  = (uint16_t*)AL((size_t)NEXP * DMAX * IN_D * 2);
  uint16_t* HHc   = (uint16_t*)AL((size_t)N_TOK * DSUM * 2);
  float* shpre  = (float*)HHc;   // alias: consumed before HHc is written

  // ---- init ----
  hipMemsetAsync(zblk, 0, (size_t)N_TOK * 10 * 4 + N_TOK * 4 + 4 * 16 * 4, stream);
  hipMemsetAsync(cbias, 0, 3072 * 4, stream);
  hipMemcpyAsync(cbias + 2048, wvb, 1024 * 4, hipMemcpyDeviceToDevice, stream);
  hipMemcpyAsync(cur, x, NI * 4, hipMemcpyDeviceToDevice, stream);
  fill1_kernel<<<(N_TOK * 24 + 255) / 256, 256, 0, stream>>>(Ac, N_TOK * 24);
  cvt_bf16_kernel<<<2048, 256, 0, stream>>>(eup, upbf, (size_t)NEXP * DMAX * IN_D);

  // x split -> A_route cols 0-1023
  split_strided<<<1024, 256, 0, stream>>>(x, Arh, Arl, N_TOK, 1024, 3072);
  // preW: [suw | K2 | saw | wgt | 0], rows of width 1024
  split_kernel<<<1024, 256, 0, stream>>>(suw, preWh, preWl, (size_t)SHD * 1024);
  split_kernel<<<256, 256, 0, stream>>>(saw, preWh + (size_t)2072*1024, preWl + (size_t)2072*1024, (size_t)40 * 1024);
  split_kernel<<<256, 256, 0, stream>>>(wgt, preWh + (size_t)2112*1024, preWl + (size_t)2112*1024, (size_t)10 * 1024);
  hipMemsetAsync(preWh + (size_t)2122*1024, 0, (size_t)54 * 1024 * 2, stream);
  hipMemsetAsync(preWl + (size_t)2122*1024, 0, (size_t)54 * 1024 * 2, stream);
  // qtW: [dqw | dkw | dvw | wvw | K2 | saw | 0]
  split_kernel<<<1024, 256, 0, stream>>>(dqw, qtWh, qtWl, W1M);
  split_kernel<<<1024, 256, 0, stream>>>(dkw, qtWh + W1M, qtWl + W1M, W1M);
  split_kernel<<<1024, 256, 0, stream>>>(dvw, qtWh + 2*W1M, qtWl + 2*W1M, W1M);
  split_kernel<<<1024, 256, 0, stream>>>(wvw, qtWh + 3*W1M, qtWl + 3*W1M, W1M);
  split_kernel<<<256, 256, 0, stream>>>(saw, qtWh + (size_t)4120*1024, qtWl + (size_t)4120*1024, (size_t)40 * 1024);
  hipMemsetAsync(qtWh + (size_t)4160*1024, 0, (size_t)64 * 1024 * 2, stream);
  hipMemsetAsync(qtWl + (size_t)4160*1024, 0, (size_t)64 * 1024 * 2, stream);
  // K2 = keys @ mqw, then into preW rows 2048 and qtW rows 4096
  k2_kernel<<<dim3(24, 4), 256, 0, stream>>>(keys, mqw, K2f);
  split_kernel<<<256, 256, 0, stream>>>(K2f, preWh + (size_t)2048*1024, preWl + (size_t)2048*1024, (size_t)24 * 1024);
  split_kernel<<<256, 256, 0, stream>>>(K2f, qtWh + (size_t)4096*1024, qtWl + (size_t)4096*1024, (size_t)24 * 1024);
  // route weights (4 t-variants)
  build_routew<<<2048, 256, 0, stream>>>(msw, mmw, bw, wgw, hw, mow, dow, rtWh, rtWl);
  // fc weights
  split_kernel<<<1024, 256, 0, stream>>>(fc1w, fc1wh, fc1wl, WFC);
  split_kernel<<<1024, 256, 0, stream>>>(fc2w, fc2wh, fc2wl, WFC);

  // preamble GEMM: [silu(shared_up) | K2 | saw | base] over x
  gemm_sp<EPI_PRE><<<dim3(17, 16), 256, 0, stream>>>(
      Arh, Arl, 3072, preWh, preWl, nullptr, nullptr,
      shpre, qaux, nullptr, nullptr, nullptr, IN_D, 2176);
  shared_kernel<<<512, 256, 0, stream>>>(shpre, sdw, sng, snb, sharedp);

  float* trioB[3] = {trio0, trio1, trio2};

  for (int t = 0; t < NSTEP; t++){
    ctx_enr_kernel<<<2048, 256, 0, stream>>>(qaux, dqbuf, Ac, W0, W1, W2, mvi,
                                             trio0, trio1, trio2, cur, sab, sbw, sbb,
                                             clng, clnb, enr, lnh, lnl, Arh, Arl, t);
    gemm_sp<EPI_GELU><<<dim3(INNER/128, 16), 256, 0, stream>>>(
        lnh, lnl, 1024, fc1wh + (size_t)t * INNER * IN_D, fc1wl + (size_t)t * INNER * IN_D,
        fc1b + t * INNER, nullptr, nullptr, nullptr, nullptr, h7h, h7l, IN_D, INNER);
    gemm_sp<EPI_CUR><<<dim3(8, 16), 256, 0, stream>>>(
        h7h, h7l, 768, fc2wh + (size_t)t * IN_D * INNER, fc2wl + (size_t)t * IN_D * INNER,
        fc2b + t * IN_D, enr, cur, nullptr, nullptr, Arh, Arl, INNER, IN_D);
    gemm_sp<EPI_ROUTE><<<dim3(1, 16), 256, 0, stream>>>(
        Arh, Arl, 3072, rtWh + (size_t)t * 128 * 3072, rtWl + (size_t)t * 128 * 3072,
        nullptr, nullptr, routeOut, nullptr, nullptr, nullptr, nullptr, 3072, 128);
    route_fin<<<8, 256, 0, stream>>>(routeOut, mmb, msb, ebias, bb, wgb, hb,
                                     sg, haltb, Ac, W0, W1, W2,
                                     cnt + t * 16, gidx, pos, t);
    expert_up_mfma<<<dim3(16, 188), 256, 0, stream>>>(Arh, upbf, cnt + t * 16, gidx, HHc);
    downfin_kernel<<<512, 256, 0, stream>>>(HHc, pos, edn, sg, eng, enb,
                                            routeOut, haltb, total, cumh);
    if (t < 3)
      gemm_sp<EPI_QTRIO><<<dim3(33, 16), 256, 0, stream>>>(
          Arh, Arl, 3072, qtWh, qtWl, cbias, nullptr,
          dqbuf, trioB[t], qaux, nullptr, nullptr, IN_D, 4224);
  }
  final_lite<<<8, 256, 0, stream>>>(qaux, bias, sharedp, total, routeOut,
                                    sscale, alphap, betap, outp);
}

// Round 8
// 2706.576 us; speedup vs baseline: 1.6939x; 1.3815x over previous
//
#include <hip/hip_runtime.h>
#include <stdint.h>

#define N_TOK 2048
#define IN_D  1024
#define NEXP  10
#define NSTEP 4
#define INNER 768
#define SHD   2048
#define DMAX  3328
#define DSUM  24064

typedef __attribute__((ext_vector_type(4))) float f32x4;
typedef __attribute__((ext_vector_type(8))) short bf16x8;

__device__ const int c_dims[10] = {1536,2048,2560,3072,1792,2304,2816,2048,2560,3328};
__device__ const int c_offs[10] = {0,1536,3584,6144,9216,11008,13312,16128,18176,20736};
__device__ const int c_acts[10] = {0,1,2,3,4,5,6,7,0,1};
__device__ const int c_cum[11]  = {0,12,28,48,72,86,104,126,142,162,188};

__device__ __forceinline__ float wred(float v){
#pragma unroll
  for (int s = 32; s > 0; s >>= 1) v += __shfl_xor(v, s, 64);
  return v;
}
__device__ __forceinline__ float wmax(float v){
#pragma unroll
  for (int s = 32; s > 0; s >>= 1) v = fmaxf(v, __shfl_xor(v, s, 64));
  return v;
}
__device__ __forceinline__ float bf2f(uint16_t u){
  return __uint_as_float(((uint32_t)u) << 16);
}
__device__ __forceinline__ uint16_t f2bf(float f){
  uint32_t u = __float_as_uint(f);
  return (uint16_t)((u + 0x7FFFu + ((u >> 16) & 1u)) >> 16);
}
__device__ __forceinline__ void gload16(const uint16_t* g, uint16_t* l){
  __builtin_amdgcn_global_load_lds(
      (const __attribute__((address_space(1))) uint32_t*)(const void*)g,
      (__attribute__((address_space(3))) uint32_t*)(void*)l, 16, 0, 0);
}

__device__ __forceinline__ float actf(int a, float x){
  switch(a){
    case 0: return x / (1.f + expf(-x));
    case 1: return 0.5f * x * (1.f + erff(x * 0.7071067811865475f));
    case 2: { float sp = fmaxf(x,0.f) + log1pf(expf(-fabsf(x)));
              return x * tanhf(sp); }
    case 3: return fmaxf(x, 0.f);
    case 4: return x > 0.f ? 1.0507009873554805f * x
                           : 1.7580993408473768f * expm1f(x);
    case 5: return tanhf(x);
    case 6: return fmaxf(x,0.f) + log1pf(expf(-fabsf(x)));
    default: return x > 0.f ? x : expm1f(x);
  }
}

// ---------------- f32 -> (hi, lo) bf16 split, contiguous ------------------------
__global__ void split_kernel(const float* __restrict__ src, uint16_t* __restrict__ hi,
                             uint16_t* __restrict__ lo, size_t n){
  size_t i = ((size_t)blockIdx.x * blockDim.x + threadIdx.x) << 2;
  size_t stride = ((size_t)gridDim.x * blockDim.x) << 2;
  for (; i < n; i += stride){
    float4 v = *(const float4*)(src + i);
    ushort4 h, l;
    h.x = f2bf(v.x); l.x = f2bf(v.x - bf2f(h.x));
    h.y = f2bf(v.y); l.y = f2bf(v.y - bf2f(h.y));
    h.z = f2bf(v.z); l.z = f2bf(v.z - bf2f(h.z));
    h.w = f2bf(v.w); l.w = f2bf(v.w - bf2f(h.w));
    *(ushort4*)(hi + i) = h;
    *(ushort4*)(lo + i) = l;
  }
}
__global__ void split_strided(const float* __restrict__ src, uint16_t* __restrict__ hi,
                              uint16_t* __restrict__ lo, int rows, int cols, int ldd){
  int nq = rows * (cols >> 2);
  for (int i = blockIdx.x * blockDim.x + threadIdx.x; i < nq; i += gridDim.x * blockDim.x){
    int r = i / (cols >> 2), c4 = (i - r * (cols >> 2)) << 2;
    float4 v = *(const float4*)(src + (size_t)r * cols + c4);
    ushort4 h, l;
    h.x = f2bf(v.x); l.x = f2bf(v.x - bf2f(h.x));
    h.y = f2bf(v.y); l.y = f2bf(v.y - bf2f(h.y));
    h.z = f2bf(v.z); l.z = f2bf(v.z - bf2f(h.z));
    h.w = f2bf(v.w); l.w = f2bf(v.w - bf2f(h.w));
    size_t d = (size_t)r * ldd + c4;
    *(ushort4*)(hi + d) = h;
    *(ushort4*)(lo + d) = l;
  }
}
__global__ void cvt_bf16_kernel(const float* __restrict__ src, uint16_t* __restrict__ dst, size_t n){
  size_t i = ((size_t)blockIdx.x * blockDim.x + threadIdx.x) << 2;
  size_t stride = ((size_t)gridDim.x * blockDim.x) << 2;
  for (; i < n; i += stride){
    float4 v = *(const float4*)(src + i);
    ushort4 h;
    h.x = f2bf(v.x); h.y = f2bf(v.y); h.z = f2bf(v.z); h.w = f2bf(v.w);
    *(ushort4*)(dst + i) = h;
  }
}
__global__ void fill1_kernel(float* __restrict__ p, int n){
  int i = blockIdx.x * blockDim.x + threadIdx.x;
  if (i < n) p[i] = 1.f;
}

// ---------------- K2 = keys @ mqw  [24,1024] ------------------------------------
__global__ __launch_bounds__(256)
void k2_kernel(const float* __restrict__ keys, const float* __restrict__ mqw,
               float* __restrict__ K2){
  int m = blockIdx.x;
  int j = blockIdx.y * 256 + threadIdx.x;
  float acc = 0.f;
  for (int d = 0; d < 1024; d++)
    acc = fmaf(keys[m * 1024 + d], mqw[d * 1024 + j], acc);
  K2[m * 1024 + j] = acc;
}

// ---------------- route weight builder: 4 x [128 rows x 3072] -------------------
__global__ void build_routew(const float* __restrict__ msw, const float* __restrict__ mmw,
                             const float* __restrict__ bw, const float* __restrict__ wgw,
                             const float* __restrict__ hw, const float* __restrict__ mow,
                             const float* __restrict__ dow, uint16_t* __restrict__ Wh,
                             uint16_t* __restrict__ Wl){
  const int TOT = 4 * 128 * 3072;
  for (int i = blockIdx.x * 256 + threadIdx.x; i < TOT; i += gridDim.x * 256){
    int t = i / (128 * 3072);
    int rem = i - t * (128 * 3072);
    int row = rem / 3072, col = rem - row * 3072;
    float v = 0.f;
    if (row < 40){ if (col < 1024) v = msw[row * 1024 + col]; }
    else if (row < 44){ if (col < 1024) v = mmw[(row - 40) * 1024 + col]; }
    else if (row < 48){ if (col < 1024) v = bw[(row - 44) * 1024 + col]; }
    else if (row < 72){ if (col < 2048) v = wgw[(row - 48) * 2048 + col]; }
    else if (row == 72){
      if (col < 1024) v = hw[t * 1024 + col];
      else if (col < 2048) v = 0.2f * hw[t * 1024 + col - 1024];
      else v = 0.1f * hw[t * 1024 + col - 2048];
    }
    else if (row < 83){ if (col >= 1024 && col < 2048) v = mow[(row - 73) * 1024 + col - 1024]; }
    else if (row < 93){ if (col >= 2048) v = dow[(row - 83) * 1024 + col - 2048]; }
    else if (row < 103){ if (col < 1024) v = mow[(row - 93) * 1024 + col]; }
    uint16_t h = f2bf(v);
    Wh[i] = h; Wl[i] = f2bf(v - bf2f(h));
  }
}

// ---------------- split-bf16 MFMA GEMM, 2-phase dbuf -----------------------------
// LDS mapping (both-sides swizzle): unit u holds global chunk ((u&3)^((u>>3)&3))
// of row (u>>2). Staging: 4 consecutive lanes = one 64B segment (coalesced).
// Fragment read (R,g): u = R*4 + (g ^ ((R>>1)&3)) -> 2-way banks per quarter-wave.
enum { EPI_GELU=0, EPI_CUR=1, EPI_PRE=2, EPI_QTRIO=3, EPI_ROUTE=4 };

template<int EPI>
__global__ __launch_bounds__(256)
void gemm_sp(const uint16_t* __restrict__ Ah, const uint16_t* __restrict__ Al, int lda,
             const uint16_t* __restrict__ Wh, const uint16_t* __restrict__ Wl,
             const float* __restrict__ bias, const float* __restrict__ addend,
             float* __restrict__ D0, float* __restrict__ D1, float* __restrict__ D2,
             uint16_t* __restrict__ oH, uint16_t* __restrict__ oL,
             int K, int D)
{
  __shared__ __align__(16) uint16_t sm[4][2][4096];
  int tid = threadIdx.x, lane = tid & 63, wave = tid >> 6;
  int wr = wave >> 1, wc = wave & 1;
  int arow = lane & 15, agrp = lane >> 4;
  int rowBase = blockIdx.y * 128;
  int colBase = (EPI == EPI_ROUTE) ? 0 : blockIdx.x * 128;
  int kBase   = (EPI == EPI_ROUTE) ? blockIdx.x * 768 : 0;
  int kLen    = (EPI == EPI_ROUTE) ? 768 : K;
  f32x4 acc[4][4];
#pragma unroll
  for (int m = 0; m < 4; m++)
#pragma unroll
    for (int n = 0; n < 4; n++){ f32x4 z = {0.f,0.f,0.f,0.f}; acc[m][n] = z; }

#define STAGE_G(buf, k0) do { \
  _Pragma("unroll") \
  for (int s = 0; s < 2; s++){ \
    int u = tid + s * 256; \
    int rr = u >> 2; \
    int ch = (u & 3) ^ ((rr >> 1) & 3); \
    size_t ga = (size_t)(rowBase + rr) * lda + kBase + (k0) + ch * 8; \
    size_t gw = (size_t)(colBase + rr) * K + kBase + (k0) + ch * 8; \
    gload16(&Ah[ga], &sm[0][buf][u << 3]); \
    gload16(&Al[ga], &sm[1][buf][u << 3]); \
    gload16(&Wh[gw], &sm[2][buf][u << 3]); \
    gload16(&Wl[gw], &sm[3][buf][u << 3]); \
  } } while(0)

  STAGE_G(0, 0);
  __syncthreads();
  int nk = kLen >> 5;
  int perm = (arow >> 1) & 3;
  for (int ki = 0; ki < nk; ki++){
    int cb = ki & 1;
    if (ki + 1 < nk) STAGE_G(cb ^ 1, (ki + 1) << 5);
    bf16x8 ah[4], al[4], bh[4], bl[4];
#pragma unroll
    for (int m = 0; m < 4; m++){
      int u = ((wr*64 + m*16 + arow) << 2) + (agrp ^ perm);
      ah[m] = *(const bf16x8*)&sm[0][cb][u << 3];
      al[m] = *(const bf16x8*)&sm[1][cb][u << 3];
    }
#pragma unroll
    for (int n = 0; n < 4; n++){
      int u = ((wc*64 + n*16 + arow) << 2) + (agrp ^ perm);
      bh[n] = *(const bf16x8*)&sm[2][cb][u << 3];
      bl[n] = *(const bf16x8*)&sm[3][cb][u << 3];
    }
#pragma unroll
    for (int m = 0; m < 4; m++)
#pragma unroll
      for (int n = 0; n < 4; n++){
        acc[m][n] = __builtin_amdgcn_mfma_f32_16x16x32_bf16(ah[m], bh[n], acc[m][n], 0, 0, 0);
        acc[m][n] = __builtin_amdgcn_mfma_f32_16x16x32_bf16(ah[m], bl[n], acc[m][n], 0, 0, 0);
        acc[m][n] = __builtin_amdgcn_mfma_f32_16x16x32_bf16(al[m], bh[n], acc[m][n], 0, 0, 0);
      }
    __syncthreads();
  }
#undef STAGE_G
#pragma unroll
  for (int m = 0; m < 4; m++){
#pragma unroll
    for (int n = 0; n < 4; n++){
      int col = colBase + wc*64 + n*16 + arow;
#pragma unroll
      for (int r2 = 0; r2 < 4; r2++){
        int row = rowBase + wr*64 + m*16 + agrp*4 + r2;
        float v = acc[m][n][r2];
        if (EPI == EPI_GELU){
          v += bias[col];
          v = 0.5f * v * (1.f + erff(v * 0.7071067811865475f));
          size_t idx = (size_t)row * D + col;
          uint16_t h = f2bf(v); oH[idx] = h; oL[idx] = f2bf(v - bf2f(h));
        }
        if (EPI == EPI_CUR){
          v += bias[col] + addend[(size_t)row * 1024 + col];
          D0[(size_t)row * 1024 + col] = v;
          size_t idx = (size_t)row * 3072 + col;
          uint16_t h = f2bf(v); oH[idx] = h; oL[idx] = f2bf(v - bf2f(h));
        }
        if (EPI == EPI_PRE){
          if (col < 2048) D0[(size_t)row * 2048 + col] = v / (1.f + expf(-v));
          else D1[(size_t)row * 128 + col - 2048] = v;
        }
        if (EPI == EPI_QTRIO){
          if (col < 1024) D0[(size_t)row * 1024 + col] = v;
          else if (col < 4096) D1[(size_t)row * 3072 + col - 1024] = v + bias[col - 1024];
          else if (col < 4160) D2[(size_t)row * 128 + col - 4096] = v;
        }
        if (EPI == EPI_ROUTE)
          D0[((size_t)blockIdx.x * N_TOK + row) * 128 + col] = v;
      }
    }
  }
}

// ---------------- sparse expert up: 128x128 tile, BK=32, 2-phase dbuf ----------
__global__ __launch_bounds__(256)
void expert_up_mfma(const uint16_t* __restrict__ Abf, const uint16_t* __restrict__ Ubf,
                    const int* __restrict__ cnt, const int* __restrict__ gidx,
                    uint16_t* __restrict__ HH)
{
  int y = blockIdx.y;
  int e = 0;
#pragma unroll
  for (int i = 1; i < 11; i++) if (y >= c_cum[i]) e = i;
  int ct = y - c_cum[e];
  int dcols = c_dims[e];
  int ne = cnt[e];
  int rowBase = blockIdx.x * 128;
  if (rowBase >= ne) return;
  const uint16_t* W = Ubf + (size_t)e * DMAX * IN_D + (size_t)ct * 128 * IN_D;

  __shared__ __align__(16) uint16_t smem[16384];
  uint16_t* sA = smem;
  uint16_t* sB = smem + 8192;
  int tid = threadIdx.x, lane = tid & 63, wave = tid >> 6;
  int wr = wave >> 1, wc = wave & 1;
  int arow = lane & 15, agrp = lane >> 4;

  // row for stage s: s=0 -> tid>>2, s=1 -> 64 + (tid>>2). 4 lanes share one token.
  int r0 = rowBase + (tid >> 2);
  int tok0 = (r0 < ne) ? gidx[e * N_TOK + r0] : 0;
  int tok1 = (r0 + 64 < ne) ? gidx[e * N_TOK + r0 + 64] : 0;

  f32x4 acc[4][4];
#pragma unroll
  for (int m = 0; m < 4; m++)
#pragma unroll
    for (int n = 0; n < 4; n++){ f32x4 z = {0.f,0.f,0.f,0.f}; acc[m][n] = z; }

#define STAGE_E(buf, k0) do { \
  _Pragma("unroll") \
  for (int s = 0; s < 2; s++){ \
    int u = tid + s * 256; \
    int rr = u >> 2; \
    int ch = (u & 3) ^ ((rr >> 1) & 3); \
    int tk = (s == 0) ? tok0 : tok1; \
    gload16(&Abf[(size_t)tk * 3072 + (k0) + ch * 8], &sA[((buf) * 512 + u) << 3]); \
    gload16(&W[(size_t)rr * IN_D + (k0) + ch * 8],   &sB[((buf) * 512 + u) << 3]); \
  } } while(0)

  STAGE_E(0, 0);
  __syncthreads();
  int perm = (arow >> 1) & 3;
#pragma unroll 1
  for (int ki = 0; ki < 32; ki++){
    int cb = ki & 1;
    if (ki + 1 < 32) STAGE_E(cb ^ 1, (ki + 1) << 5);
    bf16x8 a[4], b[4];
#pragma unroll
    for (int m = 0; m < 4; m++){
      int u = cb * 512 + ((wr*64 + m*16 + arow) << 2) + (agrp ^ perm);
      a[m] = *(const bf16x8*)&sA[u << 3];
    }
#pragma unroll
    for (int n = 0; n < 4; n++){
      int u = cb * 512 + ((wc*64 + n*16 + arow) << 2) + (agrp ^ perm);
      b[n] = *(const bf16x8*)&sB[u << 3];
    }
#pragma unroll
    for (int m = 0; m < 4; m++)
#pragma unroll
      for (int n = 0; n < 4; n++)
        acc[m][n] = __builtin_amdgcn_mfma_f32_16x16x32_bf16(a[m], b[n], acc[m][n], 0, 0, 0);
    __syncthreads();
  }
#undef STAGE_E
  int actid = c_acts[e];
  uint16_t* Ht = smem;
#pragma unroll
  for (int m = 0; m < 4; m++){
    int rb0 = wr*64 + m*16 + agrp*4;
#pragma unroll
    for (int n = 0; n < 4; n++){
      int col = wc*64 + n*16 + arow;
#pragma unroll
      for (int r2 = 0; r2 < 4; r2++){
        int row = rb0 + r2;
        float v = actf(actid, acc[m][n][r2]);
        Ht[row * 128 + (col ^ ((row & 7) << 3))] = f2bf(v);
      }
    }
  }
  __syncthreads();
  size_t base_e = (size_t)N_TOK * c_offs[e];
#pragma unroll
  for (int i = 0; i < 8; i++){
    int c = tid + i * 256;
    int row = c >> 4, chunk = c & 15;
    int schunk = (chunk & 8) | ((chunk ^ row) & 7);
    int4 val = *(const int4*)&Ht[row * 128 + schunk * 8];
    *(int4*)&HH[base_e + (size_t)(rowBase + row) * dcols
                + (size_t)ct * 128 + chunk * 8] = val;
  }
}

// ---------------- ctx_enr: mem softmax, depth attn, mctx/dctx/enriched/LN ------
__global__ __launch_bounds__(256)
void ctx_enr_kernel(const float* __restrict__ qaux, const float* __restrict__ dqbuf,
                    const float* __restrict__ Ac, const float* __restrict__ W0,
                    const float* __restrict__ W1, const float* __restrict__ W2,
                    const float* __restrict__ mvi,
                    const float* __restrict__ t0, const float* __restrict__ t1,
                    const float* __restrict__ t2, const float* __restrict__ cur,
                    const float* __restrict__ sab, const float* __restrict__ sbw,
                    const float* __restrict__ sbb, const float* __restrict__ lng,
                    const float* __restrict__ lnbv,
                    float* __restrict__ enr, uint16_t* __restrict__ lnh,
                    uint16_t* __restrict__ lnl, uint16_t* __restrict__ Arh,
                    uint16_t* __restrict__ Arl, int t)
{
  int row = blockIdx.x, tid = threadIdx.x;
  __shared__ float su[24], ss[3], s40[40], red[12], redm[8];
  if (tid < 64){
    float pj = (tid < 24) ? qaux[(size_t)row * 128 + tid] * 0.03125f : -1e30f;
    float mx = wmax(pj);
    float ex = (tid < 24) ? expf(pj - mx) : 0.f;
    float sum = wred(ex);
    float attn = ex / sum;
    if (tid < 24) su[tid] = attn * Ac[row * 24 + tid];
    float w0v = (t > 0 && tid < 24) ? W0[row * 24 + tid] : 0.f;
    float s0 = wred(attn * w0v);
    float w1v = (t > 1 && tid < 24) ? W1[row * 24 + tid] : 0.f;
    float s1 = wred(attn * w1v);
    float w2v = (t > 2 && tid < 24) ? W2[row * 24 + tid] : 0.f;
    float s2 = wred(attn * w2v);
    if (tid == 0){ ss[0] = s0; ss[1] = s1; ss[2] = s2; }
    if (tid < 40) s40[tid] = tanhf(qaux[(size_t)row * 128 + 24 + tid] + sab[tid]);
  }
  size_t tb = (size_t)row * 3072;
  if (t > 0){
    float a0 = 0.f, a1 = 0.f, a2 = 0.f;
#pragma unroll
    for (int j = 0; j < 4; j++){
      int d = tid + j * 256;
      float dq = dqbuf[(size_t)row * 1024 + d];
      a0 = fmaf(dq, t0[tb + d], a0);
      if (t > 1) a1 = fmaf(dq, t1[tb + d], a1);
      if (t > 2) a2 = fmaf(dq, t2[tb + d], a2);
    }
    a0 = wred(a0); a1 = wred(a1); a2 = wred(a2);
    if ((tid & 63) == 0){ int w = tid >> 6; red[w] = a0; red[4+w] = a1; red[8+w] = a2; }
  }
  __syncthreads();
  float e0 = 0.f, e1 = 0.f, e2 = 0.f;
  if (t > 0){
    float A0 = (red[0]+red[1]+red[2]+red[3]) * 0.03125f;
    float A1 = (red[4]+red[5]+red[6]+red[7]) * 0.03125f;
    float A2 = (red[8]+red[9]+red[10]+red[11]) * 0.03125f;
    float dmx = A0;
    if (t > 1) dmx = fmaxf(dmx, A1);
    if (t > 2) dmx = fmaxf(dmx, A2);
    e0 = expf(A0 - dmx);
    e1 = (t > 1) ? expf(A1 - dmx) : 0.f;
    e2 = (t > 2) ? expf(A2 - dmx) : 0.f;
    float dinv = 1.f / (e0 + e1 + e2);
    e0 *= dinv; e1 *= dinv; e2 *= dinv;
  }
  size_t ar = (size_t)row * 3072;
  float ev[4];
  float part = 0.f;
#pragma unroll
  for (int j = 0; j < 4; j++){
    int d = tid + j * 256;
    size_t idx = (size_t)row * IN_D + d;
    float mv = 0.f;
#pragma unroll
    for (int m = 0; m < 24; m++) mv = fmaf(su[m], mvi[m * IN_D + d], mv);
    float dv = 0.f;
    if (t > 0){
      mv = fmaf(ss[0], t0[tb + 2048 + d], mv);
      dv = e0 * t0[tb + 1024 + d];
      if (t > 1){ mv = fmaf(ss[1], t1[tb + 2048 + d], mv); dv = fmaf(e1, t1[tb + 1024 + d], dv); }
      if (t > 2){ mv = fmaf(ss[2], t2[tb + 2048 + d], mv); dv = fmaf(e2, t2[tb + 1024 + d], dv); }
    }
    float sv = sbb[d];
#pragma unroll
    for (int o = 0; o < 40; o++) sv = fmaf(s40[o], sbw[d * 40 + o], sv);
    float v = cur[idx] + 0.34f * mv + 0.22f * dv + 0.18f * sv;
    uint16_t mh = f2bf(mv);
    Arh[ar + 1024 + d] = mh; Arl[ar + 1024 + d] = f2bf(mv - bf2f(mh));
    uint16_t dh = f2bf(dv);
    Arh[ar + 2048 + d] = dh; Arl[ar + 2048 + d] = f2bf(dv - bf2f(dh));
    ev[j] = v; part += v;
  }
  part = wred(part);
  if ((tid & 63) == 0) redm[tid >> 6] = part;
  __syncthreads();
  float mean = (redm[0] + redm[1] + redm[2] + redm[3]) * (1.f / 1024.f);
  float vp = 0.f;
#pragma unroll
  for (int j = 0; j < 4; j++){ float dd = ev[j] - mean; vp += dd * dd; }
  vp = wred(vp);
  if ((tid & 63) == 0) redm[4 + (tid >> 6)] = vp;
  __syncthreads();
  float var = (redm[4] + redm[5] + redm[6] + redm[7]) * (1.f / 1024.f);
  float rs = 1.f / sqrtf(var + 1e-5f);
#pragma unroll
  for (int j = 0; j < 4; j++){
    int d = tid + j * 256;
    size_t idx = (size_t)row * IN_D + d;
    enr[idx] = ev[j];
    float v = (ev[j] - mean) * rs * lng[t * IN_D + d] + lnbv[t * IN_D + d];
    uint16_t h = f2bf(v);
    lnh[idx] = h;
    lnl[idx] = f2bf(v - bf2f(h));
  }
}

// ---------------- route_fin: sums 4 K-split partials, softmaxes, top-k ----------
__global__ __launch_bounds__(256)
void route_fin(const float* __restrict__ ROq, const float* __restrict__ mmb,
               const float* __restrict__ msb, const float* __restrict__ ebias,
               const float* __restrict__ bb, const float* __restrict__ wgb,
               const float* __restrict__ hb,
               float* __restrict__ sg, float* __restrict__ haltb,
               float* __restrict__ Ac, float* __restrict__ W0,
               float* __restrict__ W1, float* __restrict__ W2,
               int* __restrict__ cnt, int* __restrict__ gidx,
               int* __restrict__ pos, float* __restrict__ routeS, int t)
{
  int row = blockIdx.x * 256 + threadIdx.x;
  int lane = threadIdx.x & 63;
  const size_t P = (size_t)N_TOK * 128;
  const float* r0 = ROq + (size_t)row * 128;
  const float* r1 = r0 + P;
  const float* r2 = r0 + 2 * P;
  const float* r3 = r0 + 3 * P;
  auto R = [&](int j){ return r0[j] + r1[j] + r2[j] + r3[j]; };
  // mix softmax
  float pm[4];
#pragma unroll
  for (int o = 0; o < 4; o++) pm[o] = R(40 + o) + mmb[o];
  float mmx = fmaxf(fmaxf(pm[0], pm[1]), fmaxf(pm[2], pm[3]));
  float msum = 0.f;
#pragma unroll
  for (int o = 0; o < 4; o++){ pm[o] = expf(pm[o] - mmx); msum += pm[o]; }
  float minv = 1.f / msum;
  float gl[10];
#pragma unroll
  for (int e = 0; e < 10; e++){
    float g = ebias[e];
#pragma unroll
    for (int s2 = 0; s2 < 4; s2++)
      g = fmaf(pm[s2] * minv, R(s2 * 10 + e) + msb[s2 * 10 + e], g);
    gl[e] = g;
  }
  float gmx = gl[0];
#pragma unroll
  for (int e = 1; e < 10; e++) gmx = fmaxf(gmx, gl[e]);
  float gs = 0.f;
#pragma unroll
  for (int e = 0; e < 10; e++){ gl[e] = expf(gl[e] - gmx); gs += gl[e]; }
  float ginv = 1.f / gs;
#pragma unroll
  for (int e = 0; e < 10; e++) gl[e] *= ginv;
  float pb0 = R(44) + bb[0], pb1 = R(45) + bb[1], pb2 = R(46) + bb[2], pb3 = R(47) + bb[3];
  int bud = 1; float bbest = pb0;
  if (pb1 > bbest){ bbest = pb1; bud = 2; }
  if (pb2 > bbest){ bbest = pb2; bud = 3; }
  if (pb3 > bbest){ bbest = pb3; bud = 4; }
  float tv[4]; int ti[4]; unsigned used = 0;
#pragma unroll
  for (int j = 0; j < 4; j++){
    float best = -1e30f; int bi = 0;
#pragma unroll
    for (int e = 0; e < 10; e++){
      bool ok = (!((used >> e) & 1u)) && (gl[e] > best);
      if (ok){ best = gl[e]; bi = e; }
    }
    tv[j] = best; ti[j] = bi; used |= (1u << bi);
  }
  float ssum = tv[0];
  if (bud > 1) ssum += tv[1];
  if (bud > 2) ssum += tv[2];
  if (bud > 3) ssum += tv[3];
  float den = fmaxf(ssum, 1e-6f);
  float sup = 1.f - tv[0] / den;
  float sgv[10];
#pragma unroll
  for (int e = 0; e < 10; e++){
    float sv = 0.f;
#pragma unroll
    for (int j = 0; j < 4; j++) if (j < bud && ti[j] == e) sv = tv[j] / den;
    sgv[e] = sv;
    sg[row * 10 + e] = sv;
  }
  float pw[24];
#pragma unroll
  for (int m = 0; m < 24; m++) pw[m] = R(48 + m) + wgb[m];
  float wmx2 = pw[0];
#pragma unroll
  for (int m = 1; m < 24; m++) wmx2 = fmaxf(wmx2, pw[m]);
  float wsum = 0.f;
#pragma unroll
  for (int m = 0; m < 24; m++){ pw[m] = expf(pw[m] - wmx2); wsum += pw[m]; }
  float winv = 1.f / wsum;
#pragma unroll
  for (int m = 0; m < 24; m++){
    float c = sup * pw[m] * winv;
    float om = 1.f - c;
    Ac[row * 24 + m] *= om;
    if (t > 0) W0[row * 24 + m] *= om;
    if (t > 1) W1[row * 24 + m] *= om;
    if (t > 2) W2[row * 24 + m] *= om;
    if (t == 0)      W0[row * 24 + m] = c;
    else if (t == 1) W1[row * 24 + m] = c;
    else if (t == 2) W2[row * 24 + m] = c;
  }
  haltb[row] = 1.f / (1.f + expf(-(R(72) + hb[t])));
  // summed tail entries for downfin (73-92) and final_lite (93-102)
#pragma unroll
  for (int i = 0; i < 30; i++) routeS[row * 32 + i] = R(73 + i);
  // ballot compaction
#pragma unroll
  for (int e = 0; e < 10; e++){
    bool act = sgv[e] != 0.f;
    unsigned long long mask = __ballot(act);
    int cw = __popcll(mask);
    int b0 = 0;
    if (lane == 0 && cw > 0) b0 = atomicAdd(&cnt[e], cw);
    b0 = __shfl(b0, 0, 64);
    if (act){
      int slot = b0 + __popcll(mask & ((1ull << lane) - 1ull));
      gidx[e * N_TOK + slot] = row;
      pos[row * 10 + e] = slot;
    }
  }
}

// ---------------- downfin: expert down + LN + gated acc + step finalize --------
__global__ __launch_bounds__(256)
void downfin_kernel(const uint16_t* __restrict__ HH, const int* __restrict__ pos,
                    const float* __restrict__ ED, const float* __restrict__ sg,
                    const float* __restrict__ eng, const float* __restrict__ enb,
                    const float* __restrict__ routeS, const float* __restrict__ haltb,
                    float* __restrict__ total, float* __restrict__ cumh)
{
  int lane = threadIdx.x & 63;
  int row = blockIdx.x * 4 + (threadIdx.x >> 6);
  float out[10] = {};
  for (int e = 0; e < NEXP; e++){
    float g = sg[row * 10 + e];
    if (g != 0.0f){
      int d = c_dims[e];
      int slot = pos[row * 10 + e];
      const uint16_t* hr = HH + (size_t)N_TOK * c_offs[e] + (size_t)slot * d;
      const float* wd = ED + (size_t)e * 10 * DMAX;
      float p[10] = {};
      for (int k = lane * 2; k < d; k += 128){
        uint32_t hv2 = *(const uint32_t*)&hr[k];
        float h0 = bf2f((uint16_t)hv2), h1 = bf2f((uint16_t)(hv2 >> 16));
#pragma unroll
        for (int o = 0; o < 10; o++){
          float2 w2 = *(const float2*)&wd[o * DMAX + k];
          p[o] = fmaf(h0, w2.x, fmaf(h1, w2.y, p[o]));
        }
      }
#pragma unroll
      for (int o = 0; o < 10; o++) p[o] = wred(p[o]);
      float mean = 0.f;
#pragma unroll
      for (int o = 0; o < 10; o++) mean += p[o];
      mean *= 0.1f;
      float var = 0.f;
#pragma unroll
      for (int o = 0; o < 10; o++){ float dd = p[o] - mean; var += dd * dd; }
      var *= 0.1f;
      float rs = 1.f / sqrtf(var + 1e-5f);
#pragma unroll
      for (int o = 0; o < 10; o++)
        out[o] += g * ((p[o] - mean) * rs * eng[e * 10 + o] + enb[e * 10 + o]);
    }
  }
  if (lane == 0){
    const float* r = routeS + (size_t)row * 32;
    float rem = 1.f - cumh[row];
#pragma unroll
    for (int o = 0; o < 10; o++)
      total[row * 10 + o] += rem * (out[o] + 0.22f * r[o] + 0.14f * r[10 + o]);
    cumh[row] += rem * haltb[row];
  }
}

// ---------------- shared branch --------------------------------------------------
__global__ __launch_bounds__(256)
void shared_kernel(const float* __restrict__ shpre, const float* __restrict__ sdw,
                   const float* __restrict__ g, const float* __restrict__ b,
                   float* __restrict__ outp)
{
  int lane = threadIdx.x & 63;
  int row = blockIdx.x * 4 + (threadIdx.x >> 6);
  const float* xr = shpre + (size_t)row * SHD;
  float p[10];
#pragma unroll
  for (int o = 0; o < 10; o++) p[o] = 0.f;
  for (int k = lane; k < SHD; k += 64){
    float xv = xr[k];
#pragma unroll
    for (int o = 0; o < 10; o++) p[o] = fmaf(xv, sdw[o * SHD + k], p[o]);
  }
#pragma unroll
  for (int o = 0; o < 10; o++) p[o] = wred(p[o]);
  float mean = 0.f;
#pragma unroll
  for (int o = 0; o < 10; o++) mean += p[o];
  mean *= 0.1f;
  float var = 0.f;
#pragma unroll
  for (int o = 0; o < 10; o++){ float dd = p[o] - mean; var += dd * dd; }
  var *= 0.1f;
  float rs = 1.f / sqrtf(var + 1e-5f);
  if (lane == 0){
#pragma unroll
    for (int o = 0; o < 10; o++) outp[row * 10 + o] = (p[o] - mean) * rs * g[o] + b[o];
  }
}

// ---------------- final output (lite) --------------------------------------------
__global__ __launch_bounds__(256)
void final_lite(const float* __restrict__ qaux, const float* __restrict__ biasp,
                const float* __restrict__ sharedp, const float* __restrict__ total,
                const float* __restrict__ routeS, const float* __restrict__ sscale,
                const float* __restrict__ alphap, const float* __restrict__ betap,
                float* __restrict__ outp)
{
  int row = blockIdx.x * 256 + threadIdx.x;
  float ss = sscale[0], av = alphap[0] + 1e-4f, bv = betap[0];
#pragma unroll
  for (int o = 0; o < 10; o++)
    outp[row * 10 + o] = (qaux[(size_t)row * 128 + 64 + o] + biasp[o])
                       + ss * sharedp[row * 10 + o]
                       + av * (total[row * 10 + o] * 0.25f)
                       + bv * routeS[(size_t)row * 32 + 20 + o];
}

// ====================================================================================
extern "C" void kernel_launch(void* const* d_in, const int* in_sizes, int n_in,
                              void* d_out, int out_size, void* d_ws, size_t ws_size,
                              hipStream_t stream)
{
  const float* x     = (const float*)d_in[0];
  const float* wgt   = (const float*)d_in[1];
  const float* bias  = (const float*)d_in[2];
  const float* suw   = (const float*)d_in[3];
  const float* sdw   = (const float*)d_in[4];
  const float* sng   = (const float*)d_in[5];
  const float* snb   = (const float*)d_in[6];
  const float* sscale= (const float*)d_in[7];
  const float* keys  = (const float*)d_in[8];
  const float* mvi   = (const float*)d_in[9];
  const float* mqw   = (const float*)d_in[10];
  const float* mow   = (const float*)d_in[11];
  const float* wgw   = (const float*)d_in[12];
  const float* wgb   = (const float*)d_in[13];
  const float* wvw   = (const float*)d_in[14];
  const float* wvb   = (const float*)d_in[15];
  const float* dqw   = (const float*)d_in[16];
  const float* dkw   = (const float*)d_in[17];
  const float* dvw   = (const float*)d_in[18];
  const float* dow   = (const float*)d_in[19];
  const float* clng  = (const float*)d_in[20];
  const float* clnb  = (const float*)d_in[21];
  const float* fc1w  = (const float*)d_in[22];
  const float* fc1b  = (const float*)d_in[23];
  const float* fc2w  = (const float*)d_in[24];
  const float* fc2b  = (const float*)d_in[25];
  const float* saw   = (const float*)d_in[26];
  const float* sab   = (const float*)d_in[27];
  const float* sbw   = (const float*)d_in[28];
  const float* sbb   = (const float*)d_in[29];
  const float* msw   = (const float*)d_in[30];
  const float* msb   = (const float*)d_in[31];
  const float* mmw   = (const float*)d_in[32];
  const float* mmb   = (const float*)d_in[33];
  const float* ebias = (const float*)d_in[34];
  const float* bw    = (const float*)d_in[35];
  const float* bb    = (const float*)d_in[36];
  const float* eup   = (const float*)d_in[37];
  const float* edn   = (const float*)d_in[38];
  const float* eng   = (const float*)d_in[39];
  const float* enb   = (const float*)d_in[40];
  const float* hw    = (const float*)d_in[41];
  const float* hb    = (const float*)d_in[42];
  const float* alphap= (const float*)d_in[43];
  const float* betap = (const float*)d_in[44];
  float* outp = (float*)d_out;

  char* wsb = (char*)d_ws;
  size_t off = 0;
  auto AL = [&](size_t bytes) -> void* {
    void* p = wsb + off;
    off = (off + bytes + 255) & ~(size_t)255;
    return p;
  };
  const size_t NI = (size_t)N_TOK * IN_D;
  float* cur    = (float*)AL(NI * 4);
  float* enr    = (float*)AL(NI * 4);
  float* dqbuf  = (float*)AL(NI * 4);
  float* qaux   = (float*)AL((size_t)N_TOK * 128 * 4);
  float* routeQ = (float*)AL((size_t)4 * N_TOK * 128 * 4);
  float* routeS = (float*)AL((size_t)N_TOK * 32 * 4);
  float* trio0  = (float*)AL((size_t)N_TOK * 3072 * 4);
  float* trio1  = (float*)AL((size_t)N_TOK * 3072 * 4);
  float* trio2  = (float*)AL((size_t)N_TOK * 3072 * 4);
  float* Ac     = (float*)AL((size_t)N_TOK * 24 * 4);
  float* W0     = (float*)AL((size_t)N_TOK * 24 * 4);
  float* W1     = (float*)AL((size_t)N_TOK * 24 * 4);
  float* W2     = (float*)AL((size_t)N_TOK * 24 * 4);
  float* sg     = (float*)AL((size_t)N_TOK * 10 * 4);
  float* haltb  = (float*)AL((size_t)N_TOK * 4);
  char*  zblk   = (char*)AL((size_t)N_TOK * 10 * 4 + N_TOK * 4 + 4 * 16 * 4);
  float* total  = (float*)zblk;
  float* cumh   = (float*)(zblk + (size_t)N_TOK * 10 * 4);
  int*   cnt    = (int*)(zblk + (size_t)N_TOK * 10 * 4 + N_TOK * 4);
  int*   gidx   = (int*)AL((size_t)NEXP * N_TOK * 4);
  int*   pos    = (int*)AL((size_t)N_TOK * NEXP * 4);
  float* sharedp= (float*)AL((size_t)N_TOK * 10 * 4);
  float* cbias  = (float*)AL(3072 * 4);
  float* K2f    = (float*)AL((size_t)24 * 1024 * 4);
  uint16_t* lnh  = (uint16_t*)AL(NI * 2);
  uint16_t* lnl  = (uint16_t*)AL(NI * 2);
  uint16_t* h7h  = (uint16_t*)AL((size_t)N_TOK * INNER * 2);
  uint16_t* h7l  = (uint16_t*)AL((size_t)N_TOK * INNER * 2);
  uint16_t* Arh  = (uint16_t*)AL((size_t)N_TOK * 3072 * 2);
  uint16_t* Arl  = (uint16_t*)AL((size_t)N_TOK * 3072 * 2);
  const size_t W1M = (size_t)IN_D * IN_D;
  uint16_t* preWh  = (uint16_t*)AL((size_t)2176 * 1024 * 2);
  uint16_t* preWl  = (uint16_t*)AL((size_t)2176 * 1024 * 2);
  uint16_t* qtWh   = (uint16_t*)AL((size_t)4224 * 1024 * 2);
  uint16_t* qtWl   = (uint16_t*)AL((size_t)4224 * 1024 * 2);
  uint16_t* rtWh   = (uint16_t*)AL((size_t)4 * 128 * 3072 * 2);
  uint16_t* rtWl   = (uint16_t*)AL((size_t)4 * 128 * 3072 * 2);
  const size_t WFC = (size_t)NSTEP * INNER * IN_D;
  uint16_t* fc1wh = (uint16_t*)AL(WFC * 2); uint16_t* fc1wl = (uint16_t*)AL(WFC * 2);
  uint16_t* fc2wh = (uint16_t*)AL(WFC * 2); uint16_t* fc2wl = (uint16_t*)AL(WFC * 2);
  uint16_t* upbf  = (uint16_t*)AL((size_t)NEXP * DMAX * IN_D * 2);
  uint16_t* HHc   = (uint16_t*)AL((size_t)N_TOK * DSUM * 2);
  float* shpre  = (float*)HHc;   // alias: consumed before HHc is written

  // ---- init ----
  hipMemsetAsync(zblk, 0, (size_t)N_TOK * 10 * 4 + N_TOK * 4 + 4 * 16 * 4, stream);
  hipMemsetAsync(cbias, 0, 3072 * 4, stream);
  hipMemcpyAsync(cbias + 2048, wvb, 1024 * 4, hipMemcpyDeviceToDevice, stream);
  hipMemcpyAsync(cur, x, NI * 4, hipMemcpyDeviceToDevice, stream);
  fill1_kernel<<<(N_TOK * 24 + 255) / 256, 256, 0, stream>>>(Ac, N_TOK * 24);
  cvt_bf16_kernel<<<2048, 256, 0, stream>>>(eup, upbf, (size_t)NEXP * DMAX * IN_D);

  split_strided<<<1024, 256, 0, stream>>>(x, Arh, Arl, N_TOK, 1024, 3072);
  split_kernel<<<1024, 256, 0, stream>>>(suw, preWh, preWl, (size_t)SHD * 1024);
  split_kernel<<<256, 256, 0, stream>>>(saw, preWh + (size_t)2072*1024, preWl + (size_t)2072*1024, (size_t)40 * 1024);
  split_kernel<<<256, 256, 0, stream>>>(wgt, preWh + (size_t)2112*1024, preWl + (size_t)2112*1024, (size_t)10 * 1024);
  hipMemsetAsync(preWh + (size_t)2122*1024, 0, (size_t)54 * 1024 * 2, stream);
  hipMemsetAsync(preWl + (size_t)2122*1024, 0, (size_t)54 * 1024 * 2, stream);
  split_kernel<<<1024, 256, 0, stream>>>(dqw, qtWh, qtWl, W1M);
  split_kernel<<<1024, 256, 0, stream>>>(dkw, qtWh + W1M, qtWl + W1M, W1M);
  split_kernel<<<1024, 256, 0, stream>>>(dvw, qtWh + 2*W1M, qtWl + 2*W1M, W1M);
  split_kernel<<<1024, 256, 0, stream>>>(wvw, qtWh + 3*W1M, qtWl + 3*W1M, W1M);
  split_kernel<<<256, 256, 0, stream>>>(saw, qtWh + (size_t)4120*1024, qtWl + (size_t)4120*1024, (size_t)40 * 1024);
  hipMemsetAsync(qtWh + (size_t)4160*1024, 0, (size_t)64 * 1024 * 2, stream);
  hipMemsetAsync(qtWl + (size_t)4160*1024, 0, (size_t)64 * 1024 * 2, stream);
  k2_kernel<<<dim3(24, 4), 256, 0, stream>>>(keys, mqw, K2f);
  split_kernel<<<256, 256, 0, stream>>>(K2f, preWh + (size_t)2048*1024, preWl + (size_t)2048*1024, (size_t)24 * 1024);
  split_kernel<<<256, 256, 0, stream>>>(K2f, qtWh + (size_t)4096*1024, qtWl + (size_t)4096*1024, (size_t)24 * 1024);
  build_routew<<<2048, 256, 0, stream>>>(msw, mmw, bw, wgw, hw, mow, dow, rtWh, rtWl);
  split_kernel<<<1024, 256, 0, stream>>>(fc1w, fc1wh, fc1wl, WFC);
  split_kernel<<<1024, 256, 0, stream>>>(fc2w, fc2wh, fc2wl, WFC);

  gemm_sp<EPI_PRE><<<dim3(17, 16), 256, 0, stream>>>(
      Arh, Arl, 3072, preWh, preWl, nullptr, nullptr,
      shpre, qaux, nullptr, nullptr, nullptr, IN_D, 2176);
  shared_kernel<<<512, 256, 0, stream>>>(shpre, sdw, sng, snb, sharedp);

  float* trioB[3] = {trio0, trio1, trio2};

  for (int t = 0; t < NSTEP; t++){
    ctx_enr_kernel<<<2048, 256, 0, stream>>>(qaux, dqbuf, Ac, W0, W1, W2, mvi,
                                             trio0, trio1, trio2, cur, sab, sbw, sbb,
                                             clng, clnb, enr, lnh, lnl, Arh, Arl, t);
    gemm_sp<EPI_GELU><<<dim3(INNER/128, 16), 256, 0, stream>>>(
        lnh, lnl, 1024, fc1wh + (size_t)t * INNER * IN_D, fc1wl + (size_t)t * INNER * IN_D,
        fc1b + t * INNER, nullptr, nullptr, nullptr, nullptr, h7h, h7l, IN_D, INNER);
    gemm_sp<EPI_CUR><<<dim3(8, 16), 256, 0, stream>>>(
        h7h, h7l, 768, fc2wh + (size_t)t * IN_D * INNER, fc2wl + (size_t)t * IN_D * INNER,
        fc2b + t * IN_D, enr, cur, nullptr, nullptr, Arh, Arl, INNER, IN_D);
    gemm_sp<EPI_ROUTE><<<dim3(4, 16), 256, 0, stream>>>(
        Arh, Arl, 3072, rtWh + (size_t)t * 128 * 3072, rtWl + (size_t)t * 128 * 3072,
        nullptr, nullptr, routeQ, nullptr, nullptr, nullptr, nullptr, 3072, 128);
    route_fin<<<8, 256, 0, stream>>>(routeQ, mmb, msb, ebias, bb, wgb, hb,
                                     sg, haltb, Ac, W0, W1, W2,
                                     cnt + t * 16, gidx, pos, routeS, t);
    expert_up_mfma<<<dim3(16, 188), 256, 0, stream>>>(Arh, upbf, cnt + t * 16, gidx, HHc);
    downfin_kernel<<<512, 256, 0, stream>>>(HHc, pos, edn, sg, eng, enb,
                                            routeS, haltb, total, cumh);
    if (t < 3)
      gemm_sp<EPI_QTRIO><<<dim3(33, 16), 256, 0, stream>>>(
          Arh, Arl, 3072, qtWh, qtWl, cbias, nullptr,
          dqbuf, trioB[t], qaux, nullptr, nullptr, IN_D, 4224);
  }
  final_lite<<<8, 256, 0, stream>>>(qaux, bias, sharedp, total, routeS,
                                    sscale, alphap, betap, outp);
}

// Round 9
// 2613.242 us; speedup vs baseline: 1.7544x; 1.0357x over previous
//
#include <hip/hip_runtime.h>
#include <stdint.h>

#define N_TOK 2048
#define IN_D  1024
#define NEXP  10
#define NSTEP 4
#define INNER 768
#define SHD   2048
#define DMAX  3328
#define DSUM  24064

typedef __attribute__((ext_vector_type(4))) float f32x4;
typedef __attribute__((ext_vector_type(8))) short bf16x8;

__device__ const int c_dims[10] = {1536,2048,2560,3072,1792,2304,2816,2048,2560,3328};
__device__ const int c_offs[10] = {0,1536,3584,6144,9216,11008,13312,16128,18176,20736};
__device__ const int c_acts[10] = {0,1,2,3,4,5,6,7,0,1};
__device__ const int c_cum[11]  = {0,12,28,48,72,86,104,126,142,162,188};

__device__ __forceinline__ float wred(float v){
#pragma unroll
  for (int s = 32; s > 0; s >>= 1) v += __shfl_xor(v, s, 64);
  return v;
}
__device__ __forceinline__ float wmax(float v){
#pragma unroll
  for (int s = 32; s > 0; s >>= 1) v = fmaxf(v, __shfl_xor(v, s, 64));
  return v;
}
__device__ __forceinline__ float bf2f(uint16_t u){
  return __uint_as_float(((uint32_t)u) << 16);
}
__device__ __forceinline__ uint16_t f2bf(float f){
  uint32_t u = __float_as_uint(f);
  return (uint16_t)((u + 0x7FFFu + ((u >> 16) & 1u)) >> 16);
}
__device__ __forceinline__ void gload16(const uint16_t* g, uint16_t* l){
  __builtin_amdgcn_global_load_lds(
      (const __attribute__((address_space(1))) uint32_t*)(const void*)g,
      (__attribute__((address_space(3))) uint32_t*)(void*)l, 16, 0, 0);
}

__device__ __forceinline__ float actf(int a, float x){
  switch(a){
    case 0: return x / (1.f + expf(-x));
    case 1: return 0.5f * x * (1.f + erff(x * 0.7071067811865475f));
    case 2: { float sp = fmaxf(x,0.f) + log1pf(expf(-fabsf(x)));
              return x * tanhf(sp); }
    case 3: return fmaxf(x, 0.f);
    case 4: return x > 0.f ? 1.0507009873554805f * x
                           : 1.7580993408473768f * expm1f(x);
    case 5: return tanhf(x);
    case 6: return fmaxf(x,0.f) + log1pf(expf(-fabsf(x)));
    default: return x > 0.f ? x : expm1f(x);
  }
}

// ---------------- f32 -> (hi, lo) bf16 split, contiguous ------------------------
__global__ void split_kernel(const float* __restrict__ src, uint16_t* __restrict__ hi,
                             uint16_t* __restrict__ lo, size_t n){
  size_t i = ((size_t)blockIdx.x * blockDim.x + threadIdx.x) << 2;
  size_t stride = ((size_t)gridDim.x * blockDim.x) << 2;
  for (; i < n; i += stride){
    float4 v = *(const float4*)(src + i);
    ushort4 h, l;
    h.x = f2bf(v.x); l.x = f2bf(v.x - bf2f(h.x));
    h.y = f2bf(v.y); l.y = f2bf(v.y - bf2f(h.y));
    h.z = f2bf(v.z); l.z = f2bf(v.z - bf2f(h.z));
    h.w = f2bf(v.w); l.w = f2bf(v.w - bf2f(h.w));
    *(ushort4*)(hi + i) = h;
    *(ushort4*)(lo + i) = l;
  }
}
__global__ void split_strided(const float* __restrict__ src, uint16_t* __restrict__ hi,
                              uint16_t* __restrict__ lo, int rows, int cols, int ldd){
  int nq = rows * (cols >> 2);
  for (int i = blockIdx.x * blockDim.x + threadIdx.x; i < nq; i += gridDim.x * blockDim.x){
    int r = i / (cols >> 2), c4 = (i - r * (cols >> 2)) << 2;
    float4 v = *(const float4*)(src + (size_t)r * cols + c4);
    ushort4 h, l;
    h.x = f2bf(v.x); l.x = f2bf(v.x - bf2f(h.x));
    h.y = f2bf(v.y); l.y = f2bf(v.y - bf2f(h.y));
    h.z = f2bf(v.z); l.z = f2bf(v.z - bf2f(h.z));
    h.w = f2bf(v.w); l.w = f2bf(v.w - bf2f(h.w));
    size_t d = (size_t)r * ldd + c4;
    *(ushort4*)(hi + d) = h;
    *(ushort4*)(lo + d) = l;
  }
}
__global__ void cvt_bf16_kernel(const float* __restrict__ src, uint16_t* __restrict__ dst, size_t n){
  size_t i = ((size_t)blockIdx.x * blockDim.x + threadIdx.x) << 2;
  size_t stride = ((size_t)gridDim.x * blockDim.x) << 2;
  for (; i < n; i += stride){
    float4 v = *(const float4*)(src + i);
    ushort4 h;
    h.x = f2bf(v.x); h.y = f2bf(v.y); h.z = f2bf(v.z); h.w = f2bf(v.w);
    *(ushort4*)(dst + i) = h;
  }
}
__global__ void fill1_kernel(float* __restrict__ p, int n){
  int i = blockIdx.x * blockDim.x + threadIdx.x;
  if (i < n) p[i] = 1.f;
}

// ---------------- K2 = keys @ mqw  [24,1024] ------------------------------------
__global__ __launch_bounds__(256)
void k2_kernel(const float* __restrict__ keys, const float* __restrict__ mqw,
               float* __restrict__ K2){
  int m = blockIdx.x;
  int j = blockIdx.y * 256 + threadIdx.x;
  float acc = 0.f;
  for (int d = 0; d < 1024; d++)
    acc = fmaf(keys[m * 1024 + d], mqw[d * 1024 + j], acc);
  K2[m * 1024 + j] = acc;
}

// ---------------- route weight builder: 4 x [128 rows x 3072] -------------------
__global__ void build_routew(const float* __restrict__ msw, const float* __restrict__ mmw,
                             const float* __restrict__ bw, const float* __restrict__ wgw,
                             const float* __restrict__ hw, const float* __restrict__ mow,
                             const float* __restrict__ dow, uint16_t* __restrict__ Wh,
                             uint16_t* __restrict__ Wl){
  const int TOT = 4 * 128 * 3072;
  for (int i = blockIdx.x * 256 + threadIdx.x; i < TOT; i += gridDim.x * 256){
    int t = i / (128 * 3072);
    int rem = i - t * (128 * 3072);
    int row = rem / 3072, col = rem - row * 3072;
    float v = 0.f;
    if (row < 40){ if (col < 1024) v = msw[row * 1024 + col]; }
    else if (row < 44){ if (col < 1024) v = mmw[(row - 40) * 1024 + col]; }
    else if (row < 48){ if (col < 1024) v = bw[(row - 44) * 1024 + col]; }
    else if (row < 72){ if (col < 2048) v = wgw[(row - 48) * 2048 + col]; }
    else if (row == 72){
      if (col < 1024) v = hw[t * 1024 + col];
      else if (col < 2048) v = 0.2f * hw[t * 1024 + col - 1024];
      else v = 0.1f * hw[t * 1024 + col - 2048];
    }
    else if (row < 83){ if (col >= 1024 && col < 2048) v = mow[(row - 73) * 1024 + col - 1024]; }
    else if (row < 93){ if (col >= 2048) v = dow[(row - 83) * 1024 + col - 2048]; }
    else if (row < 103){ if (col < 1024) v = mow[(row - 93) * 1024 + col]; }
    uint16_t h = f2bf(v);
    Wh[i] = h; Wl[i] = f2bf(v - bf2f(h));
  }
}

// ---------------- split-bf16 MFMA GEMM, counted-vmcnt 2-deep pipeline -----------
// LDS: unit u holds global chunk ((u&3)^((u>>3)&3)) of row (u>>2).
// Fragment read (R,g): u = R*4 + (g ^ ((R>>1)&3)).
// K-loop: stage ki+2 issued after post-compute barrier; waits are vmcnt(8)
// (one stage = 8 loads/thread in flight), never 0 until the final iteration.
enum { EPI_GELU=0, EPI_CUR=1, EPI_PRE=2, EPI_QTRIO=3, EPI_ROUTE=4 };

template<int EPI>
__global__ __launch_bounds__(256)
void gemm_sp(const uint16_t* __restrict__ Ah, const uint16_t* __restrict__ Al, int lda,
             const uint16_t* __restrict__ Wh, const uint16_t* __restrict__ Wl,
             const float* __restrict__ bias, const float* __restrict__ addend,
             float* __restrict__ D0, float* __restrict__ D1, float* __restrict__ D2,
             uint16_t* __restrict__ oH, uint16_t* __restrict__ oL,
             int K, int D)
{
  __shared__ __align__(16) uint16_t sm[4][2][4096];
  int tid = threadIdx.x, lane = tid & 63, wave = tid >> 6;
  int wr = wave >> 1, wc = wave & 1;
  int arow = lane & 15, agrp = lane >> 4;
  int rowBase = blockIdx.y * 128;
  int colBase = (EPI == EPI_ROUTE) ? 0 : blockIdx.x * 128;
  int kBase   = (EPI == EPI_ROUTE) ? blockIdx.x * 768 : 0;
  int kLen    = (EPI == EPI_ROUTE) ? 768 : K;
  f32x4 acc[4][4];
#pragma unroll
  for (int m = 0; m < 4; m++)
#pragma unroll
    for (int n = 0; n < 4; n++){ f32x4 z = {0.f,0.f,0.f,0.f}; acc[m][n] = z; }

#define STAGE_G(buf, k0) do { \
  _Pragma("unroll") \
  for (int s = 0; s < 2; s++){ \
    int u = tid + s * 256; \
    int rr = u >> 2; \
    int ch = (u & 3) ^ ((rr >> 1) & 3); \
    size_t ga = (size_t)(rowBase + rr) * lda + kBase + (k0) + ch * 8; \
    size_t gw = (size_t)(colBase + rr) * K + kBase + (k0) + ch * 8; \
    gload16(&Ah[ga], &sm[0][buf][u << 3]); \
    gload16(&Al[ga], &sm[1][buf][u << 3]); \
    gload16(&Wh[gw], &sm[2][buf][u << 3]); \
    gload16(&Wl[gw], &sm[3][buf][u << 3]); \
  } } while(0)

  int nk = kLen >> 5;
  STAGE_G(0, 0);
  if (nk > 1) STAGE_G(1, 32);
  int perm = (arow >> 1) & 3;
#pragma unroll 1
  for (int ki = 0; ki < nk; ki++){
    int cb = ki & 1;
    // wait for stage ki to land; stage ki+1 (8 loads) may remain in flight
    if (ki + 1 < nk) asm volatile("s_waitcnt vmcnt(8)" ::: "memory");
    else             asm volatile("s_waitcnt vmcnt(0)" ::: "memory");
    __builtin_amdgcn_s_barrier();
    bf16x8 ah[4], al[4], bh[4], bl[4];
#pragma unroll
    for (int m = 0; m < 4; m++){
      int u = ((wr*64 + m*16 + arow) << 2) + (agrp ^ perm);
      ah[m] = *(const bf16x8*)&sm[0][cb][u << 3];
      al[m] = *(const bf16x8*)&sm[1][cb][u << 3];
    }
#pragma unroll
    for (int n = 0; n < 4; n++){
      int u = ((wc*64 + n*16 + arow) << 2) + (agrp ^ perm);
      bh[n] = *(const bf16x8*)&sm[2][cb][u << 3];
      bl[n] = *(const bf16x8*)&sm[3][cb][u << 3];
    }
#pragma unroll
    for (int m = 0; m < 4; m++)
#pragma unroll
      for (int n = 0; n < 4; n++){
        acc[m][n] = __builtin_amdgcn_mfma_f32_16x16x32_bf16(ah[m], bh[n], acc[m][n], 0, 0, 0);
        acc[m][n] = __builtin_amdgcn_mfma_f32_16x16x32_bf16(ah[m], bl[n], acc[m][n], 0, 0, 0);
        acc[m][n] = __builtin_amdgcn_mfma_f32_16x16x32_bf16(al[m], bh[n], acc[m][n], 0, 0, 0);
      }
    __builtin_amdgcn_s_barrier();
    asm volatile("" ::: "memory");
    if (ki + 2 < nk) STAGE_G(cb, (ki + 2) << 5);
  }
#undef STAGE_G
#pragma unroll
  for (int m = 0; m < 4; m++){
#pragma unroll
    for (int n = 0; n < 4; n++){
      int col = colBase + wc*64 + n*16 + arow;
#pragma unroll
      for (int r2 = 0; r2 < 4; r2++){
        int row = rowBase + wr*64 + m*16 + agrp*4 + r2;
        float v = acc[m][n][r2];
        if (EPI == EPI_GELU){
          v += bias[col];
          v = 0.5f * v * (1.f + erff(v * 0.7071067811865475f));
          size_t idx = (size_t)row * D + col;
          uint16_t h = f2bf(v); oH[idx] = h; oL[idx] = f2bf(v - bf2f(h));
        }
        if (EPI == EPI_CUR){
          v += bias[col] + addend[(size_t)row * 1024 + col];
          D0[(size_t)row * 1024 + col] = v;
          size_t idx = (size_t)row * 3072 + col;
          uint16_t h = f2bf(v); oH[idx] = h; oL[idx] = f2bf(v - bf2f(h));
        }
        if (EPI == EPI_PRE){
          if (col < 2048) D0[(size_t)row * 2048 + col] = v / (1.f + expf(-v));
          else D1[(size_t)row * 128 + col - 2048] = v;
        }
        if (EPI == EPI_QTRIO){
          if (col < 1024) D0[(size_t)row * 1024 + col] = v;
          else if (col < 4096) D1[(size_t)row * 3072 + col - 1024] = v + bias[col - 1024];
          else if (col < 4160) D2[(size_t)row * 128 + col - 4096] = v;
        }
        if (EPI == EPI_ROUTE)
          D0[((size_t)blockIdx.x * N_TOK + row) * 128 + col] = v;
      }
    }
  }
}

// ---------------- sparse expert up: 128x128 tile, counted-vmcnt pipeline --------
__global__ __launch_bounds__(256)
void expert_up_mfma(const uint16_t* __restrict__ Abf, const uint16_t* __restrict__ Ubf,
                    const int* __restrict__ cnt, const int* __restrict__ gidx,
                    uint16_t* __restrict__ HH)
{
  int y = blockIdx.y;
  int e = 0;
#pragma unroll
  for (int i = 1; i < 11; i++) if (y >= c_cum[i]) e = i;
  int ct = y - c_cum[e];
  int dcols = c_dims[e];
  int ne = cnt[e];
  int rowBase = blockIdx.x * 128;
  if (rowBase >= ne) return;
  const uint16_t* W = Ubf + (size_t)e * DMAX * IN_D + (size_t)ct * 128 * IN_D;

  __shared__ __align__(16) uint16_t smem[16384];
  uint16_t* sA = smem;
  uint16_t* sB = smem + 8192;
  int tid = threadIdx.x, lane = tid & 63, wave = tid >> 6;
  int wr = wave >> 1, wc = wave & 1;
  int arow = lane & 15, agrp = lane >> 4;

  int r0 = rowBase + (tid >> 2);
  int tok0 = (r0 < ne) ? gidx[e * N_TOK + r0] : 0;
  int tok1 = (r0 + 64 < ne) ? gidx[e * N_TOK + r0 + 64] : 0;

  f32x4 acc[4][4];
#pragma unroll
  for (int m = 0; m < 4; m++)
#pragma unroll
    for (int n = 0; n < 4; n++){ f32x4 z = {0.f,0.f,0.f,0.f}; acc[m][n] = z; }

#define STAGE_E(buf, k0) do { \
  _Pragma("unroll") \
  for (int s = 0; s < 2; s++){ \
    int u = tid + s * 256; \
    int rr = u >> 2; \
    int ch = (u & 3) ^ ((rr >> 1) & 3); \
    int tk = (s == 0) ? tok0 : tok1; \
    gload16(&Abf[(size_t)tk * 3072 + (k0) + ch * 8], &sA[((buf) * 512 + u) << 3]); \
    gload16(&W[(size_t)rr * IN_D + (k0) + ch * 8],   &sB[((buf) * 512 + u) << 3]); \
  } } while(0)

  STAGE_E(0, 0);
  STAGE_E(1, 32);
  int perm = (arow >> 1) & 3;
#pragma unroll 1
  for (int ki = 0; ki < 32; ki++){
    int cb = ki & 1;
    // wait for stage ki; stage ki+1 (4 loads/thread) may remain in flight
    if (ki + 1 < 32) asm volatile("s_waitcnt vmcnt(4)" ::: "memory");
    else             asm volatile("s_waitcnt vmcnt(0)" ::: "memory");
    __builtin_amdgcn_s_barrier();
    bf16x8 a[4], b[4];
#pragma unroll
    for (int m = 0; m < 4; m++){
      int u = cb * 512 + ((wr*64 + m*16 + arow) << 2) + (agrp ^ perm);
      a[m] = *(const bf16x8*)&sA[u << 3];
    }
#pragma unroll
    for (int n = 0; n < 4; n++){
      int u = cb * 512 + ((wc*64 + n*16 + arow) << 2) + (agrp ^ perm);
      b[n] = *(const bf16x8*)&sB[u << 3];
    }
#pragma unroll
    for (int m = 0; m < 4; m++)
#pragma unroll
      for (int n = 0; n < 4; n++)
        acc[m][n] = __builtin_amdgcn_mfma_f32_16x16x32_bf16(a[m], b[n], acc[m][n], 0, 0, 0);
    __builtin_amdgcn_s_barrier();
    asm volatile("" ::: "memory");
    if (ki + 2 < 32) STAGE_E(cb, (ki + 2) << 5);
  }
#undef STAGE_E
  int actid = c_acts[e];
  uint16_t* Ht = smem;
#pragma unroll
  for (int m = 0; m < 4; m++){
    int rb0 = wr*64 + m*16 + agrp*4;
#pragma unroll
    for (int n = 0; n < 4; n++){
      int col = wc*64 + n*16 + arow;
#pragma unroll
      for (int r2 = 0; r2 < 4; r2++){
        int row = rb0 + r2;
        float v = actf(actid, acc[m][n][r2]);
        Ht[row * 128 + (col ^ ((row & 7) << 3))] = f2bf(v);
      }
    }
  }
  __syncthreads();
  size_t base_e = (size_t)N_TOK * c_offs[e];
#pragma unroll
  for (int i = 0; i < 8; i++){
    int c = tid + i * 256;
    int row = c >> 4, chunk = c & 15;
    int schunk = (chunk & 8) | ((chunk ^ row) & 7);
    int4 val = *(const int4*)&Ht[row * 128 + schunk * 8];
    *(int4*)&HH[base_e + (size_t)(rowBase + row) * dcols
                + (size_t)ct * 128 + chunk * 8] = val;
  }
}

// ---------------- ctx_enr: mem softmax, depth attn, mctx/dctx/enriched/LN ------
__global__ __launch_bounds__(256)
void ctx_enr_kernel(const float* __restrict__ qaux, const float* __restrict__ dqbuf,
                    const float* __restrict__ Ac, const float* __restrict__ W0,
                    const float* __restrict__ W1, const float* __restrict__ W2,
                    const float* __restrict__ mvi,
                    const float* __restrict__ t0, const float* __restrict__ t1,
                    const float* __restrict__ t2, const float* __restrict__ cur,
                    const float* __restrict__ sab, const float* __restrict__ sbw,
                    const float* __restrict__ sbb, const float* __restrict__ lng,
                    const float* __restrict__ lnbv,
                    float* __restrict__ enr, uint16_t* __restrict__ lnh,
                    uint16_t* __restrict__ lnl, uint16_t* __restrict__ Arh,
                    uint16_t* __restrict__ Arl, int t)
{
  int row = blockIdx.x, tid = threadIdx.x;
  __shared__ float su[24], ss[3], s40[40], red[12], redm[8];
  if (tid < 64){
    float pj = (tid < 24) ? qaux[(size_t)row * 128 + tid] * 0.03125f : -1e30f;
    float mx = wmax(pj);
    float ex = (tid < 24) ? expf(pj - mx) : 0.f;
    float sum = wred(ex);
    float attn = ex / sum;
    if (tid < 24) su[tid] = attn * Ac[row * 24 + tid];
    float w0v = (t > 0 && tid < 24) ? W0[row * 24 + tid] : 0.f;
    float s0 = wred(attn * w0v);
    float w1v = (t > 1 && tid < 24) ? W1[row * 24 + tid] : 0.f;
    float s1 = wred(attn * w1v);
    float w2v = (t > 2 && tid < 24) ? W2[row * 24 + tid] : 0.f;
    float s2 = wred(attn * w2v);
    if (tid == 0){ ss[0] = s0; ss[1] = s1; ss[2] = s2; }
    if (tid < 40) s40[tid] = tanhf(qaux[(size_t)row * 128 + 24 + tid] + sab[tid]);
  }
  size_t tb = (size_t)row * 3072;
  if (t > 0){
    float a0 = 0.f, a1 = 0.f, a2 = 0.f;
#pragma unroll
    for (int j = 0; j < 4; j++){
      int d = tid + j * 256;
      float dq = dqbuf[(size_t)row * 1024 + d];
      a0 = fmaf(dq, t0[tb + d], a0);
      if (t > 1) a1 = fmaf(dq, t1[tb + d], a1);
      if (t > 2) a2 = fmaf(dq, t2[tb + d], a2);
    }
    a0 = wred(a0); a1 = wred(a1); a2 = wred(a2);
    if ((tid & 63) == 0){ int w = tid >> 6; red[w] = a0; red[4+w] = a1; red[8+w] = a2; }
  }
  __syncthreads();
  float e0 = 0.f, e1 = 0.f, e2 = 0.f;
  if (t > 0){
    float A0 = (red[0]+red[1]+red[2]+red[3]) * 0.03125f;
    float A1 = (red[4]+red[5]+red[6]+red[7]) * 0.03125f;
    float A2 = (red[8]+red[9]+red[10]+red[11]) * 0.03125f;
    float dmx = A0;
    if (t > 1) dmx = fmaxf(dmx, A1);
    if (t > 2) dmx = fmaxf(dmx, A2);
    e0 = expf(A0 - dmx);
    e1 = (t > 1) ? expf(A1 - dmx) : 0.f;
    e2 = (t > 2) ? expf(A2 - dmx) : 0.f;
    float dinv = 1.f / (e0 + e1 + e2);
    e0 *= dinv; e1 *= dinv; e2 *= dinv;
  }
  size_t ar = (size_t)row * 3072;
  float ev[4];
  float part = 0.f;
#pragma unroll
  for (int j = 0; j < 4; j++){
    int d = tid + j * 256;
    size_t idx = (size_t)row * IN_D + d;
    float mv = 0.f;
#pragma unroll
    for (int m = 0; m < 24; m++) mv = fmaf(su[m], mvi[m * IN_D + d], mv);
    float dv = 0.f;
    if (t > 0){
      mv = fmaf(ss[0], t0[tb + 2048 + d], mv);
      dv = e0 * t0[tb + 1024 + d];
      if (t > 1){ mv = fmaf(ss[1], t1[tb + 2048 + d], mv); dv = fmaf(e1, t1[tb + 1024 + d], dv); }
      if (t > 2){ mv = fmaf(ss[2], t2[tb + 2048 + d], mv); dv = fmaf(e2, t2[tb + 1024 + d], dv); }
    }
    float sv = sbb[d];
#pragma unroll
    for (int o = 0; o < 40; o++) sv = fmaf(s40[o], sbw[d * 40 + o], sv);
    float v = cur[idx] + 0.34f * mv + 0.22f * dv + 0.18f * sv;
    uint16_t mh = f2bf(mv);
    Arh[ar + 1024 + d] = mh; Arl[ar + 1024 + d] = f2bf(mv - bf2f(mh));
    uint16_t dh = f2bf(dv);
    Arh[ar + 2048 + d] = dh; Arl[ar + 2048 + d] = f2bf(dv - bf2f(dh));
    ev[j] = v; part += v;
  }
  part = wred(part);
  if ((tid & 63) == 0) redm[tid >> 6] = part;
  __syncthreads();
  float mean = (redm[0] + redm[1] + redm[2] + redm[3]) * (1.f / 1024.f);
  float vp = 0.f;
#pragma unroll
  for (int j = 0; j < 4; j++){ float dd = ev[j] - mean; vp += dd * dd; }
  vp = wred(vp);
  if ((tid & 63) == 0) redm[4 + (tid >> 6)] = vp;
  __syncthreads();
  float var = (redm[4] + redm[5] + redm[6] + redm[7]) * (1.f / 1024.f);
  float rs = 1.f / sqrtf(var + 1e-5f);
#pragma unroll
  for (int j = 0; j < 4; j++){
    int d = tid + j * 256;
    size_t idx = (size_t)row * IN_D + d;
    enr[idx] = ev[j];
    float v = (ev[j] - mean) * rs * lng[t * IN_D + d] + lnbv[t * IN_D + d];
    uint16_t h = f2bf(v);
    lnh[idx] = h;
    lnl[idx] = f2bf(v - bf2f(h));
  }
}

// ---------------- route_fin: sums 4 K-split partials, softmaxes, top-k ----------
__global__ __launch_bounds__(256)
void route_fin(const float* __restrict__ ROq, const float* __restrict__ mmb,
               const float* __restrict__ msb, const float* __restrict__ ebias,
               const float* __restrict__ bb, const float* __restrict__ wgb,
               const float* __restrict__ hb,
               float* __restrict__ sg, float* __restrict__ haltb,
               float* __restrict__ Ac, float* __restrict__ W0,
               float* __restrict__ W1, float* __restrict__ W2,
               int* __restrict__ cnt, int* __restrict__ gidx,
               int* __restrict__ pos, float* __restrict__ routeS, int t)
{
  int row = blockIdx.x * 256 + threadIdx.x;
  int lane = threadIdx.x & 63;
  const size_t P = (size_t)N_TOK * 128;
  const float* r0 = ROq + (size_t)row * 128;
  const float* r1 = r0 + P;
  const float* r2 = r0 + 2 * P;
  const float* r3 = r0 + 3 * P;
  auto R = [&](int j){ return r0[j] + r1[j] + r2[j] + r3[j]; };
  float pm[4];
#pragma unroll
  for (int o = 0; o < 4; o++) pm[o] = R(40 + o) + mmb[o];
  float mmx = fmaxf(fmaxf(pm[0], pm[1]), fmaxf(pm[2], pm[3]));
  float msum = 0.f;
#pragma unroll
  for (int o = 0; o < 4; o++){ pm[o] = expf(pm[o] - mmx); msum += pm[o]; }
  float minv = 1.f / msum;
  float gl[10];
#pragma unroll
  for (int e = 0; e < 10; e++){
    float g = ebias[e];
#pragma unroll
    for (int s2 = 0; s2 < 4; s2++)
      g = fmaf(pm[s2] * minv, R(s2 * 10 + e) + msb[s2 * 10 + e], g);
    gl[e] = g;
  }
  float gmx = gl[0];
#pragma unroll
  for (int e = 1; e < 10; e++) gmx = fmaxf(gmx, gl[e]);
  float gs = 0.f;
#pragma unroll
  for (int e = 0; e < 10; e++){ gl[e] = expf(gl[e] - gmx); gs += gl[e]; }
  float ginv = 1.f / gs;
#pragma unroll
  for (int e = 0; e < 10; e++) gl[e] *= ginv;
  float pb0 = R(44) + bb[0], pb1 = R(45) + bb[1], pb2 = R(46) + bb[2], pb3 = R(47) + bb[3];
  int bud = 1; float bbest = pb0;
  if (pb1 > bbest){ bbest = pb1; bud = 2; }
  if (pb2 > bbest){ bbest = pb2; bud = 3; }
  if (pb3 > bbest){ bbest = pb3; bud = 4; }
  float tv[4]; int ti[4]; unsigned used = 0;
#pragma unroll
  for (int j = 0; j < 4; j++){
    float best = -1e30f; int bi = 0;
#pragma unroll
    for (int e = 0; e < 10; e++){
      bool ok = (!((used >> e) & 1u)) && (gl[e] > best);
      if (ok){ best = gl[e]; bi = e; }
    }
    tv[j] = best; ti[j] = bi; used |= (1u << bi);
  }
  float ssum = tv[0];
  if (bud > 1) ssum += tv[1];
  if (bud > 2) ssum += tv[2];
  if (bud > 3) ssum += tv[3];
  float den = fmaxf(ssum, 1e-6f);
  float sup = 1.f - tv[0] / den;
  float sgv[10];
#pragma unroll
  for (int e = 0; e < 10; e++){
    float sv = 0.f;
#pragma unroll
    for (int j = 0; j < 4; j++) if (j < bud && ti[j] == e) sv = tv[j] / den;
    sgv[e] = sv;
    sg[row * 10 + e] = sv;
  }
  float pw[24];
#pragma unroll
  for (int m = 0; m < 24; m++) pw[m] = R(48 + m) + wgb[m];
  float wmx2 = pw[0];
#pragma unroll
  for (int m = 1; m < 24; m++) wmx2 = fmaxf(wmx2, pw[m]);
  float wsum = 0.f;
#pragma unroll
  for (int m = 0; m < 24; m++){ pw[m] = expf(pw[m] - wmx2); wsum += pw[m]; }
  float winv = 1.f / wsum;
#pragma unroll
  for (int m = 0; m < 24; m++){
    float c = sup * pw[m] * winv;
    float om = 1.f - c;
    Ac[row * 24 + m] *= om;
    if (t > 0) W0[row * 24 + m] *= om;
    if (t > 1) W1[row * 24 + m] *= om;
    if (t > 2) W2[row * 24 + m] *= om;
    if (t == 0)      W0[row * 24 + m] = c;
    else if (t == 1) W1[row * 24 + m] = c;
    else if (t == 2) W2[row * 24 + m] = c;
  }
  haltb[row] = 1.f / (1.f + expf(-(R(72) + hb[t])));
#pragma unroll
  for (int i = 0; i < 30; i++) routeS[row * 32 + i] = R(73 + i);
#pragma unroll
  for (int e = 0; e < 10; e++){
    bool act = sgv[e] != 0.f;
    unsigned long long mask = __ballot(act);
    int cw = __popcll(mask);
    int b0 = 0;
    if (lane == 0 && cw > 0) b0 = atomicAdd(&cnt[e], cw);
    b0 = __shfl(b0, 0, 64);
    if (act){
      int slot = b0 + __popcll(mask & ((1ull << lane) - 1ull));
      gidx[e * N_TOK + slot] = row;
      pos[row * 10 + e] = slot;
    }
  }
}

// ---------------- downfin: expert down + LN + gated acc + step finalize --------
__global__ __launch_bounds__(256)
void downfin_kernel(const uint16_t* __restrict__ HH, const int* __restrict__ pos,
                    const float* __restrict__ ED, const float* __restrict__ sg,
                    const float* __restrict__ eng, const float* __restrict__ enb,
                    const float* __restrict__ routeS, const float* __restrict__ haltb,
                    float* __restrict__ total, float* __restrict__ cumh)
{
  int lane = threadIdx.x & 63;
  int row = blockIdx.x * 4 + (threadIdx.x >> 6);
  float out[10] = {};
  for (int e = 0; e < NEXP; e++){
    float g = sg[row * 10 + e];
    if (g != 0.0f){
      int d = c_dims[e];
      int slot = pos[row * 10 + e];
      const uint16_t* hr = HH + (size_t)N_TOK * c_offs[e] + (size_t)slot * d;
      const float* wd = ED + (size_t)e * 10 * DMAX;
      float p[10] = {};
      for (int k = lane * 2; k < d; k += 128){
        uint32_t hv2 = *(const uint32_t*)&hr[k];
        float h0 = bf2f((uint16_t)hv2), h1 = bf2f((uint16_t)(hv2 >> 16));
#pragma unroll
        for (int o = 0; o < 10; o++){
          float2 w2 = *(const float2*)&wd[o * DMAX + k];
          p[o] = fmaf(h0, w2.x, fmaf(h1, w2.y, p[o]));
        }
      }
#pragma unroll
      for (int o = 0; o < 10; o++) p[o] = wred(p[o]);
      float mean = 0.f;
#pragma unroll
      for (int o = 0; o < 10; o++) mean += p[o];
      mean *= 0.1f;
      float var = 0.f;
#pragma unroll
      for (int o = 0; o < 10; o++){ float dd = p[o] - mean; var += dd * dd; }
      var *= 0.1f;
      float rs = 1.f / sqrtf(var + 1e-5f);
#pragma unroll
      for (int o = 0; o < 10; o++)
        out[o] += g * ((p[o] - mean) * rs * eng[e * 10 + o] + enb[e * 10 + o]);
    }
  }
  if (lane == 0){
    const float* r = routeS + (size_t)row * 32;
    float rem = 1.f - cumh[row];
#pragma unroll
    for (int o = 0; o < 10; o++)
      total[row * 10 + o] += rem * (out[o] + 0.22f * r[o] + 0.14f * r[10 + o]);
    cumh[row] += rem * haltb[row];
  }
}

// ---------------- shared branch --------------------------------------------------
__global__ __launch_bounds__(256)
void shared_kernel(const float* __restrict__ shpre, const float* __restrict__ sdw,
                   const float* __restrict__ g, const float* __restrict__ b,
                   float* __restrict__ outp)
{
  int lane = threadIdx.x & 63;
  int row = blockIdx.x * 4 + (threadIdx.x >> 6);
  const float* xr = shpre + (size_t)row * SHD;
  float p[10];
#pragma unroll
  for (int o = 0; o < 10; o++) p[o] = 0.f;
  for (int k = lane; k < SHD; k += 64){
    float xv = xr[k];
#pragma unroll
    for (int o = 0; o < 10; o++) p[o] = fmaf(xv, sdw[o * SHD + k], p[o]);
  }
#pragma unroll
  for (int o = 0; o < 10; o++) p[o] = wred(p[o]);
  float mean = 0.f;
#pragma unroll
  for (int o = 0; o < 10; o++) mean += p[o];
  mean *= 0.1f;
  float var = 0.f;
#pragma unroll
  for (int o = 0; o < 10; o++){ float dd = p[o] - mean; var += dd * dd; }
  var *= 0.1f;
  float rs = 1.f / sqrtf(var + 1e-5f);
  if (lane == 0){
#pragma unroll
    for (int o = 0; o < 10; o++) outp[row * 10 + o] = (p[o] - mean) * rs * g[o] + b[o];
  }
}

// ---------------- final output (lite) --------------------------------------------
__global__ __launch_bounds__(256)
void final_lite(const float* __restrict__ qaux, const float* __restrict__ biasp,
                const float* __restrict__ sharedp, const float* __restrict__ total,
                const float* __restrict__ routeS, const float* __restrict__ sscale,
                const float* __restrict__ alphap, const float* __restrict__ betap,
                float* __restrict__ outp)
{
  int row = blockIdx.x * 256 + threadIdx.x;
  float ss = sscale[0], av = alphap[0] + 1e-4f, bv = betap[0];
#pragma unroll
  for (int o = 0; o < 10; o++)
    outp[row * 10 + o] = (qaux[(size_t)row * 128 + 64 + o] + biasp[o])
                       + ss * sharedp[row * 10 + o]
                       + av * (total[row * 10 + o] * 0.25f)
                       + bv * routeS[(size_t)row * 32 + 20 + o];
}

// ====================================================================================
extern "C" void kernel_launch(void* const* d_in, const int* in_sizes, int n_in,
                              void* d_out, int out_size, void* d_ws, size_t ws_size,
                              hipStream_t stream)
{
  const float* x     = (const float*)d_in[0];
  const float* wgt   = (const float*)d_in[1];
  const float* bias  = (const float*)d_in[2];
  const float* suw   = (const float*)d_in[3];
  const float* sdw   = (const float*)d_in[4];
  const float* sng   = (const float*)d_in[5];
  const float* snb   = (const float*)d_in[6];
  const float* sscale= (const float*)d_in[7];
  const float* keys  = (const float*)d_in[8];
  const float* mvi   = (const float*)d_in[9];
  const float* mqw   = (const float*)d_in[10];
  const float* mow   = (const float*)d_in[11];
  const float* wgw   = (const float*)d_in[12];
  const float* wgb   = (const float*)d_in[13];
  const float* wvw   = (const float*)d_in[14];
  const float* wvb   = (const float*)d_in[15];
  const float* dqw   = (const float*)d_in[16];
  const float* dkw   = (const float*)d_in[17];
  const float* dvw   = (const float*)d_in[18];
  const float* dow   = (const float*)d_in[19];
  const float* clng  = (const float*)d_in[20];
  const float* clnb  = (const float*)d_in[21];
  const float* fc1w  = (const float*)d_in[22];
  const float* fc1b  = (const float*)d_in[23];
  const float* fc2w  = (const float*)d_in[24];
  const float* fc2b  = (const float*)d_in[25];
  const float* saw   = (const float*)d_in[26];
  const float* sab   = (const float*)d_in[27];
  const float* sbw   = (const float*)d_in[28];
  const float* sbb   = (const float*)d_in[29];
  const float* msw   = (const float*)d_in[30];
  const float* msb   = (const float*)d_in[31];
  const float* mmw   = (const float*)d_in[32];
  const float* mmb   = (const float*)d_in[33];
  const float* ebias = (const float*)d_in[34];
  const float* bw    = (const float*)d_in[35];
  const float* bb    = (const float*)d_in[36];
  const float* eup   = (const float*)d_in[37];
  const float* edn   = (const float*)d_in[38];
  const float* eng   = (const float*)d_in[39];
  const float* enb   = (const float*)d_in[40];
  const float* hw    = (const float*)d_in[41];
  const float* hb    = (const float*)d_in[42];
  const float* alphap= (const float*)d_in[43];
  const float* betap = (const float*)d_in[44];
  float* outp = (float*)d_out;

  char* wsb = (char*)d_ws;
  size_t off = 0;
  auto AL = [&](size_t bytes) -> void* {
    void* p = wsb + off;
    off = (off + bytes + 255) & ~(size_t)255;
    return p;
  };
  const size_t NI = (size_t)N_TOK * IN_D;
  float* cur    = (float*)AL(NI * 4);
  float* enr    = (float*)AL(NI * 4);
  float* dqbuf  = (float*)AL(NI * 4);
  float* qaux   = (float*)AL((size_t)N_TOK * 128 * 4);
  float* routeQ = (float*)AL((size_t)4 * N_TOK * 128 * 4);
  float* routeS = (float*)AL((size_t)N_TOK * 32 * 4);
  float* trio0  = (float*)AL((size_t)N_TOK * 3072 * 4);
  float* trio1  = (float*)AL((size_t)N_TOK * 3072 * 4);
  float* trio2  = (float*)AL((size_t)N_TOK * 3072 * 4);
  float* Ac     = (float*)AL((size_t)N_TOK * 24 * 4);
  float* W0     = (float*)AL((size_t)N_TOK * 24 * 4);
  float* W1     = (float*)AL((size_t)N_TOK * 24 * 4);
  float* W2     = (float*)AL((size_t)N_TOK * 24 * 4);
  float* sg     = (float*)AL((size_t)N_TOK * 10 * 4);
  float* haltb  = (float*)AL((size_t)N_TOK * 4);
  char*  zblk   = (char*)AL((size_t)N_TOK * 10 * 4 + N_TOK * 4 + 4 * 16 * 4);
  float* total  = (float*)zblk;
  float* cumh   = (float*)(zblk + (size_t)N_TOK * 10 * 4);
  int*   cnt    = (int*)(zblk + (size_t)N_TOK * 10 * 4 + N_TOK * 4);
  int*   gidx   = (int*)AL((size_t)NEXP * N_TOK * 4);
  int*   pos    = (int*)AL((size_t)N_TOK * NEXP * 4);
  float* sharedp= (float*)AL((size_t)N_TOK * 10 * 4);
  float* cbias  = (float*)AL(3072 * 4);
  float* K2f    = (float*)AL((size_t)24 * 1024 * 4);
  uint16_t* lnh  = (uint16_t*)AL(NI * 2);
  uint16_t* lnl  = (uint16_t*)AL(NI * 2);
  uint16_t* h7h  = (uint16_t*)AL((size_t)N_TOK * INNER * 2);
  uint16_t* h7l  = (uint16_t*)AL((size_t)N_TOK * INNER * 2);
  uint16_t* Arh  = (uint16_t*)AL((size_t)N_TOK * 3072 * 2);
  uint16_t* Arl  = (uint16_t*)AL((size_t)N_TOK * 3072 * 2);
  const size_t W1M = (size_t)IN_D * IN_D;
  uint16_t* preWh  = (uint16_t*)AL((size_t)2176 * 1024 * 2);
  uint16_t* preWl  = (uint16_t*)AL((size_t)2176 * 1024 * 2);
  uint16_t* qtWh   = (uint16_t*)AL((size_t)4224 * 1024 * 2);
  uint16_t* qtWl   = (uint16_t*)AL((size_t)4224 * 1024 * 2);
  uint16_t* rtWh   = (uint16_t*)AL((size_t)4 * 128 * 3072 * 2);
  uint16_t* rtWl   = (uint16_t*)AL((size_t)4 * 128 * 3072 * 2);
  const size_t WFC = (size_t)NSTEP * INNER * IN_D;
  uint16_t* fc1wh = (uint16_t*)AL(WFC * 2); uint16_t* fc1wl = (uint16_t*)AL(WFC * 2);
  uint16_t* fc2wh = (uint16_t*)AL(WFC * 2); uint16_t* fc2wl = (uint16_t*)AL(WFC * 2);
  uint16_t* upbf  = (uint16_t*)AL((size_t)NEXP * DMAX * IN_D * 2);
  uint16_t* HHc   = (uint16_t*)AL((size_t)N_TOK * DSUM * 2);
  float* shpre  = (float*)HHc;   // alias: consumed before HHc is written

  // ---- init ----
  hipMemsetAsync(zblk, 0, (size_t)N_TOK * 10 * 4 + N_TOK * 4 + 4 * 16 * 4, stream);
  hipMemsetAsync(cbias, 0, 3072 * 4, stream);
  hipMemcpyAsync(cbias + 2048, wvb, 1024 * 4, hipMemcpyDeviceToDevice, stream);
  hipMemcpyAsync(cur, x, NI * 4, hipMemcpyDeviceToDevice, stream);
  fill1_kernel<<<(N_TOK * 24 + 255) / 256, 256, 0, stream>>>(Ac, N_TOK * 24);
  cvt_bf16_kernel<<<2048, 256, 0, stream>>>(eup, upbf, (size_t)NEXP * DMAX * IN_D);

  split_strided<<<1024, 256, 0, stream>>>(x, Arh, Arl, N_TOK, 1024, 3072);
  split_kernel<<<1024, 256, 0, stream>>>(suw, preWh, preWl, (size_t)SHD * 1024);
  split_kernel<<<256, 256, 0, stream>>>(saw, preWh + (size_t)2072*1024, preWl + (size_t)2072*1024, (size_t)40 * 1024);
  split_kernel<<<256, 256, 0, stream>>>(wgt, preWh + (size_t)2112*1024, preWl + (size_t)2112*1024, (size_t)10 * 1024);
  hipMemsetAsync(preWh + (size_t)2122*1024, 0, (size_t)54 * 1024 * 2, stream);
  hipMemsetAsync(preWl + (size_t)2122*1024, 0, (size_t)54 * 1024 * 2, stream);
  split_kernel<<<1024, 256, 0, stream>>>(dqw, qtWh, qtWl, W1M);
  split_kernel<<<1024, 256, 0, stream>>>(dkw, qtWh + W1M, qtWl + W1M, W1M);
  split_kernel<<<1024, 256, 0, stream>>>(dvw, qtWh + 2*W1M, qtWl + 2*W1M, W1M);
  split_kernel<<<1024, 256, 0, stream>>>(wvw, qtWh + 3*W1M, qtWl + 3*W1M, W1M);
  split_kernel<<<256, 256, 0, stream>>>(saw, qtWh + (size_t)4120*1024, qtWl + (size_t)4120*1024, (size_t)40 * 1024);
  hipMemsetAsync(qtWh + (size_t)4160*1024, 0, (size_t)64 * 1024 * 2, stream);
  hipMemsetAsync(qtWl + (size_t)4160*1024, 0, (size_t)64 * 1024 * 2, stream);
  k2_kernel<<<dim3(24, 4), 256, 0, stream>>>(keys, mqw, K2f);
  split_kernel<<<256, 256, 0, stream>>>(K2f, preWh + (size_t)2048*1024, preWl + (size_t)2048*1024, (size_t)24 * 1024);
  split_kernel<<<256, 256, 0, stream>>>(K2f, qtWh + (size_t)4096*1024, qtWl + (size_t)4096*1024, (size_t)24 * 1024);
  build_routew<<<2048, 256, 0, stream>>>(msw, mmw, bw, wgw, hw, mow, dow, rtWh, rtWl);
  split_kernel<<<1024, 256, 0, stream>>>(fc1w, fc1wh, fc1wl, WFC);
  split_kernel<<<1024, 256, 0, stream>>>(fc2w, fc2wh, fc2wl, WFC);

  gemm_sp<EPI_PRE><<<dim3(17, 16), 256, 0, stream>>>(
      Arh, Arl, 3072, preWh, preWl, nullptr, nullptr,
      shpre, qaux, nullptr, nullptr, nullptr, IN_D, 2176);
  shared_kernel<<<512, 256, 0, stream>>>(shpre, sdw, sng, snb, sharedp);

  float* trioB[3] = {trio0, trio1, trio2};

  for (int t = 0; t < NSTEP; t++){
    ctx_enr_kernel<<<2048, 256, 0, stream>>>(qaux, dqbuf, Ac, W0, W1, W2, mvi,
                                             trio0, trio1, trio2, cur, sab, sbw, sbb,
                                             clng, clnb, enr, lnh, lnl, Arh, Arl, t);
    gemm_sp<EPI_GELU><<<dim3(INNER/128, 16), 256, 0, stream>>>(
        lnh, lnl, 1024, fc1wh + (size_t)t * INNER * IN_D, fc1wl + (size_t)t * INNER * IN_D,
        fc1b + t * INNER, nullptr, nullptr, nullptr, nullptr, h7h, h7l, IN_D, INNER);
    gemm_sp<EPI_CUR><<<dim3(8, 16), 256, 0, stream>>>(
        h7h, h7l, 768, fc2wh + (size_t)t * IN_D * INNER, fc2wl + (size_t)t * IN_D * INNER,
        fc2b + t * IN_D, enr, cur, nullptr, nullptr, Arh, Arl, INNER, IN_D);
    gemm_sp<EPI_ROUTE><<<dim3(4, 16), 256, 0, stream>>>(
        Arh, Arl, 3072, rtWh + (size_t)t * 128 * 3072, rtWl + (size_t)t * 128 * 3072,
        nullptr, nullptr, routeQ, nullptr, nullptr, nullptr, nullptr, 3072, 128);
    route_fin<<<8, 256, 0, stream>>>(routeQ, mmb, msb, ebias, bb, wgb, hb,
                                     sg, haltb, Ac, W0, W1, W2,
                                     cnt + t * 16, gidx, pos, routeS, t);
    expert_up_mfma<<<dim3(16, 188), 256, 0, stream>>>(Arh, upbf, cnt + t * 16, gidx, HHc);
    downfin_kernel<<<512, 256, 0, stream>>>(HHc, pos, edn, sg, eng, enb,
                                            routeS, haltb, total, cumh);
    if (t < 3)
      gemm_sp<EPI_QTRIO><<<dim3(33, 16), 256, 0, stream>>>(
          Arh, Arl, 3072, qtWh, qtWl, cbias, nullptr,
          dqbuf, trioB[t], qaux, nullptr, nullptr, IN_D, 4224);
  }
  final_lite<<<8, 256, 0, stream>>>(qaux, bias, sharedp, total, routeS,
                                    sscale, alphap, betap, outp);
}

// Round 10
// 2420.079 us; speedup vs baseline: 1.8945x; 1.0798x over previous
//
#include <hip/hip_runtime.h>
#include <stdint.h>

#define N_TOK 2048
#define IN_D  1024
#define NEXP  10
#define NSTEP 4
#define INNER 768
#define SHD   2048
#define DMAX  3328
#define DSUM  24064

typedef __attribute__((ext_vector_type(4))) float f32x4;
typedef __attribute__((ext_vector_type(8))) short bf16x8;

__device__ const int c_dims[10] = {1536,2048,2560,3072,1792,2304,2816,2048,2560,3328};
__device__ const int c_offs[10] = {0,1536,3584,6144,9216,11008,13312,16128,18176,20736};
__device__ const int c_acts[10] = {0,1,2,3,4,5,6,7,0,1};
__device__ const int c_cum[11]  = {0,12,28,48,72,86,104,126,142,162,188};

__device__ __forceinline__ float wred(float v){
#pragma unroll
  for (int s = 32; s > 0; s >>= 1) v += __shfl_xor(v, s, 64);
  return v;
}
__device__ __forceinline__ float wmax(float v){
#pragma unroll
  for (int s = 32; s > 0; s >>= 1) v = fmaxf(v, __shfl_xor(v, s, 64));
  return v;
}
__device__ __forceinline__ float bf2f(uint16_t u){
  return __uint_as_float(((uint32_t)u) << 16);
}
__device__ __forceinline__ uint16_t f2bf(float f){
  uint32_t u = __float_as_uint(f);
  return (uint16_t)((u + 0x7FFFu + ((u >> 16) & 1u)) >> 16);
}
__device__ __forceinline__ void gload16(const uint16_t* g, uint16_t* l){
  __builtin_amdgcn_global_load_lds(
      (const __attribute__((address_space(1))) uint32_t*)(const void*)g,
      (__attribute__((address_space(3))) uint32_t*)(void*)l, 16, 0, 0);
}

__device__ __forceinline__ float actf(int a, float x){
  switch(a){
    case 0: return x / (1.f + expf(-x));
    case 1: return 0.5f * x * (1.f + erff(x * 0.7071067811865475f));
    case 2: { float sp = fmaxf(x,0.f) + log1pf(expf(-fabsf(x)));
              return x * tanhf(sp); }
    case 3: return fmaxf(x, 0.f);
    case 4: return x > 0.f ? 1.0507009873554805f * x
                           : 1.7580993408473768f * expm1f(x);
    case 5: return tanhf(x);
    case 6: return fmaxf(x,0.f) + log1pf(expf(-fabsf(x)));
    default: return x > 0.f ? x : expm1f(x);
  }
}

// ---------------- f32 -> (hi, lo) bf16 split ------------------------------------
__global__ void split_kernel(const float* __restrict__ src, uint16_t* __restrict__ hi,
                             uint16_t* __restrict__ lo, size_t n){
  size_t i = ((size_t)blockIdx.x * blockDim.x + threadIdx.x) << 2;
  size_t stride = ((size_t)gridDim.x * blockDim.x) << 2;
  for (; i < n; i += stride){
    float4 v = *(const float4*)(src + i);
    ushort4 h, l;
    h.x = f2bf(v.x); l.x = f2bf(v.x - bf2f(h.x));
    h.y = f2bf(v.y); l.y = f2bf(v.y - bf2f(h.y));
    h.z = f2bf(v.z); l.z = f2bf(v.z - bf2f(h.z));
    h.w = f2bf(v.w); l.w = f2bf(v.w - bf2f(h.w));
    *(ushort4*)(hi + i) = h;
    *(ushort4*)(lo + i) = l;
  }
}
__global__ void split_strided(const float* __restrict__ src, uint16_t* __restrict__ hi,
                              uint16_t* __restrict__ lo, int rows, int cols, int ldd){
  int nq = rows * (cols >> 2);
  for (int i = blockIdx.x * blockDim.x + threadIdx.x; i < nq; i += gridDim.x * blockDim.x){
    int r = i / (cols >> 2), c4 = (i - r * (cols >> 2)) << 2;
    float4 v = *(const float4*)(src + (size_t)r * cols + c4);
    ushort4 h, l;
    h.x = f2bf(v.x); l.x = f2bf(v.x - bf2f(h.x));
    h.y = f2bf(v.y); l.y = f2bf(v.y - bf2f(h.y));
    h.z = f2bf(v.z); l.z = f2bf(v.z - bf2f(h.z));
    h.w = f2bf(v.w); l.w = f2bf(v.w - bf2f(h.w));
    size_t d = (size_t)r * ldd + c4;
    *(ushort4*)(hi + d) = h;
    *(ushort4*)(lo + d) = l;
  }
}
__global__ void cvt_bf16_kernel(const float* __restrict__ src, uint16_t* __restrict__ dst, size_t n){
  size_t i = ((size_t)blockIdx.x * blockDim.x + threadIdx.x) << 2;
  size_t stride = ((size_t)gridDim.x * blockDim.x) << 2;
  for (; i < n; i += stride){
    float4 v = *(const float4*)(src + i);
    ushort4 h;
    h.x = f2bf(v.x); h.y = f2bf(v.y); h.z = f2bf(v.z); h.w = f2bf(v.w);
    *(ushort4*)(dst + i) = h;
  }
}
__global__ void fill1_kernel(float* __restrict__ p, int n){
  int i = blockIdx.x * blockDim.x + threadIdx.x;
  if (i < n) p[i] = 1.f;
}

// ---------------- K2 = keys @ mqw  [24,1024] ------------------------------------
__global__ __launch_bounds__(256)
void k2_kernel(const float* __restrict__ keys, const float* __restrict__ mqw,
               float* __restrict__ K2){
  int m = blockIdx.x;
  int j = blockIdx.y * 256 + threadIdx.x;
  float acc = 0.f;
  for (int d = 0; d < 1024; d++)
    acc = fmaf(keys[m * 1024 + d], mqw[d * 1024 + j], acc);
  K2[m * 1024 + j] = acc;
}

// ---------------- route weight builder: 4 x [128 rows x 3072] -------------------
__global__ void build_routew(const float* __restrict__ msw, const float* __restrict__ mmw,
                             const float* __restrict__ bw, const float* __restrict__ wgw,
                             const float* __restrict__ hw, const float* __restrict__ mow,
                             const float* __restrict__ dow, uint16_t* __restrict__ Wh,
                             uint16_t* __restrict__ Wl){
  const int TOT = 4 * 128 * 3072;
  for (int i = blockIdx.x * 256 + threadIdx.x; i < TOT; i += gridDim.x * 256){
    int t = i / (128 * 3072);
    int rem = i - t * (128 * 3072);
    int row = rem / 3072, col = rem - row * 3072;
    float v = 0.f;
    if (row < 40){ if (col < 1024) v = msw[row * 1024 + col]; }
    else if (row < 44){ if (col < 1024) v = mmw[(row - 40) * 1024 + col]; }
    else if (row < 48){ if (col < 1024) v = bw[(row - 44) * 1024 + col]; }
    else if (row < 72){ if (col < 2048) v = wgw[(row - 48) * 2048 + col]; }
    else if (row == 72){
      if (col < 1024) v = hw[t * 1024 + col];
      else if (col < 2048) v = 0.2f * hw[t * 1024 + col - 1024];
      else v = 0.1f * hw[t * 1024 + col - 2048];
    }
    else if (row < 83){ if (col >= 1024 && col < 2048) v = mow[(row - 73) * 1024 + col - 1024]; }
    else if (row < 93){ if (col >= 2048) v = dow[(row - 83) * 1024 + col - 2048]; }
    else if (row < 103){ if (col < 1024) v = mow[(row - 93) * 1024 + col]; }
    uint16_t h = f2bf(v);
    Wh[i] = h; Wl[i] = f2bf(v - bf2f(h));
  }
}

// ---------------- split-bf16 MFMA GEMM, counted-vmcnt 2-deep pipeline -----------
// LDS: unit u holds global chunk ((u&3)^((u>>3)&3)) of row (u>>2).
// Fragment read (R,g): u = R*4 + (g ^ ((R>>1)&3)).
// EPI_QROUTE: blocks x<4 are K-split route (W2, stride 3072); x>=4 are qtrio.
enum { EPI_GELU=0, EPI_CUR=1, EPI_PRE=2, EPI_QROUTE=3 };

template<int EPI>
__global__ __launch_bounds__(256)
void gemm_sp(const uint16_t* __restrict__ Ah, const uint16_t* __restrict__ Al, int lda,
             const uint16_t* __restrict__ Wh, const uint16_t* __restrict__ Wl,
             const uint16_t* __restrict__ W2h, const uint16_t* __restrict__ W2l,
             const float* __restrict__ bias, const float* __restrict__ addend,
             float* __restrict__ D0, float* __restrict__ D1, float* __restrict__ D2,
             float* __restrict__ D3,
             uint16_t* __restrict__ oH, uint16_t* __restrict__ oL,
             int K, int D)
{
  __shared__ __align__(16) uint16_t sm[4][2][4096];
  int tid = threadIdx.x, lane = tid & 63, wave = tid >> 6;
  int wr = wave >> 1, wc = wave & 1;
  int arow = lane & 15, agrp = lane >> 4;
  int rowBase = blockIdx.y * 128;
  bool isRoute = (EPI == EPI_QROUTE) && ((int)blockIdx.x < 4);
  const uint16_t* Wsh = isRoute ? W2h : Wh;
  const uint16_t* Wsl = isRoute ? W2l : Wl;
  int wst     = isRoute ? 3072 : K;
  int colBase = isRoute ? 0 : ((EPI == EPI_QROUTE ? (int)blockIdx.x - 4 : (int)blockIdx.x) * 128);
  int kBase   = isRoute ? (int)blockIdx.x * 768 : 0;
  int kLen    = isRoute ? 768 : K;
  f32x4 acc[4][4];
#pragma unroll
  for (int m = 0; m < 4; m++)
#pragma unroll
    for (int n = 0; n < 4; n++){ f32x4 z = {0.f,0.f,0.f,0.f}; acc[m][n] = z; }

#define STAGE_G(buf, k0) do { \
  _Pragma("unroll") \
  for (int s = 0; s < 2; s++){ \
    int u = tid + s * 256; \
    int rr = u >> 2; \
    int ch = (u & 3) ^ ((rr >> 1) & 3); \
    size_t ga = (size_t)(rowBase + rr) * lda + kBase + (k0) + ch * 8; \
    size_t gw = (size_t)(colBase + rr) * wst + kBase + (k0) + ch * 8; \
    gload16(&Ah[ga], &sm[0][buf][u << 3]); \
    gload16(&Al[ga], &sm[1][buf][u << 3]); \
    gload16(&Wsh[gw], &sm[2][buf][u << 3]); \
    gload16(&Wsl[gw], &sm[3][buf][u << 3]); \
  } } while(0)

  int nk = kLen >> 5;
  STAGE_G(0, 0);
  if (nk > 1) STAGE_G(1, 32);
  int perm = (arow >> 1) & 3;
#pragma unroll 1
  for (int ki = 0; ki < nk; ki++){
    int cb = ki & 1;
    if (ki + 1 < nk) asm volatile("s_waitcnt vmcnt(8)" ::: "memory");
    else             asm volatile("s_waitcnt vmcnt(0)" ::: "memory");
    __builtin_amdgcn_s_barrier();
    bf16x8 ah[4], al[4], bh[4], bl[4];
#pragma unroll
    for (int m = 0; m < 4; m++){
      int u = ((wr*64 + m*16 + arow) << 2) + (agrp ^ perm);
      ah[m] = *(const bf16x8*)&sm[0][cb][u << 3];
      al[m] = *(const bf16x8*)&sm[1][cb][u << 3];
    }
#pragma unroll
    for (int n = 0; n < 4; n++){
      int u = ((wc*64 + n*16 + arow) << 2) + (agrp ^ perm);
      bh[n] = *(const bf16x8*)&sm[2][cb][u << 3];
      bl[n] = *(const bf16x8*)&sm[3][cb][u << 3];
    }
#pragma unroll
    for (int m = 0; m < 4; m++)
#pragma unroll
      for (int n = 0; n < 4; n++){
        acc[m][n] = __builtin_amdgcn_mfma_f32_16x16x32_bf16(ah[m], bh[n], acc[m][n], 0, 0, 0);
        acc[m][n] = __builtin_amdgcn_mfma_f32_16x16x32_bf16(ah[m], bl[n], acc[m][n], 0, 0, 0);
        acc[m][n] = __builtin_amdgcn_mfma_f32_16x16x32_bf16(al[m], bh[n], acc[m][n], 0, 0, 0);
      }
    __builtin_amdgcn_s_barrier();
    asm volatile("" ::: "memory");
    if (ki + 2 < nk) STAGE_G(cb, (ki + 2) << 5);
  }
#undef STAGE_G
#pragma unroll
  for (int m = 0; m < 4; m++){
#pragma unroll
    for (int n = 0; n < 4; n++){
      int col = colBase + wc*64 + n*16 + arow;
#pragma unroll
      for (int r2 = 0; r2 < 4; r2++){
        int row = rowBase + wr*64 + m*16 + agrp*4 + r2;
        float v = acc[m][n][r2];
        if (EPI == EPI_GELU){
          v += bias[col];
          v = 0.5f * v * (1.f + erff(v * 0.7071067811865475f));
          size_t idx = (size_t)row * D + col;
          uint16_t h = f2bf(v); oH[idx] = h; oL[idx] = f2bf(v - bf2f(h));
        }
        if (EPI == EPI_CUR){
          v += bias[col] + addend[(size_t)row * 1024 + col];
          D0[(size_t)row * 1024 + col] = v;
          size_t idx = (size_t)row * 3072 + col;
          uint16_t h = f2bf(v); oH[idx] = h; oL[idx] = f2bf(v - bf2f(h));
        }
        if (EPI == EPI_PRE){
          if (col < 2048) D0[(size_t)row * 2048 + col] = v / (1.f + expf(-v));
          else D1[(size_t)row * 128 + col - 2048] = v;
        }
        if (EPI == EPI_QROUTE){
          if (isRoute){
            D3[((size_t)blockIdx.x * N_TOK + row) * 128 + col] = v;
          } else {
            if (col < 1024) D0[(size_t)row * 1024 + col] = v;
            else if (col < 4096) D1[(size_t)row * 3072 + col - 1024] = v + bias[col - 1024];
            else if (col < 4160) D2[(size_t)row * 128 + col - 4096] = v;
          }
        }
      }
    }
  }
}

// ---------------- sparse expert up: persistent blocks, depth-3 pipeline ---------
__global__ __launch_bounds__(256)
void expert_up_mfma(const uint16_t* __restrict__ Abf, const uint16_t* __restrict__ Ubf,
                    const int* __restrict__ cnt, const int* __restrict__ gidx,
                    uint16_t* __restrict__ HH)
{
  int y = blockIdx.y;
  int e = 0;
#pragma unroll
  for (int i = 1; i < 11; i++) if (y >= c_cum[i]) e = i;
  int ct = y - c_cum[e];
  int dcols = c_dims[e];
  int ne = cnt[e];
  const uint16_t* W = Ubf + (size_t)e * DMAX * IN_D + (size_t)ct * 128 * IN_D;

  // 48KB: 3 buffers x (sA 8KB + sB 8KB); epilogue reuses first 32KB as Ht
  __shared__ __align__(16) uint16_t smem[24576];
  int tid = threadIdx.x, lane = tid & 63, wave = tid >> 6;
  int wr = wave >> 1, wc = wave & 1;
  int arow = lane & 15, agrp = lane >> 4;
  int perm = (arow >> 1) & 3;
  int actid = c_acts[e];
  size_t base_e = (size_t)N_TOK * c_offs[e];

#define STAGE_E(b, k0) do { \
  _Pragma("unroll") \
  for (int s = 0; s < 2; s++){ \
    int u = tid + s * 256; \
    int rr = u >> 2; \
    int ch = (u & 3) ^ ((rr >> 1) & 3); \
    int tk = (s == 0) ? tok0 : tok1; \
    gload16(&Abf[(size_t)tk * 3072 + (k0) + ch * 8], &smem[(((b) * 1024) + u) << 3]); \
    gload16(&W[(size_t)rr * IN_D + (k0) + ch * 8],   &smem[(((b) * 1024) + 512 + u) << 3]); \
  } } while(0)

#pragma unroll 1
  for (int rowBase = blockIdx.x * 128; rowBase < ne; rowBase += 4 * 128){
    int r0 = rowBase + (tid >> 2);
    int tok0 = (r0 < ne) ? gidx[e * N_TOK + r0] : 0;
    int tok1 = (r0 + 64 < ne) ? gidx[e * N_TOK + r0 + 64] : 0;

    f32x4 acc[4][4];
#pragma unroll
    for (int m = 0; m < 4; m++)
#pragma unroll
      for (int n = 0; n < 4; n++){ f32x4 z = {0.f,0.f,0.f,0.f}; acc[m][n] = z; }

    STAGE_E(0, 0);
    STAGE_E(1, 32);
    STAGE_E(2, 64);
    int cb = 0;
#pragma unroll 1
    for (int ki = 0; ki < 32; ki++){
      // outstanding stages after ki: min(2, 31-ki); 4 loads/wave each
      if (ki < 30)      asm volatile("s_waitcnt vmcnt(8)" ::: "memory");
      else if (ki == 30) asm volatile("s_waitcnt vmcnt(4)" ::: "memory");
      else               asm volatile("s_waitcnt vmcnt(0)" ::: "memory");
      __builtin_amdgcn_s_barrier();
      bf16x8 a[4], b[4];
#pragma unroll
      for (int m = 0; m < 4; m++){
        int u = cb * 1024 + ((wr*64 + m*16 + arow) << 2) + (agrp ^ perm);
        a[m] = *(const bf16x8*)&smem[u << 3];
      }
#pragma unroll
      for (int n = 0; n < 4; n++){
        int u = cb * 1024 + 512 + ((wc*64 + n*16 + arow) << 2) + (agrp ^ perm);
        b[n] = *(const bf16x8*)&smem[u << 3];
      }
#pragma unroll
      for (int m = 0; m < 4; m++)
#pragma unroll
        for (int n = 0; n < 4; n++)
          acc[m][n] = __builtin_amdgcn_mfma_f32_16x16x32_bf16(a[m], b[n], acc[m][n], 0, 0, 0);
      __builtin_amdgcn_s_barrier();
      asm volatile("" ::: "memory");
      if (ki + 3 < 32) STAGE_E(cb, (ki + 3) << 5);
      cb = (cb == 2) ? 0 : cb + 1;
    }
    // epilogue: activation -> swizzled LDS tile -> coalesced 16B stores
    uint16_t* Ht = smem;
#pragma unroll
    for (int m = 0; m < 4; m++){
      int rb0 = wr*64 + m*16 + agrp*4;
#pragma unroll
      for (int n = 0; n < 4; n++){
        int col = wc*64 + n*16 + arow;
#pragma unroll
        for (int r2 = 0; r2 < 4; r2++){
          int row = rb0 + r2;
          float v = actf(actid, acc[m][n][r2]);
          Ht[row * 128 + (col ^ ((row & 7) << 3))] = f2bf(v);
        }
      }
    }
    __syncthreads();
#pragma unroll
    for (int i = 0; i < 8; i++){
      int c = tid + i * 256;
      int row = c >> 4, chunk = c & 15;
      int schunk = (chunk & 8) | ((chunk ^ row) & 7);
      int4 val = *(const int4*)&Ht[row * 128 + schunk * 8];
      *(int4*)&HH[base_e + (size_t)(rowBase + row) * dcols
                  + (size_t)ct * 128 + chunk * 8] = val;
    }
    __syncthreads();
  }
#undef STAGE_E
}

// ---------------- ctx_enr: mem softmax, depth attn, mctx/dctx/enriched/LN ------
__global__ __launch_bounds__(256)
void ctx_enr_kernel(const float* __restrict__ qaux, const float* __restrict__ dqbuf,
                    const float* __restrict__ Ac, const float* __restrict__ W0,
                    const float* __restrict__ W1, const float* __restrict__ W2,
                    const float* __restrict__ mvi,
                    const float* __restrict__ t0, const float* __restrict__ t1,
                    const float* __restrict__ t2, const float* __restrict__ cur,
                    const float* __restrict__ sab, const float* __restrict__ sbw,
                    const float* __restrict__ sbb, const float* __restrict__ lng,
                    const float* __restrict__ lnbv,
                    float* __restrict__ enr, uint16_t* __restrict__ lnh,
                    uint16_t* __restrict__ lnl, uint16_t* __restrict__ Arh,
                    uint16_t* __restrict__ Arl, int t)
{
  int row = blockIdx.x, tid = threadIdx.x;
  __shared__ float su[24], ss[3], s40[40], red[12], redm[8];
  if (tid < 64){
    float pj = (tid < 24) ? qaux[(size_t)row * 128 + tid] * 0.03125f : -1e30f;
    float mx = wmax(pj);
    float ex = (tid < 24) ? expf(pj - mx) : 0.f;
    float sum = wred(ex);
    float attn = ex / sum;
    if (tid < 24) su[tid] = attn * Ac[row * 24 + tid];
    float w0v = (t > 0 && tid < 24) ? W0[row * 24 + tid] : 0.f;
    float s0 = wred(attn * w0v);
    float w1v = (t > 1 && tid < 24) ? W1[row * 24 + tid] : 0.f;
    float s1 = wred(attn * w1v);
    float w2v = (t > 2 && tid < 24) ? W2[row * 24 + tid] : 0.f;
    float s2 = wred(attn * w2v);
    if (tid == 0){ ss[0] = s0; ss[1] = s1; ss[2] = s2; }
    if (tid < 40) s40[tid] = tanhf(qaux[(size_t)row * 128 + 24 + tid] + sab[tid]);
  }
  size_t tb = (size_t)row * 3072;
  if (t > 0){
    float a0 = 0.f, a1 = 0.f, a2 = 0.f;
#pragma unroll
    for (int j = 0; j < 4; j++){
      int d = tid + j * 256;
      float dq = dqbuf[(size_t)row * 1024 + d];
      a0 = fmaf(dq, t0[tb + d], a0);
      if (t > 1) a1 = fmaf(dq, t1[tb + d], a1);
      if (t > 2) a2 = fmaf(dq, t2[tb + d], a2);
    }
    a0 = wred(a0); a1 = wred(a1); a2 = wred(a2);
    if ((tid & 63) == 0){ int w = tid >> 6; red[w] = a0; red[4+w] = a1; red[8+w] = a2; }
  }
  __syncthreads();
  float e0 = 0.f, e1 = 0.f, e2 = 0.f;
  if (t > 0){
    float A0 = (red[0]+red[1]+red[2]+red[3]) * 0.03125f;
    float A1 = (red[4]+red[5]+red[6]+red[7]) * 0.03125f;
    float A2 = (red[8]+red[9]+red[10]+red[11]) * 0.03125f;
    float dmx = A0;
    if (t > 1) dmx = fmaxf(dmx, A1);
    if (t > 2) dmx = fmaxf(dmx, A2);
    e0 = expf(A0 - dmx);
    e1 = (t > 1) ? expf(A1 - dmx) : 0.f;
    e2 = (t > 2) ? expf(A2 - dmx) : 0.f;
    float dinv = 1.f / (e0 + e1 + e2);
    e0 *= dinv; e1 *= dinv; e2 *= dinv;
  }
  size_t ar = (size_t)row * 3072;
  float ev[4];
  float part = 0.f;
#pragma unroll
  for (int j = 0; j < 4; j++){
    int d = tid + j * 256;
    size_t idx = (size_t)row * IN_D + d;
    float mv = 0.f;
#pragma unroll
    for (int m = 0; m < 24; m++) mv = fmaf(su[m], mvi[m * IN_D + d], mv);
    float dv = 0.f;
    if (t > 0){
      mv = fmaf(ss[0], t0[tb + 2048 + d], mv);
      dv = e0 * t0[tb + 1024 + d];
      if (t > 1){ mv = fmaf(ss[1], t1[tb + 2048 + d], mv); dv = fmaf(e1, t1[tb + 1024 + d], dv); }
      if (t > 2){ mv = fmaf(ss[2], t2[tb + 2048 + d], mv); dv = fmaf(e2, t2[tb + 1024 + d], dv); }
    }
    float sv = sbb[d];
#pragma unroll
    for (int o = 0; o < 40; o++) sv = fmaf(s40[o], sbw[d * 40 + o], sv);
    float v = cur[idx] + 0.34f * mv + 0.22f * dv + 0.18f * sv;
    uint16_t mh = f2bf(mv);
    Arh[ar + 1024 + d] = mh; Arl[ar + 1024 + d] = f2bf(mv - bf2f(mh));
    uint16_t dh = f2bf(dv);
    Arh[ar + 2048 + d] = dh; Arl[ar + 2048 + d] = f2bf(dv - bf2f(dh));
    ev[j] = v; part += v;
  }
  part = wred(part);
  if ((tid & 63) == 0) redm[tid >> 6] = part;
  __syncthreads();
  float mean = (redm[0] + redm[1] + redm[2] + redm[3]) * (1.f / 1024.f);
  float vp = 0.f;
#pragma unroll
  for (int j = 0; j < 4; j++){ float dd = ev[j] - mean; vp += dd * dd; }
  vp = wred(vp);
  if ((tid & 63) == 0) redm[4 + (tid >> 6)] = vp;
  __syncthreads();
  float var = (redm[4] + redm[5] + redm[6] + redm[7]) * (1.f / 1024.f);
  float rs = 1.f / sqrtf(var + 1e-5f);
#pragma unroll
  for (int j = 0; j < 4; j++){
    int d = tid + j * 256;
    size_t idx = (size_t)row * IN_D + d;
    enr[idx] = ev[j];
    float v = (ev[j] - mean) * rs * lng[t * IN_D + d] + lnbv[t * IN_D + d];
    uint16_t h = f2bf(v);
    lnh[idx] = h;
    lnl[idx] = f2bf(v - bf2f(h));
  }
}

// ---------------- route_fin: sums 4 K-split partials, softmaxes, top-k ----------
__global__ __launch_bounds__(256)
void route_fin(const float* __restrict__ ROq, const float* __restrict__ mmb,
               const float* __restrict__ msb, const float* __restrict__ ebias,
               const float* __restrict__ bb, const float* __restrict__ wgb,
               const float* __restrict__ hb,
               float* __restrict__ sg, float* __restrict__ haltb,
               float* __restrict__ Ac, float* __restrict__ W0,
               float* __restrict__ W1, float* __restrict__ W2,
               int* __restrict__ cnt, int* __restrict__ gidx,
               int* __restrict__ pos, float* __restrict__ routeS, int t)
{
  int row = blockIdx.x * 256 + threadIdx.x;
  int lane = threadIdx.x & 63;
  const size_t P = (size_t)N_TOK * 128;
  const float* r0 = ROq + (size_t)row * 128;
  const float* r1 = r0 + P;
  const float* r2 = r0 + 2 * P;
  const float* r3 = r0 + 3 * P;
  auto R = [&](int j){ return r0[j] + r1[j] + r2[j] + r3[j]; };
  float pm[4];
#pragma unroll
  for (int o = 0; o < 4; o++) pm[o] = R(40 + o) + mmb[o];
  float mmx = fmaxf(fmaxf(pm[0], pm[1]), fmaxf(pm[2], pm[3]));
  float msum = 0.f;
#pragma unroll
  for (int o = 0; o < 4; o++){ pm[o] = expf(pm[o] - mmx); msum += pm[o]; }
  float minv = 1.f / msum;
  float gl[10];
#pragma unroll
  for (int e = 0; e < 10; e++){
    float g = ebias[e];
#pragma unroll
    for (int s2 = 0; s2 < 4; s2++)
      g = fmaf(pm[s2] * minv, R(s2 * 10 + e) + msb[s2 * 10 + e], g);
    gl[e] = g;
  }
  float gmx = gl[0];
#pragma unroll
  for (int e = 1; e < 10; e++) gmx = fmaxf(gmx, gl[e]);
  float gs = 0.f;
#pragma unroll
  for (int e = 0; e < 10; e++){ gl[e] = expf(gl[e] - gmx); gs += gl[e]; }
  float ginv = 1.f / gs;
#pragma unroll
  for (int e = 0; e < 10; e++) gl[e] *= ginv;
  float pb0 = R(44) + bb[0], pb1 = R(45) + bb[1], pb2 = R(46) + bb[2], pb3 = R(47) + bb[3];
  int bud = 1; float bbest = pb0;
  if (pb1 > bbest){ bbest = pb1; bud = 2; }
  if (pb2 > bbest){ bbest = pb2; bud = 3; }
  if (pb3 > bbest){ bbest = pb3; bud = 4; }
  float tv[4]; int ti[4]; unsigned used = 0;
#pragma unroll
  for (int j = 0; j < 4; j++){
    float best = -1e30f; int bi = 0;
#pragma unroll
    for (int e = 0; e < 10; e++){
      bool ok = (!((used >> e) & 1u)) && (gl[e] > best);
      if (ok){ best = gl[e]; bi = e; }
    }
    tv[j] = best; ti[j] = bi; used |= (1u << bi);
  }
  float ssum = tv[0];
  if (bud > 1) ssum += tv[1];
  if (bud > 2) ssum += tv[2];
  if (bud > 3) ssum += tv[3];
  float den = fmaxf(ssum, 1e-6f);
  float sup = 1.f - tv[0] / den;
  float sgv[10];
#pragma unroll
  for (int e = 0; e < 10; e++){
    float sv = 0.f;
#pragma unroll
    for (int j = 0; j < 4; j++) if (j < bud && ti[j] == e) sv = tv[j] / den;
    sgv[e] = sv;
    sg[row * 10 + e] = sv;
  }
  float pw[24];
#pragma unroll
  for (int m = 0; m < 24; m++) pw[m] = R(48 + m) + wgb[m];
  float wmx2 = pw[0];
#pragma unroll
  for (int m = 1; m < 24; m++) wmx2 = fmaxf(wmx2, pw[m]);
  float wsum = 0.f;
#pragma unroll
  for (int m = 0; m < 24; m++){ pw[m] = expf(pw[m] - wmx2); wsum += pw[m]; }
  float winv = 1.f / wsum;
#pragma unroll
  for (int m = 0; m < 24; m++){
    float c = sup * pw[m] * winv;
    float om = 1.f - c;
    Ac[row * 24 + m] *= om;
    if (t > 0) W0[row * 24 + m] *= om;
    if (t > 1) W1[row * 24 + m] *= om;
    if (t > 2) W2[row * 24 + m] *= om;
    if (t == 0)      W0[row * 24 + m] = c;
    else if (t == 1) W1[row * 24 + m] = c;
    else if (t == 2) W2[row * 24 + m] = c;
  }
  haltb[row] = 1.f / (1.f + expf(-(R(72) + hb[t])));
#pragma unroll
  for (int i = 0; i < 30; i++) routeS[row * 32 + i] = R(73 + i);
#pragma unroll
  for (int e = 0; e < 10; e++){
    bool act = sgv[e] != 0.f;
    unsigned long long mask = __ballot(act);
    int cw = __popcll(mask);
    int b0 = 0;
    if (lane == 0 && cw > 0) b0 = atomicAdd(&cnt[e], cw);
    b0 = __shfl(b0, 0, 64);
    if (act){
      int slot = b0 + __popcll(mask & ((1ull << lane) - 1ull));
      gidx[e * N_TOK + slot] = row;
      pos[row * 10 + e] = slot;
    }
  }
}

// ---------------- downfin: expert down + LN + gated acc + step finalize --------
__global__ __launch_bounds__(256)
void downfin_kernel(const uint16_t* __restrict__ HH, const int* __restrict__ pos,
                    const float* __restrict__ ED, const float* __restrict__ sg,
                    const float* __restrict__ eng, const float* __restrict__ enb,
                    const float* __restrict__ routeS, const float* __restrict__ haltb,
                    float* __restrict__ total, float* __restrict__ cumh)
{
  int lane = threadIdx.x & 63;
  int row = blockIdx.x * 4 + (threadIdx.x >> 6);
  float out[10] = {};
  for (int e = 0; e < NEXP; e++){
    float g = sg[row * 10 + e];
    if (g != 0.0f){
      int d = c_dims[e];
      int slot = pos[row * 10 + e];
      const uint16_t* hr = HH + (size_t)N_TOK * c_offs[e] + (size_t)slot * d;
      const float* wd = ED + (size_t)e * 10 * DMAX;
      float p[10] = {};
      for (int k = lane * 4; k < d; k += 256){
        uint2 hv = *(const uint2*)&hr[k];
        float h0 = bf2f((uint16_t)hv.x), h1 = bf2f((uint16_t)(hv.x >> 16));
        float h2 = bf2f((uint16_t)hv.y), h3 = bf2f((uint16_t)(hv.y >> 16));
#pragma unroll
        for (int o = 0; o < 10; o++){
          float4 w4 = *(const float4*)&wd[o * DMAX + k];
          p[o] = fmaf(h0, w4.x, fmaf(h1, w4.y, fmaf(h2, w4.z, fmaf(h3, w4.w, p[o]))));
        }
      }
#pragma unroll
      for (int o = 0; o < 10; o++) p[o] = wred(p[o]);
      float mean = 0.f;
#pragma unroll
      for (int o = 0; o < 10; o++) mean += p[o];
      mean *= 0.1f;
      float var = 0.f;
#pragma unroll
      for (int o = 0; o < 10; o++){ float dd = p[o] - mean; var += dd * dd; }
      var *= 0.1f;
      float rs = 1.f / sqrtf(var + 1e-5f);
#pragma unroll
      for (int o = 0; o < 10; o++)
        out[o] += g * ((p[o] - mean) * rs * eng[e * 10 + o] + enb[e * 10 + o]);
    }
  }
  if (lane == 0){
    const float* r = routeS + (size_t)row * 32;
    float rem = 1.f - cumh[row];
#pragma unroll
    for (int o = 0; o < 10; o++)
      total[row * 10 + o] += rem * (out[o] + 0.22f * r[o] + 0.14f * r[10 + o]);
    cumh[row] += rem * haltb[row];
  }
}

// ---------------- shared branch --------------------------------------------------
__global__ __launch_bounds__(256)
void shared_kernel(const float* __restrict__ shpre, const float* __restrict__ sdw,
                   const float* __restrict__ g, const float* __restrict__ b,
                   float* __restrict__ outp)
{
  int lane = threadIdx.x & 63;
  int row = blockIdx.x * 4 + (threadIdx.x >> 6);
  const float* xr = shpre + (size_t)row * SHD;
  float p[10];
#pragma unroll
  for (int o = 0; o < 10; o++) p[o] = 0.f;
  for (int k = lane; k < SHD; k += 64){
    float xv = xr[k];
#pragma unroll
    for (int o = 0; o < 10; o++) p[o] = fmaf(xv, sdw[o * SHD + k], p[o]);
  }
#pragma unroll
  for (int o = 0; o < 10; o++) p[o] = wred(p[o]);
  float mean = 0.f;
#pragma unroll
  for (int o = 0; o < 10; o++) mean += p[o];
  mean *= 0.1f;
  float var = 0.f;
#pragma unroll
  for (int o = 0; o < 10; o++){ float dd = p[o] - mean; var += dd * dd; }
  var *= 0.1f;
  float rs = 1.f / sqrtf(var + 1e-5f);
  if (lane == 0){
#pragma unroll
    for (int o = 0; o < 10; o++) outp[row * 10 + o] = (p[o] - mean) * rs * g[o] + b[o];
  }
}

// ---------------- final output (lite) --------------------------------------------
__global__ __launch_bounds__(256)
void final_lite(const float* __restrict__ qaux, const float* __restrict__ biasp,
                const float* __restrict__ sharedp, const float* __restrict__ total,
                const float* __restrict__ routeS, const float* __restrict__ sscale,
                const float* __restrict__ alphap, const float* __restrict__ betap,
                float* __restrict__ outp)
{
  int row = blockIdx.x * 256 + threadIdx.x;
  float ss = sscale[0], av = alphap[0] + 1e-4f, bv = betap[0];
#pragma unroll
  for (int o = 0; o < 10; o++)
    outp[row * 10 + o] = (qaux[(size_t)row * 128 + 64 + o] + biasp[o])
                       + ss * sharedp[row * 10 + o]
                       + av * (total[row * 10 + o] * 0.25f)
                       + bv * routeS[(size_t)row * 32 + 20 + o];
}

// ====================================================================================
extern "C" void kernel_launch(void* const* d_in, const int* in_sizes, int n_in,
                              void* d_out, int out_size, void* d_ws, size_t ws_size,
                              hipStream_t stream)
{
  const float* x     = (const float*)d_in[0];
  const float* wgt   = (const float*)d_in[1];
  const float* bias  = (const float*)d_in[2];
  const float* suw   = (const float*)d_in[3];
  const float* sdw   = (const float*)d_in[4];
  const float* sng   = (const float*)d_in[5];
  const float* snb   = (const float*)d_in[6];
  const float* sscale= (const float*)d_in[7];
  const float* keys  = (const float*)d_in[8];
  const float* mvi   = (const float*)d_in[9];
  const float* mqw   = (const float*)d_in[10];
  const float* mow   = (const float*)d_in[11];
  const float* wgw   = (const float*)d_in[12];
  const float* wgb   = (const float*)d_in[13];
  const float* wvw   = (const float*)d_in[14];
  const float* wvb   = (const float*)d_in[15];
  const float* dqw   = (const float*)d_in[16];
  const float* dkw   = (const float*)d_in[17];
  const float* dvw   = (const float*)d_in[18];
  const float* dow   = (const float*)d_in[19];
  const float* clng  = (const float*)d_in[20];
  const float* clnb  = (const float*)d_in[21];
  const float* fc1w  = (const float*)d_in[22];
  const float* fc1b  = (const float*)d_in[23];
  const float* fc2w  = (const float*)d_in[24];
  const float* fc2b  = (const float*)d_in[25];
  const float* saw   = (const float*)d_in[26];
  const float* sab   = (const float*)d_in[27];
  const float* sbw   = (const float*)d_in[28];
  const float* sbb   = (const float*)d_in[29];
  const float* msw   = (const float*)d_in[30];
  const float* msb   = (const float*)d_in[31];
  const float* mmw   = (const float*)d_in[32];
  const float* mmb   = (const float*)d_in[33];
  const float* ebias = (const float*)d_in[34];
  const float* bw    = (const float*)d_in[35];
  const float* bb    = (const float*)d_in[36];
  const float* eup   = (const float*)d_in[37];
  const float* edn   = (const float*)d_in[38];
  const float* eng   = (const float*)d_in[39];
  const float* enb   = (const float*)d_in[40];
  const float* hw    = (const float*)d_in[41];
  const float* hb    = (const float*)d_in[42];
  const float* alphap= (const float*)d_in[43];
  const float* betap = (const float*)d_in[44];
  float* outp = (float*)d_out;

  char* wsb = (char*)d_ws;
  size_t off = 0;
  auto AL = [&](size_t bytes) -> void* {
    void* p = wsb + off;
    off = (off + bytes + 255) & ~(size_t)255;
    return p;
  };
  const size_t NI = (size_t)N_TOK * IN_D;
  float* cur    = (float*)AL(NI * 4);
  float* enr    = (float*)AL(NI * 4);
  float* dqbuf  = (float*)AL(NI * 4);
  float* qaux   = (float*)AL((size_t)N_TOK * 128 * 4);
  float* routeQ = (float*)AL((size_t)4 * N_TOK * 128 * 4);
  float* routeS = (float*)AL((size_t)N_TOK * 32 * 4);
  float* trio0  = (float*)AL((size_t)N_TOK * 3072 * 4);
  float* trio1  = (float*)AL((size_t)N_TOK * 3072 * 4);
  float* trio2  = (float*)AL((size_t)N_TOK * 3072 * 4);
  float* Ac     = (float*)AL((size_t)N_TOK * 24 * 4);
  float* W0     = (float*)AL((size_t)N_TOK * 24 * 4);
  float* W1     = (float*)AL((size_t)N_TOK * 24 * 4);
  float* W2     = (float*)AL((size_t)N_TOK * 24 * 4);
  float* sg     = (float*)AL((size_t)N_TOK * 10 * 4);
  float* haltb  = (float*)AL((size_t)N_TOK * 4);
  char*  zblk   = (char*)AL((size_t)N_TOK * 10 * 4 + N_TOK * 4 + 4 * 16 * 4);
  float* total  = (float*)zblk;
  float* cumh   = (float*)(zblk + (size_t)N_TOK * 10 * 4);
  int*   cnt    = (int*)(zblk + (size_t)N_TOK * 10 * 4 + N_TOK * 4);
  int*   gidx   = (int*)AL((size_t)NEXP * N_TOK * 4);
  int*   pos    = (int*)AL((size_t)N_TOK * NEXP * 4);
  float* sharedp= (float*)AL((size_t)N_TOK * 10 * 4);
  float* cbias  = (float*)AL(3072 * 4);
  float* K2f    = (float*)AL((size_t)24 * 1024 * 4);
  uint16_t* lnh  = (uint16_t*)AL(NI * 2);
  uint16_t* lnl  = (uint16_t*)AL(NI * 2);
  uint16_t* h7h  = (uint16_t*)AL((size_t)N_TOK * INNER * 2);
  uint16_t* h7l  = (uint16_t*)AL((size_t)N_TOK * INNER * 2);
  uint16_t* Arh  = (uint16_t*)AL((size_t)N_TOK * 3072 * 2);
  uint16_t* Arl  = (uint16_t*)AL((size_t)N_TOK * 3072 * 2);
  const size_t W1M = (size_t)IN_D * IN_D;
  uint16_t* preWh  = (uint16_t*)AL((size_t)2176 * 1024 * 2);
  uint16_t* preWl  = (uint16_t*)AL((size_t)2176 * 1024 * 2);
  uint16_t* qtWh   = (uint16_t*)AL((size_t)4224 * 1024 * 2);
  uint16_t* qtWl   = (uint16_t*)AL((size_t)4224 * 1024 * 2);
  uint16_t* rtWh   = (uint16_t*)AL((size_t)4 * 128 * 3072 * 2);
  uint16_t* rtWl   = (uint16_t*)AL((size_t)4 * 128 * 3072 * 2);
  const size_t WFC = (size_t)NSTEP * INNER * IN_D;
  uint16_t* fc1wh = (uint16_t*)AL(WFC * 2); uint16_t* fc1wl = (uint16_t*)AL(WFC * 2);
  uint16_t* fc2wh = (uint16_t*)AL(WFC * 2); uint16_t* fc2wl = (uint16_t*)AL(WFC * 2);
  uint16_t* upbf  = (uint16_t*)AL((size_t)NEXP * DMAX * IN_D * 2);
  uint16_t* HHc   = (uint16_t*)AL((size_t)N_TOK * DSUM * 2);
  float* shpre  = (float*)HHc;   // alias: consumed before HHc is written

  // ---- init ----
  hipMemsetAsync(zblk, 0, (size_t)N_TOK * 10 * 4 + N_TOK * 4 + 4 * 16 * 4, stream);
  hipMemsetAsync(cbias, 0, 3072 * 4, stream);
  hipMemcpyAsync(cbias + 2048, wvb, 1024 * 4, hipMemcpyDeviceToDevice, stream);
  hipMemcpyAsync(cur, x, NI * 4, hipMemcpyDeviceToDevice, stream);
  fill1_kernel<<<(N_TOK * 24 + 255) / 256, 256, 0, stream>>>(Ac, N_TOK * 24);
  cvt_bf16_kernel<<<2048, 256, 0, stream>>>(eup, upbf, (size_t)NEXP * DMAX * IN_D);

  split_strided<<<1024, 256, 0, stream>>>(x, Arh, Arl, N_TOK, 1024, 3072);
  split_kernel<<<1024, 256, 0, stream>>>(suw, preWh, preWl, (size_t)SHD * 1024);
  split_kernel<<<256, 256, 0, stream>>>(saw, preWh + (size_t)2072*1024, preWl + (size_t)2072*1024, (size_t)40 * 1024);
  split_kernel<<<256, 256, 0, stream>>>(wgt, preWh + (size_t)2112*1024, preWl + (size_t)2112*1024, (size_t)10 * 1024);
  hipMemsetAsync(preWh + (size_t)2122*1024, 0, (size_t)54 * 1024 * 2, stream);
  hipMemsetAsync(preWl + (size_t)2122*1024, 0, (size_t)54 * 1024 * 2, stream);
  split_kernel<<<1024, 256, 0, stream>>>(dqw, qtWh, qtWl, W1M);
  split_kernel<<<1024, 256, 0, stream>>>(dkw, qtWh + W1M, qtWl + W1M, W1M);
  split_kernel<<<1024, 256, 0, stream>>>(dvw, qtWh + 2*W1M, qtWl + 2*W1M, W1M);
  split_kernel<<<1024, 256, 0, stream>>>(wvw, qtWh + 3*W1M, qtWl + 3*W1M, W1M);
  split_kernel<<<256, 256, 0, stream>>>(saw, qtWh + (size_t)4120*1024, qtWl + (size_t)4120*1024, (size_t)40 * 1024);
  hipMemsetAsync(qtWh + (size_t)4160*1024, 0, (size_t)64 * 1024 * 2, stream);
  hipMemsetAsync(qtWl + (size_t)4160*1024, 0, (size_t)64 * 1024 * 2, stream);
  k2_kernel<<<dim3(24, 4), 256, 0, stream>>>(keys, mqw, K2f);
  split_kernel<<<256, 256, 0, stream>>>(K2f, preWh + (size_t)2048*1024, preWl + (size_t)2048*1024, (size_t)24 * 1024);
  split_kernel<<<256, 256, 0, stream>>>(K2f, qtWh + (size_t)4096*1024, qtWl + (size_t)4096*1024, (size_t)24 * 1024);
  build_routew<<<2048, 256, 0, stream>>>(msw, mmw, bw, wgw, hw, mow, dow, rtWh, rtWl);
  split_kernel<<<1024, 256, 0, stream>>>(fc1w, fc1wh, fc1wl, WFC);
  split_kernel<<<1024, 256, 0, stream>>>(fc2w, fc2wh, fc2wl, WFC);

  gemm_sp<EPI_PRE><<<dim3(17, 16), 256, 0, stream>>>(
      Arh, Arl, 3072, preWh, preWl, nullptr, nullptr, nullptr, nullptr,
      shpre, qaux, nullptr, nullptr, nullptr, nullptr, IN_D, 2176);
  shared_kernel<<<512, 256, 0, stream>>>(shpre, sdw, sng, snb, sharedp);

  float* trioB[3] = {trio0, trio1, trio2};

  for (int t = 0; t < NSTEP; t++){
    ctx_enr_kernel<<<2048, 256, 0, stream>>>(qaux, dqbuf, Ac, W0, W1, W2, mvi,
                                             trio0, trio1, trio2, cur, sab, sbw, sbb,
                                             clng, clnb, enr, lnh, lnl, Arh, Arl, t);
    gemm_sp<EPI_GELU><<<dim3(INNER/128, 16), 256, 0, stream>>>(
        lnh, lnl, 1024, fc1wh + (size_t)t * INNER * IN_D, fc1wl + (size_t)t * INNER * IN_D,
        nullptr, nullptr, fc1b + t * INNER, nullptr,
        nullptr, nullptr, nullptr, nullptr, h7h, h7l, IN_D, INNER);
    gemm_sp<EPI_CUR><<<dim3(8, 16), 256, 0, stream>>>(
        h7h, h7l, 768, fc2wh + (size_t)t * IN_D * INNER, fc2wl + (size_t)t * IN_D * INNER,
        nullptr, nullptr, fc2b + t * IN_D, enr,
        cur, nullptr, nullptr, nullptr, Arh, Arl, INNER, IN_D);
    // fused: blocks x<4 = route (K-split over 3072), x>=4 = qtrio (t<3 only)
    gemm_sp<EPI_QROUTE><<<dim3(t < 3 ? 37 : 4, 16), 256, 0, stream>>>(
        Arh, Arl, 3072, qtWh, qtWl,
        rtWh + (size_t)t * 128 * 3072, rtWl + (size_t)t * 128 * 3072,
        cbias, nullptr, dqbuf, t < 3 ? trioB[t] : nullptr, qaux, routeQ,
        nullptr, nullptr, IN_D, 4224);
    route_fin<<<8, 256, 0, stream>>>(routeQ, mmb, msb, ebias, bb, wgb, hb,
                                     sg, haltb, Ac, W0, W1, W2,
                                     cnt + t * 16, gidx, pos, routeS, t);
    expert_up_mfma<<<dim3(4, 188), 256, 0, stream>>>(Arh, upbf, cnt + t * 16, gidx, HHc);
    downfin_kernel<<<512, 256, 0, stream>>>(HHc, pos, edn, sg, eng, enb,
                                            routeS, haltb, total, cumh);
  }
  final_lite<<<8, 256, 0, stream>>>(qaux, bias, sharedp, total, routeS,
                                    sscale, alphap, betap, outp);
}